// Round 9
// baseline (1146.874 us; speedup 1.0000x reference)
//
#include <hip/hip_runtime.h>
#include <hip/hip_bf16.h>
#include <math.h>

#define BB 16
#define TT 512
#define VV 2048
#define DD 512
#define HDD 64
#define LL 6
#define FF 2048
#define BT 8192   // B*T

typedef __hip_bfloat16 bf16;
typedef __attribute__((ext_vector_type(8))) short bf8s;   // 8 bf16 (4 VGPRs)
typedef __attribute__((ext_vector_type(4))) float f4;     // C/D frag

__device__ __forceinline__ float cvt(float x){ return x; }
__device__ __forceinline__ float cvt(bf16 x){ return __bfloat162float(x); }

// async global->LDS, 16B per lane. LDS dest wave-uniform base (+lane*16 by HW).
__device__ __forceinline__ void gl16(const bf16* g, bf16* l){
  __builtin_amdgcn_global_load_lds(
      (const __attribute__((address_space(1))) void*)g,
      (__attribute__((address_space(3))) void*)l,
      16, 0, 0);
}

// ---------------- dtype flag ----------------
__global__ void k_flag(const void* g1, int* flagp){
  if(threadIdx.x==0 && blockIdx.x==0){
    const unsigned short* u = (const unsigned short*)g1;
    *flagp = (u[0] == 0) ? 1 : 0;   // 1 = inputs f32, 0 = bf16
  }
}

__global__ __launch_bounds__(256) void k_cvt(const void* __restrict__ src,
                                             bf16* __restrict__ dst, int n,
                                             const int* __restrict__ flagp){
  int i = blockIdx.x*256 + threadIdx.x;
  if(i >= n) return;
  if(*flagp) dst[i] = (bf16)(((const float*)src)[i]);
  else       dst[i] = ((const bf16*)src)[i];
}

__global__ void k_packb(const void* bq, const void* bk, const void* bv,
                        bf16* dst, const int* flagp){
  int i = blockIdx.x*256 + threadIdx.x;
  if(i >= LL*192) return;
  int l = i/192, r = i%192, j = r>>6, hh = r&63;
  const void* s = (j==0)?bq:((j==1)?bk:bv);
  float v = (*flagp) ? ((const float*)s)[l*64+hh] : cvt(((const bf16*)s)[l*64+hh]);
  dst[i] = (bf16)v;
}

// ---------------- tiled transpose: src [z][R][C] -> dst [z][C][R(ldD)] bf16 ----------------
__global__ __launch_bounds__(256) void k_tr(const void* __restrict__ src, bf16* __restrict__ dst,
                                            int R, int C, long long sS, long long sD, int ldD,
                                            const int* __restrict__ flagp){
  __shared__ bf16 t[32][33];
  int z = blockIdx.z;
  int c0 = blockIdx.x*32, r0 = blockIdx.y*32;
  int tx = threadIdx.x & 31, ty = threadIdx.x >> 5;
  bool isf = flagp && (*flagp);
  const float* sf = (const float*)src;
  const bf16*  sb = (const bf16*)src;
  for(int i=ty; i<32; i+=8){
    size_t off = (size_t)z*sS + (size_t)(r0+i)*C + (c0+tx);
    float v = isf ? sf[off] : cvt(sb[off]);
    t[i][tx] = (bf16)v;
  }
  __syncthreads();
  for(int i=ty; i<32; i+=8){
    dst[(size_t)z*sD + (size_t)(c0+i)*ldD + (r0+tx)] = t[tx][i];
  }
}

// ---------------- wsT_all[l][d][h] = sum_n Wo[l][n*64+h][d] ----------------
__global__ __launch_bounds__(256) void k_wsumT(const void* __restrict__ Wo,
                                               bf16* __restrict__ wsT,
                                               const int* __restrict__ flagp){
  int i = blockIdx.x*256 + threadIdx.x;
  if(i >= LL*64*512) return;
  int l = i >> 15, j = i & 32767, hh = j>>9, d = j&511;
  size_t loff = (size_t)l*512*512;
  bool isf = *flagp;
  float a = 0.f;
  #pragma unroll
  for(int n=0;n<8;++n){
    size_t idx = loff + (size_t)(n*64+hh)*512 + d;
    a += isf ? ((const float*)Wo)[idx] : cvt(((const bf16*)Wo)[idx]);
  }
  wsT[(size_t)l*32768 + d*64 + hh] = (bf16)a;
}

// ---------------- embed + positional encoding ----------------
__global__ __launch_bounds__(256) void k_embed(const int* __restrict__ idx,
                                               const void* __restrict__ emb,
                                               float* __restrict__ h,
                                               const int* __restrict__ flagp){
  int r = blockIdx.x;
  int t = r & (TT-1);
  int tok = idx[r];
  bool isf = *flagp;
  for(int d = threadIdx.x; d < DD; d += 256){
    int p = d >> 1;
    float ang = (float)t * powf(10000.f, -(float)p * (1.f/128.f));
    float pe = (d & 1) ? cosf(ang) : sinf(ang);
    size_t off = (size_t)tok*DD + d;
    float ev = isf ? ((const float*)emb)[off] : cvt(((const bf16*)emb)[off]);
    h[(size_t)r*DD + d] = 2.f*ev + pe;
  }
}

// ---------------- LayerNorm ----------------
__global__ __launch_bounds__(256) void k_ln(const float* __restrict__ x,
                                            const bf16* __restrict__ g,
                                            const bf16* __restrict__ b,
                                            bf16* __restrict__ y){
  int r = blockIdx.x;
  int tid = threadIdx.x;
  const float* xr = x + (size_t)r*DD;
  float v0 = xr[tid], v1 = xr[tid+256];
  float s = v0+v1, s2 = v0*v0 + v1*v1;
  for(int o=32;o;o>>=1){ s += __shfl_down(s,o); s2 += __shfl_down(s2,o); }
  __shared__ float red[8];
  int wv = tid>>6, ln = tid&63;
  if(ln==0){ red[wv]=s; red[4+wv]=s2; }
  __syncthreads();
  float a  = red[0]+red[1]+red[2]+red[3];
  float a2 = red[4]+red[5]+red[6]+red[7];
  float m  = a*(1.f/DD);
  float var = a2*(1.f/DD) - m*m;
  float inv = rsqrtf(var + 1e-5f);
  y[(size_t)r*DD+tid]     = (bf16)((v0-m)*inv*cvt(g[tid])     + cvt(b[tid]));
  y[(size_t)r*DD+tid+256] = (bf16)((v1-m)*inv*cvt(g[tid+256]) + cvt(b[tid+256]));
}

__global__ __launch_bounds__(256) void k_f2b(const float* __restrict__ x, bf16* __restrict__ o, int n){
  int i = blockIdx.x*256 + threadIdx.x;
  if(i < n) o[i] = (bf16)x[i];
}

// =====================  MFMA GEMM (unchanged)  =====================
template<int BM,int BN,int WM,int WN,int CMODE,bool RELU,bool RESID>
__global__ __launch_bounds__(256) void mm(const bf16* __restrict__ A,
                                          const bf16* __restrict__ Bt,
                                          void* __restrict__ Cv,
                                          const bf16* __restrict__ bias,
                                          int M, int N, int K,
                                          long long sA, long long sB, long long sC, int sBias,
                                          int gx,
                                          const int* __restrict__ flagp){
  constexpr int BK  = 64;
  constexpr int FM  = BM/(WM*16);
  constexpr int FN  = BN/(WN*16);
  constexpr int S   = (BM+BN)*BK;
  constexpr int CAW = (BM*BK/512)/4;
  constexpr int CBW = (BN*BK/512)/4;
  __shared__ bf16 lds[2*S];
  int nwg = gridDim.x, bid = blockIdx.x;
  int q = nwg>>3, rr = nwg&7, xcd = bid&7, ii = bid>>3;
  int wg = (xcd<rr ? xcd*(q+1) : rr*(q+1)+(xcd-rr)*q) + ii;
  int bx = wg % gx, by = wg / gx;
  int z = blockIdx.z;
  A  += (size_t)z*sA;
  Bt += (size_t)z*sB;
  if(bias) bias += (size_t)z*sBias;
  int tid = threadIdx.x, lane = tid&63, w = tid>>6;
  int m0 = by*BM, n0 = bx*BN;
  int wrow = (w/WN)*(FM*16), wcol = (w%WN)*(FN*16);
  int l15 = lane&15, l4 = lane>>4;
  int lrow = lane>>3, lgr = lane&7;
  int nk = K/BK;
  auto stage = [&](int kt, int buf){
    bf16* Ab = lds + buf*S;
    bf16* Bb = Ab + BM*BK;
    const bf16* gA = A + (size_t)m0*K + kt*BK;
    const bf16* gB = Bt + (size_t)n0*K + kt*BK;
    #pragma unroll
    for(int i=0;i<CAW;++i){
      int chunk = w*CAW + i;
      int row = chunk*8 + lrow;
      gl16(gA + (size_t)row*K + ((lgr ^ (row&7))*8), Ab + chunk*512);
    }
    #pragma unroll
    for(int i=0;i<CBW;++i){
      int chunk = w*CBW + i;
      int row = chunk*8 + lrow;
      gl16(gB + (size_t)row*K + ((lgr ^ (row&7))*8), Bb + chunk*512);
    }
  };
  f4 acc[FM][FN] = {};
  stage(0, 0);
  __syncthreads();
  for(int kt=0; kt<nk; ++kt){
    int cur = kt & 1;
    if(kt+1 < nk) stage(kt+1, cur^1);
    const bf16* Ab = lds + cur*S;
    const bf16* Bb = Ab + BM*BK;
    #pragma unroll
    for(int g=0; g<2; ++g){
      bf8s af[FM], bfv[FN];
      #pragma unroll
      for(int i=0;i<FM;++i){
        int r = wrow + i*16 + l15;
        af[i] = *(const bf8s*)(Ab + r*BK + (((g*4+l4) ^ (r&7))*8));
      }
      #pragma unroll
      for(int j=0;j<FN;++j){
        int r = wcol + j*16 + l15;
        bfv[j] = *(const bf8s*)(Bb + r*BK + (((g*4+l4) ^ (r&7))*8));
      }
      #pragma unroll
      for(int i=0;i<FM;++i)
        #pragma unroll
        for(int j=0;j<FN;++j)
          acc[i][j] = __builtin_amdgcn_mfma_f32_16x16x32_bf16(af[i], bfv[j], acc[i][j], 0,0,0);
    }
    __syncthreads();
  }
  bool f32o = (CMODE==2) ? (*flagp != 0) : (CMODE==1);
  #pragma unroll
  for(int i=0;i<FM;++i){
    #pragma unroll
    for(int j=0;j<FN;++j){
      int col = n0 + wcol + j*16 + l15;
      float bv = bias ? cvt(bias[col]) : 0.f;
      #pragma unroll
      for(int q2=0;q2<4;++q2){
        int row = m0 + wrow + i*16 + l4*4 + q2;
        size_t off = (size_t)z*sC + (size_t)row*N + col;
        float v = acc[i][j][q2] + bv;
        if(RESID) v += ((const float*)Cv)[off];
        if(RELU)  v = fmaxf(v, 0.f);
        if(CMODE==0)      ((bf16*)Cv)[off] = (bf16)v;
        else if(CMODE==1) ((float*)Cv)[off] = v;
        else { if(f32o) ((float*)Cv)[off] = v; else ((bf16*)Cv)[off] = (bf16)v; }
      }
    }
  }
}

// =====================  FUSED ATTENTION  =====================
// Block = (ti, b): 32 q-rows, 2 waves x 16 rows, no cross-wave dataflow.
// FIX vs round 8: amlds (bucket sums) is now zero-initialized — for rows t<16,
// buckets m<16-t are never written by the softmax phase but ARE read by the
// rel-bias epilogue (was reading stale LDS garbage).
__global__ __launch_bounds__(128) void k_attn_fused(const bf16* __restrict__ Q,
                                                    const bf16* __restrict__ K,
                                                    const bf16* __restrict__ VbT,
                                                    const bf16* __restrict__ rel,  // [33][64]
                                                    bf16* __restrict__ vals){
  int ti = blockIdx.x, b = blockIdx.y;
  int t0 = ti*32;
  int tid = threadIdx.x, lane = tid & 63, w = tid >> 6;
  int l15 = lane & 15, l4 = lane >> 4;
  __shared__ bf16  Plds[32][520];
  __shared__ float qrs[32][17];
  __shared__ float amlds[32][17];
  int nj = (t0 + 32) >> 4;          // 16-wide s-tiles staged
  int nk = (t0 + 32 + 63) >> 6;     // 64-wide k-chunks for PV

  const bf16* Qb = Q + ((size_t)b*512 + t0)*64;
  const bf16* Kb = K + (size_t)b*512*64;
  const bf16* Vb = VbT + (size_t)b*64*512;

  // zero Plds (PV reads up to nk*64 cols; only nj*16 get written) + amlds
  for(int i=tid; i<(32*520)/8; i+=128) ((bf8s*)Plds)[i] = (bf8s){0,0,0,0,0,0,0,0};
  for(int i=tid; i<32*17; i+=128) ((float*)amlds)[i] = 0.f;
  __syncthreads();

  // Q fragments for this wave's 16 rows (reused for qrel and QK^T)
  bf8s af0 = *(const bf8s*)(Qb + (size_t)(w*16+l15)*64 + l4*8);
  bf8s af1 = *(const bf8s*)(Qb + (size_t)(w*16+l15)*64 + 32 + l4*8);

  // qrel via MFMA: Q[16x64] @ rel^T -> qrs (m = 0..16)
  #pragma unroll
  for(int jn=0;jn<2;++jn){
    f4 qa = {};
    bf8s r0 = *(const bf8s*)(rel + (size_t)(jn*16+l15)*64 + l4*8);
    bf8s r1 = *(const bf8s*)(rel + (size_t)(jn*16+l15)*64 + 32 + l4*8);
    qa = __builtin_amdgcn_mfma_f32_16x16x32_bf16(af0, r0, qa, 0,0,0);
    qa = __builtin_amdgcn_mfma_f32_16x16x32_bf16(af1, r1, qa, 0,0,0);
    int m = jn*16 + l15;
    if(m < 17){
      #pragma unroll
      for(int q=0;q<4;++q) qrs[w*16 + l4*4 + q][m] = qa[q];
    }
  }
  // S tiles: raw scores bf16 into Plds
  for(int j=0;j<nj;++j){
    f4 sa = {};
    bf8s k0 = *(const bf8s*)(Kb + (size_t)(j*16+l15)*64 + l4*8);
    bf8s k1 = *(const bf8s*)(Kb + (size_t)(j*16+l15)*64 + 32 + l4*8);
    sa = __builtin_amdgcn_mfma_f32_16x16x32_bf16(af0, k0, sa, 0,0,0);
    sa = __builtin_amdgcn_mfma_f32_16x16x32_bf16(af1, k1, sa, 0,0,0);
    #pragma unroll
    for(int q=0;q<4;++q) Plds[w*16 + l4*4 + q][j*16 + l15] = (bf16)sa[q];
  }
  __syncthreads();

  // row softmax: 4 threads per row
  int row = tid >> 2, g4 = tid & 3;
  int t = t0 + row;
  int send = nj*16;
  float mx = -INFINITY;
  for(int s=g4; s<send; s+=4){
    if(s <= t){
      int m = s - t + 16; m = m < 0 ? 0 : m;
      float v = (cvt(Plds[row][s]) + qrs[row][m])*0.125f;
      mx = fmaxf(mx, v);
    }
  }
  mx = fmaxf(mx, __shfl_xor(mx,1));
  mx = fmaxf(mx, __shfl_xor(mx,2));
  float sum = 0.f;
  for(int s=g4; s<send; s+=4){
    float e = 0.f;
    if(s <= t){
      int m = s - t + 16; m = m < 0 ? 0 : m;
      e = expf((cvt(Plds[row][s]) + qrs[row][m])*0.125f - mx);
    }
    sum += e;
  }
  sum += __shfl_xor(sum,1);
  sum += __shfl_xor(sum,2);
  float rs = 1.f/sum;
  float part0 = 0.f;
  for(int s=g4; s<send; s+=4){
    float p = 0.f;
    if(s <= t){
      int m = s - t + 16;
      p = expf((cvt(Plds[row][s]) + qrs[row][m<0?0:m])*0.125f - mx)*rs;
      if(m <= 0) part0 += p;
      else       amlds[row][m] = p;       // unique owner per (row,m)
    }
    Plds[row][s] = (bf16)p;
  }
  part0 += __shfl_xor(part0,1);
  part0 += __shfl_xor(part0,2);
  if(g4==0) amlds[row][0] = part0;
  __syncthreads();

  // PV: wave's own 16 rows x 64 h, K = nk*64
  f4 pacc[4] = {};
  for(int ks=0; ks<nk; ++ks){
    #pragma unroll
    for(int g=0; g<2; ++g){
      bf8s ap = *(const bf8s*)(&Plds[w*16 + l15][ks*64 + g*32 + l4*8]);
      #pragma unroll
      for(int jn=0;jn<4;++jn){
        bf8s bv = *(const bf8s*)(Vb + (size_t)(jn*16+l15)*512 + ks*64 + g*32 + l4*8);
        pacc[jn] = __builtin_amdgcn_mfma_f32_16x16x32_bf16(ap, bv, pacc[jn], 0,0,0);
      }
    }
  }
  // epilogue: + sum_m am[r][m]*rel[m][h], store
  #pragma unroll
  for(int jn=0;jn<4;++jn){
    int h = jn*16 + l15;
    float v0=pacc[jn][0], v1=pacc[jn][1], v2=pacc[jn][2], v3=pacc[jn][3];
    int rbase = w*16 + l4*4;
    #pragma unroll
    for(int m=0;m<17;++m){
      float rl = cvt(rel[m*64 + h]);
      v0 += amlds[rbase+0][m]*rl;
      v1 += amlds[rbase+1][m]*rl;
      v2 += amlds[rbase+2][m]*rl;
      v3 += amlds[rbase+3][m]*rl;
    }
    size_t o = ((size_t)b*512 + t0 + rbase)*64 + h;
    vals[o]       = (bf16)v0;
    vals[o+64]    = (bf16)v1;
    vals[o+128]   = (bf16)v2;
    vals[o+192]   = (bf16)v3;
  }
}

extern "C" void kernel_launch(void* const* d_in, const int* in_sizes, int n_in,
                              void* d_out, int out_size, void* d_ws, size_t ws_size,
                              hipStream_t stream){
  const int* idx = (const int*)d_in[0];

  char* p = (char*)d_ws;
  auto alloc = [&](size_t bytes)->char*{ char* r = p; p += (bytes + 255) & ~(size_t)255; return r; };

  int*  flag  = (int*)alloc(4);
  bf16* rel_b = (bf16*)alloc(12672*2);
  bf16* bo_b  = (bf16*)alloc(3072*2);
  bf16* g1_b  = (bf16*)alloc(3072*2);
  bf16* be1_b = (bf16*)alloc(3072*2);
  bf16* g2_b  = (bf16*)alloc(3072*2);
  bf16* be2_b = (bf16*)alloc(3072*2);
  bf16* b1_b  = (bf16*)alloc(12288*2);
  bf16* b2_b  = (bf16*)alloc(3072*2);
  bf16* bout_b= (bf16*)alloc(2048*2);
  bf16* bqkv  = (bf16*)alloc(LL*192*2);
  bf16* WqkvT = (bf16*)alloc((size_t)LL*3*64*512*2);    // [L][3][64][512]
  bf16* W1T   = (bf16*)alloc((size_t)LL*2048*512*2);    // [L][2048][512]
  bf16* W2T   = (bf16*)alloc((size_t)LL*512*2048*2);    // [L][512][2048]
  bf16* WoutT = (bf16*)alloc((size_t)2048*512*2);       // [2048][512]
  bf16* wsT_all=(bf16*)alloc((size_t)LL*512*64*2);      // [L][512][64]
  float* h    = (float*)alloc((size_t)BT*DD*4);         // 16 MB
  bf16*  y    = (bf16*) alloc((size_t)BT*DD*2);         //  8 MB
  bf16*  hb   = y;                                      // f2b output (y dead by then)
  bf16*  QKV  = (bf16*) alloc((size_t)3*BT*64*2);       // Q|K|V contiguous
  bf16*  vals = (bf16*) alloc((size_t)BT*64*2);
  bf16*  VbT  = (bf16*) alloc((size_t)BB*64*512*2);     // [16][64][512]
  bf16*  mid  = (bf16*)d_out;                           // FFN scratch in d_out
  bf16*  Qb = QKV, *Kb = QKV + (size_t)BT*64;

  // ---- setup ----
  k_flag<<<1,64,0,stream>>>(d_in[11], flag);
  k_cvt<<<(12672+255)/256,256,0,stream>>>(d_in[8],  rel_b, 12672, flag);
  k_cvt<<<(3072+255)/256,256,0,stream>>>(d_in[10], bo_b,  3072, flag);
  k_cvt<<<(3072+255)/256,256,0,stream>>>(d_in[11], g1_b,  3072, flag);
  k_cvt<<<(3072+255)/256,256,0,stream>>>(d_in[12], be1_b, 3072, flag);
  k_cvt<<<(3072+255)/256,256,0,stream>>>(d_in[13], g2_b,  3072, flag);
  k_cvt<<<(3072+255)/256,256,0,stream>>>(d_in[14], be2_b, 3072, flag);
  k_cvt<<<(12288+255)/256,256,0,stream>>>(d_in[16], b1_b, 12288, flag);
  k_cvt<<<(3072+255)/256,256,0,stream>>>(d_in[18], b2_b,  3072, flag);
  k_cvt<<<(2048+255)/256,256,0,stream>>>(d_in[20], bout_b, 2048, flag);
  k_packb<<<(LL*192+255)/256,256,0,stream>>>(d_in[3], d_in[5], d_in[7], bqkv, flag);
  k_tr<<<dim3(2,16,LL),256,0,stream>>>(d_in[2], WqkvT,            512, 64, 512*64, 3*64*512, 512, flag);
  k_tr<<<dim3(2,16,LL),256,0,stream>>>(d_in[4], WqkvT + 64*512,   512, 64, 512*64, 3*64*512, 512, flag);
  k_tr<<<dim3(2,16,LL),256,0,stream>>>(d_in[6], WqkvT + 2*64*512, 512, 64, 512*64, 3*64*512, 512, flag);
  k_tr<<<dim3(64,16,LL),256,0,stream>>>(d_in[15], W1T, 512, 2048, 512*2048, 2048*512, 512, flag);
  k_tr<<<dim3(16,64,LL),256,0,stream>>>(d_in[17], W2T, 2048, 512, 2048*512, 512*2048, 2048, flag);
  k_tr<<<dim3(64,16,1),256,0,stream>>>(d_in[19], WoutT, 512, 2048, 0, 0, 512, flag);
  k_wsumT<<<(LL*32768+255)/256,256,0,stream>>>(d_in[9], wsT_all, flag);

  k_embed<<<BT,256,0,stream>>>(idx, d_in[1], h, flag);

  for(int l=0; l<LL; ++l){
    k_ln<<<BT,256,0,stream>>>(h, g1_b+l*DD, be1_b+l*DD, y);
    // QKV: batched z=3, N=64
    mm<128,64,4,1,0,false,false><<<dim3(64,1,3),256,0,stream>>>(
        y, WqkvT + (size_t)l*3*64*512, QKV, bqkv + l*192,
        BT, 64, 512, 0, 64*512, (long long)BT*64, 64, 1, nullptr);
    // V [16][512][64] -> VbT [16][64][512]
    k_tr<<<dim3(2,16,BB),256,0,stream>>>(QKV + (size_t)2*BT*64, VbT, 512, 64, 512*64, 64*512, 512, nullptr);
    // fused scores+softmax+bucket+PV+relbias
    k_attn_fused<<<dim3(16,16),128,0,stream>>>(Qb, Kb, VbT, rel_b + l*33*64, vals);
    // h += vals @ WsumT + bo
    mm<128,64,4,1,1,false,true><<<dim3(512,1,1),256,0,stream>>>(
        vals, wsT_all + (size_t)l*32768, h, bo_b + l*DD, BT, 512, 64, 0,0,0,0, 8, nullptr);
    k_ln<<<BT,256,0,stream>>>(h, g2_b+l*DD, be2_b+l*DD, y);
    // mid = relu(y @ W1 + b1)   (bf16, d_out scratch)
    mm<128,64,4,1,0,true,false><<<dim3(2048,1,1),256,0,stream>>>(
        y, W1T + (size_t)l*2048*512, mid, b1_b + l*FF, BT, 2048, 512, 0,0,0,0, 32, nullptr);
    // h += mid @ W2 + b2
    mm<128,64,4,1,1,false,true><<<dim3(512,1,1),256,0,stream>>>(
        mid, W2T + (size_t)l*512*2048, h, b2_b + l*DD, BT, 512, 2048, 0,0,0,0, 8, nullptr);
  }
  k_f2b<<<(BT*DD+255)/256,256,0,stream>>>(h, hb, BT*DD);
  // out = hb @ Wout + bout (dual store per flag; fully rewrites d_out)
  mm<128,64,4,1,2,false,false><<<dim3(2048,1,1),256,0,stream>>>(
      hb, WoutT, d_out, bout_b, BT, 2048, 512, 0,0,0,0, 32, flag);
}

// Round 10
// 940.725 us; speedup vs baseline: 1.2191x; 1.2191x over previous
//
#include <hip/hip_runtime.h>
#include <hip/hip_bf16.h>
#include <math.h>

#define BB 16
#define TT 512
#define VV 2048
#define DD 512
#define HDD 64
#define LL 6
#define FF 2048
#define BT 8192   // B*T

typedef __hip_bfloat16 bf16;
typedef __attribute__((ext_vector_type(8))) short bf8s;   // 8 bf16 (4 VGPRs)
typedef __attribute__((ext_vector_type(4))) float f4;     // C/D frag

__device__ __forceinline__ float cvt(float x){ return x; }
__device__ __forceinline__ float cvt(bf16 x){ return __bfloat162float(x); }

// async global->LDS, 16B per lane. LDS dest wave-uniform base (+lane*16 by HW).
__device__ __forceinline__ void gl16(const bf16* g, bf16* l){
  __builtin_amdgcn_global_load_lds(
      (const __attribute__((address_space(1))) void*)g,
      (__attribute__((address_space(3))) void*)l,
      16, 0, 0);
}

// ---------------- dtype flag ----------------
__global__ void k_flag(const void* g1, int* flagp){
  if(threadIdx.x==0 && blockIdx.x==0){
    const unsigned short* u = (const unsigned short*)g1;
    *flagp = (u[0] == 0) ? 1 : 0;   // 1 = inputs f32, 0 = bf16
  }
}

__global__ __launch_bounds__(256) void k_cvt(const void* __restrict__ src,
                                             bf16* __restrict__ dst, int n,
                                             const int* __restrict__ flagp){
  int i = blockIdx.x*256 + threadIdx.x;
  if(i >= n) return;
  if(*flagp) dst[i] = (bf16)(((const float*)src)[i]);
  else       dst[i] = ((const bf16*)src)[i];
}

__global__ void k_packb(const void* bq, const void* bk, const void* bv,
                        bf16* dst, const int* flagp){
  int i = blockIdx.x*256 + threadIdx.x;
  if(i >= LL*192) return;
  int l = i/192, r = i%192, j = r>>6, hh = r&63;
  const void* s = (j==0)?bq:((j==1)?bk:bv);
  float v = (*flagp) ? ((const float*)s)[l*64+hh] : cvt(((const bf16*)s)[l*64+hh]);
  dst[i] = (bf16)v;
}

// ---------------- tiled transpose: src [z][R][C] -> dst [z][C][R(ldD)] bf16 ----------------
__global__ __launch_bounds__(256) void k_tr(const void* __restrict__ src, bf16* __restrict__ dst,
                                            int R, int C, long long sS, long long sD, int ldD,
                                            const int* __restrict__ flagp){
  __shared__ bf16 t[32][33];
  int z = blockIdx.z;
  int c0 = blockIdx.x*32, r0 = blockIdx.y*32;
  int tx = threadIdx.x & 31, ty = threadIdx.x >> 5;
  bool isf = flagp && (*flagp);
  const float* sf = (const float*)src;
  const bf16*  sb = (const bf16*)src;
  for(int i=ty; i<32; i+=8){
    size_t off = (size_t)z*sS + (size_t)(r0+i)*C + (c0+tx);
    float v = isf ? sf[off] : cvt(sb[off]);
    t[i][tx] = (bf16)v;
  }
  __syncthreads();
  for(int i=ty; i<32; i+=8){
    dst[(size_t)z*sD + (size_t)(c0+i)*ldD + (r0+tx)] = t[tx][i];
  }
}

// ---------------- wsT_all[l][d][h] = sum_n Wo[l][n*64+h][d] ----------------
__global__ __launch_bounds__(256) void k_wsumT(const void* __restrict__ Wo,
                                               bf16* __restrict__ wsT,
                                               const int* __restrict__ flagp){
  int i = blockIdx.x*256 + threadIdx.x;
  if(i >= LL*64*512) return;
  int l = i >> 15, j = i & 32767, hh = j>>9, d = j&511;
  size_t loff = (size_t)l*512*512;
  bool isf = *flagp;
  float a = 0.f;
  #pragma unroll
  for(int n=0;n<8;++n){
    size_t idx = loff + (size_t)(n*64+hh)*512 + d;
    a += isf ? ((const float*)Wo)[idx] : cvt(((const bf16*)Wo)[idx]);
  }
  wsT[(size_t)l*32768 + d*64 + hh] = (bf16)a;
}

// ---------------- embed + positional encoding ----------------
__global__ __launch_bounds__(256) void k_embed(const int* __restrict__ idx,
                                               const void* __restrict__ emb,
                                               float* __restrict__ h,
                                               const int* __restrict__ flagp){
  int r = blockIdx.x;
  int t = r & (TT-1);
  int tok = idx[r];
  bool isf = *flagp;
  for(int d = threadIdx.x; d < DD; d += 256){
    int p = d >> 1;
    float ang = (float)t * powf(10000.f, -(float)p * (1.f/128.f));
    float pe = (d & 1) ? cosf(ang) : sinf(ang);
    size_t off = (size_t)tok*DD + d;
    float ev = isf ? ((const float*)emb)[off] : cvt(((const bf16*)emb)[off]);
    h[(size_t)r*DD + d] = 2.f*ev + pe;
  }
}

// ---------------- LayerNorm ----------------
__global__ __launch_bounds__(256) void k_ln(const float* __restrict__ x,
                                            const bf16* __restrict__ g,
                                            const bf16* __restrict__ b,
                                            bf16* __restrict__ y){
  int r = blockIdx.x;
  int tid = threadIdx.x;
  const float* xr = x + (size_t)r*DD;
  float v0 = xr[tid], v1 = xr[tid+256];
  float s = v0+v1, s2 = v0*v0 + v1*v1;
  for(int o=32;o;o>>=1){ s += __shfl_down(s,o); s2 += __shfl_down(s2,o); }
  __shared__ float red[8];
  int wv = tid>>6, ln = tid&63;
  if(ln==0){ red[wv]=s; red[4+wv]=s2; }
  __syncthreads();
  float a  = red[0]+red[1]+red[2]+red[3];
  float a2 = red[4]+red[5]+red[6]+red[7];
  float m  = a*(1.f/DD);
  float var = a2*(1.f/DD) - m*m;
  float inv = rsqrtf(var + 1e-5f);
  y[(size_t)r*DD+tid]     = (bf16)((v0-m)*inv*cvt(g[tid])     + cvt(b[tid]));
  y[(size_t)r*DD+tid+256] = (bf16)((v1-m)*inv*cvt(g[tid+256]) + cvt(b[tid+256]));
}

__global__ __launch_bounds__(256) void k_f2b(const float* __restrict__ x, bf16* __restrict__ o, int n){
  int i = blockIdx.x*256 + threadIdx.x;
  if(i < n) o[i] = (bf16)x[i];
}

// =====================  MFMA GEMM (unchanged)  =====================
template<int BM,int BN,int WM,int WN,int CMODE,bool RELU,bool RESID>
__global__ __launch_bounds__(256) void mm(const bf16* __restrict__ A,
                                          const bf16* __restrict__ Bt,
                                          void* __restrict__ Cv,
                                          const bf16* __restrict__ bias,
                                          int M, int N, int K,
                                          long long sA, long long sB, long long sC, int sBias,
                                          int gx,
                                          const int* __restrict__ flagp){
  constexpr int BK  = 64;
  constexpr int FM  = BM/(WM*16);
  constexpr int FN  = BN/(WN*16);
  constexpr int S   = (BM+BN)*BK;
  constexpr int CAW = (BM*BK/512)/4;
  constexpr int CBW = (BN*BK/512)/4;
  __shared__ bf16 lds[2*S];
  int nwg = gridDim.x, bid = blockIdx.x;
  int q = nwg>>3, rr = nwg&7, xcd = bid&7, ii = bid>>3;
  int wg = (xcd<rr ? xcd*(q+1) : rr*(q+1)+(xcd-rr)*q) + ii;
  int bx = wg % gx, by = wg / gx;
  int z = blockIdx.z;
  A  += (size_t)z*sA;
  Bt += (size_t)z*sB;
  if(bias) bias += (size_t)z*sBias;
  int tid = threadIdx.x, lane = tid&63, w = tid>>6;
  int m0 = by*BM, n0 = bx*BN;
  int wrow = (w/WN)*(FM*16), wcol = (w%WN)*(FN*16);
  int l15 = lane&15, l4 = lane>>4;
  int lrow = lane>>3, lgr = lane&7;
  int nk = K/BK;
  auto stage = [&](int kt, int buf){
    bf16* Ab = lds + buf*S;
    bf16* Bb = Ab + BM*BK;
    const bf16* gA = A + (size_t)m0*K + kt*BK;
    const bf16* gB = Bt + (size_t)n0*K + kt*BK;
    #pragma unroll
    for(int i=0;i<CAW;++i){
      int chunk = w*CAW + i;
      int row = chunk*8 + lrow;
      gl16(gA + (size_t)row*K + ((lgr ^ (row&7))*8), Ab + chunk*512);
    }
    #pragma unroll
    for(int i=0;i<CBW;++i){
      int chunk = w*CBW + i;
      int row = chunk*8 + lrow;
      gl16(gB + (size_t)row*K + ((lgr ^ (row&7))*8), Bb + chunk*512);
    }
  };
  f4 acc[FM][FN] = {};
  stage(0, 0);
  __syncthreads();
  for(int kt=0; kt<nk; ++kt){
    int cur = kt & 1;
    if(kt+1 < nk) stage(kt+1, cur^1);
    const bf16* Ab = lds + cur*S;
    const bf16* Bb = Ab + BM*BK;
    #pragma unroll
    for(int g=0; g<2; ++g){
      bf8s af[FM], bfv[FN];
      #pragma unroll
      for(int i=0;i<FM;++i){
        int r = wrow + i*16 + l15;
        af[i] = *(const bf8s*)(Ab + r*BK + (((g*4+l4) ^ (r&7))*8));
      }
      #pragma unroll
      for(int j=0;j<FN;++j){
        int r = wcol + j*16 + l15;
        bfv[j] = *(const bf8s*)(Bb + r*BK + (((g*4+l4) ^ (r&7))*8));
      }
      #pragma unroll
      for(int i=0;i<FM;++i)
        #pragma unroll
        for(int j=0;j<FN;++j)
          acc[i][j] = __builtin_amdgcn_mfma_f32_16x16x32_bf16(af[i], bfv[j], acc[i][j], 0,0,0);
    }
    __syncthreads();
  }
  bool f32o = (CMODE==2) ? (*flagp != 0) : (CMODE==1);
  #pragma unroll
  for(int i=0;i<FM;++i){
    #pragma unroll
    for(int j=0;j<FN;++j){
      int col = n0 + wcol + j*16 + l15;
      float bv = bias ? cvt(bias[col]) : 0.f;
      #pragma unroll
      for(int q2=0;q2<4;++q2){
        int row = m0 + wrow + i*16 + l4*4 + q2;
        size_t off = (size_t)z*sC + (size_t)row*N + col;
        float v = acc[i][j][q2] + bv;
        if(RESID) v += ((const float*)Cv)[off];
        if(RELU)  v = fmaxf(v, 0.f);
        if(CMODE==0)      ((bf16*)Cv)[off] = (bf16)v;
        else if(CMODE==1) ((float*)Cv)[off] = v;
        else { if(f32o) ((float*)Cv)[off] = v; else ((bf16*)Cv)[off] = (bf16)v; }
      }
    }
  }
}

// =====================  FUSED ATTENTION v2  =====================
// Block = (ti16, b): 16 q-rows, 128 threads = 2 waves splitting s-tiles by parity.
// Grid 32x16 = 512 blocks (2 blocks/CU co-resident; ~19 KB LDS).
// pass1: S' = (Q@K^T + qrel)*scale (MFMA) -> bf16 LDS, max tracked IN-REGISTER.
// pass2: e = exp(S'-mx) over own cols only (unnormalized), sum in-register,
//        diagonal e -> bucket array. 1/sum folded into the PV epilogue
//        (softmax is linear in e). am[0] = sum - sum(am[1..16]).
__global__ __launch_bounds__(128) void k_attn_fused(const bf16* __restrict__ Q,
                                                    const bf16* __restrict__ K,
                                                    const bf16* __restrict__ VbT,
                                                    const bf16* __restrict__ rel,  // [33][64]
                                                    bf16* __restrict__ vals){
  int ti = blockIdx.x, b = blockIdx.y;
  int t0 = ti*16;
  int tid = threadIdx.x, lane = tid & 63, wc = tid >> 6;   // wc = s-tile parity
  int l15 = lane & 15, l4 = lane >> 4;
  __shared__ bf16  Plds[16][520];
  __shared__ float qrs[16][17];
  __shared__ float amlds[16][17];
  __shared__ float redmx[2][16];
  __shared__ float redsum[2][16];
  int nj = ti + 1;                    // 16-col s-tiles (causal)
  int KC = (nj*16 + 31) >> 5;         // 32-wide PV k-chunks

  const bf16* Qb = Q + ((size_t)b*512 + t0)*64;
  const bf16* Kb = K + (size_t)b*512*64;
  const bf16* Vb = VbT + (size_t)b*64*512;

  // zero bucket array; zero trailing Plds tile if nj odd (PV reads KC*32 cols)
  for(int i=tid; i<16*17; i+=128) ((float*)amlds)[i] = 0.f;
  if(nj & 1){
    int r = tid>>3, c = tid&7;
    ((unsigned int*)&Plds[r][nj*16])[c] = 0u;
  }

  // Q fragments (16 rows, both waves load the same)
  bf8s af0 = *(const bf8s*)(Qb + (size_t)l15*64 + l4*8);
  bf8s af1 = *(const bf8s*)(Qb + (size_t)l15*64 + 32 + l4*8);

  // qrel: wave wc computes m-tile wc (only m<17 kept)
  {
    f4 qa = {};
    bf8s r0 = *(const bf8s*)(rel + (size_t)(wc*16+l15)*64 + l4*8);
    bf8s r1 = *(const bf8s*)(rel + (size_t)(wc*16+l15)*64 + 32 + l4*8);
    qa = __builtin_amdgcn_mfma_f32_16x16x32_bf16(af0, r0, qa, 0,0,0);
    qa = __builtin_amdgcn_mfma_f32_16x16x32_bf16(af1, r1, qa, 0,0,0);
    int m = wc*16 + l15;
    if(m < 17){
      #pragma unroll
      for(int q=0;q<4;++q) qrs[l4*4+q][m] = qa[q];
    }
  }
  __syncthreads();

  // pass1: QK^T + bias + scale, bf16 store, in-register max
  float mx4[4] = {-INFINITY,-INFINITY,-INFINITY,-INFINITY};
  for(int j=wc; j<nj; j+=2){
    f4 sa = {};
    const bf16* kr = Kb + (size_t)(j*16+l15)*64;
    bf8s k0 = *(const bf8s*)(kr + l4*8);
    bf8s k1 = *(const bf8s*)(kr + 32 + l4*8);
    sa = __builtin_amdgcn_mfma_f32_16x16x32_bf16(af0, k0, sa, 0,0,0);
    sa = __builtin_amdgcn_mfma_f32_16x16x32_bf16(af1, k1, sa, 0,0,0);
    int s = j*16 + l15;
    #pragma unroll
    for(int q=0;q<4;++q){
      int row = l4*4+q, t = t0+row;
      float sp = -1e30f;
      if(s <= t){
        int m = s - t + 16; m = m < 0 ? 0 : m;
        sp = (sa[q] + qrs[row][m])*0.125f;
        mx4[q] = fmaxf(mx4[q], sp);
      }
      Plds[row][s] = (bf16)sp;
    }
  }
  #pragma unroll
  for(int q=0;q<4;++q){
    float m = mx4[q];
    m = fmaxf(m, __shfl_xor(m,1)); m = fmaxf(m, __shfl_xor(m,2));
    m = fmaxf(m, __shfl_xor(m,4)); m = fmaxf(m, __shfl_xor(m,8));
    mx4[q] = m;
  }
  if(l15==0){
    #pragma unroll
    for(int q=0;q<4;++q) redmx[wc][l4*4+q] = mx4[q];
  }
  __syncthreads();

  // pass2: e = exp(S'-mx) (unnormalized), sum, diagonal buckets
  float mxg[4], sum4[4] = {0.f,0.f,0.f,0.f};
  #pragma unroll
  for(int q=0;q<4;++q) mxg[q] = fmaxf(redmx[0][l4*4+q], redmx[1][l4*4+q]);
  for(int j=wc; j<nj; j+=2){
    int s = j*16 + l15;
    #pragma unroll
    for(int q=0;q<4;++q){
      int row = l4*4+q, t = t0+row;
      float e = expf(cvt(Plds[row][s]) - mxg[q]);   // masked: exp(-1e30-mx)=0
      Plds[row][s] = (bf16)e;
      sum4[q] += e;
      int m = s - t + 16;
      if(m >= 1 && m <= 16) amlds[row][m] = e;      // unique owner
    }
  }
  #pragma unroll
  for(int q=0;q<4;++q){
    float s = sum4[q];
    s += __shfl_xor(s,1); s += __shfl_xor(s,2);
    s += __shfl_xor(s,4); s += __shfl_xor(s,8);
    sum4[q] = s;
  }
  if(l15==0){
    #pragma unroll
    for(int q=0;q<4;++q) redsum[wc][l4*4+q] = sum4[q];
  }
  __syncthreads();

  // PV: wave wc owns h-tiles {2wc, 2wc+1}; A = e rows from Plds, B = V^T global
  f4 pacc[2] = {{0,0,0,0},{0,0,0,0}};
  for(int ks=0; ks<KC; ++ks){
    bf8s ap = *(const bf8s*)(&Plds[l15][ks*32 + l4*8]);
    #pragma unroll
    for(int jj=0;jj<2;++jj){
      int hb = (wc*2+jj)*16 + l15;
      bf8s bv = *(const bf8s*)(Vb + (size_t)hb*512 + ks*32 + l4*8);
      pacc[jj] = __builtin_amdgcn_mfma_f32_16x16x32_bf16(ap, bv, pacc[jj], 0,0,0);
    }
  }
  // epilogue: v = (pacc + sum_{m=1..16} am[m]*rel[m][h] + am0*rel[0][h]) / sum
  #pragma unroll
  for(int q=0;q<4;++q){
    int row = l4*4+q;
    float sum = redsum[0][row] + redsum[1][row];
    float rs = 1.f/sum;
    float a[16];
    float amsum = 0.f;
    #pragma unroll
    for(int m=1;m<=16;++m){ a[m-1] = amlds[row][m]; amsum += a[m-1]; }
    float am0 = sum - amsum;
    #pragma unroll
    for(int jj=0;jj<2;++jj){
      int h = (wc*2+jj)*16 + l15;
      float acc = pacc[jj][q] + am0*cvt(rel[h]);
      #pragma unroll
      for(int m=1;m<=16;++m) acc += a[m-1]*cvt(rel[m*64 + h]);
      vals[((size_t)b*512 + t0 + row)*64 + h] = (bf16)(acc*rs);
    }
  }
}

extern "C" void kernel_launch(void* const* d_in, const int* in_sizes, int n_in,
                              void* d_out, int out_size, void* d_ws, size_t ws_size,
                              hipStream_t stream){
  const int* idx = (const int*)d_in[0];

  char* p = (char*)d_ws;
  auto alloc = [&](size_t bytes)->char*{ char* r = p; p += (bytes + 255) & ~(size_t)255; return r; };

  int*  flag  = (int*)alloc(4);
  bf16* rel_b = (bf16*)alloc(12672*2);
  bf16* bo_b  = (bf16*)alloc(3072*2);
  bf16* g1_b  = (bf16*)alloc(3072*2);
  bf16* be1_b = (bf16*)alloc(3072*2);
  bf16* g2_b  = (bf16*)alloc(3072*2);
  bf16* be2_b = (bf16*)alloc(3072*2);
  bf16* b1_b  = (bf16*)alloc(12288*2);
  bf16* b2_b  = (bf16*)alloc(3072*2);
  bf16* bout_b= (bf16*)alloc(2048*2);
  bf16* bqkv  = (bf16*)alloc(LL*192*2);
  bf16* WqkvT = (bf16*)alloc((size_t)LL*3*64*512*2);    // [L][3][64][512]
  bf16* W1T   = (bf16*)alloc((size_t)LL*2048*512*2);    // [L][2048][512]
  bf16* W2T   = (bf16*)alloc((size_t)LL*512*2048*2);    // [L][512][2048]
  bf16* WoutT = (bf16*)alloc((size_t)2048*512*2);       // [2048][512]
  bf16* wsT_all=(bf16*)alloc((size_t)LL*512*64*2);      // [L][512][64]
  float* h    = (float*)alloc((size_t)BT*DD*4);         // 16 MB
  bf16*  y    = (bf16*) alloc((size_t)BT*DD*2);         //  8 MB
  bf16*  hb   = y;                                      // f2b output (y dead by then)
  bf16*  QKV  = (bf16*) alloc((size_t)3*BT*64*2);       // Q|K|V contiguous
  bf16*  vals = (bf16*) alloc((size_t)BT*64*2);
  bf16*  VbT  = (bf16*) alloc((size_t)BB*64*512*2);     // [16][64][512]
  bf16*  mid  = (bf16*)d_out;                           // FFN scratch in d_out
  bf16*  Qb = QKV, *Kb = QKV + (size_t)BT*64;

  // ---- setup ----
  k_flag<<<1,64,0,stream>>>(d_in[11], flag);
  k_cvt<<<(12672+255)/256,256,0,stream>>>(d_in[8],  rel_b, 12672, flag);
  k_cvt<<<(3072+255)/256,256,0,stream>>>(d_in[10], bo_b,  3072, flag);
  k_cvt<<<(3072+255)/256,256,0,stream>>>(d_in[11], g1_b,  3072, flag);
  k_cvt<<<(3072+255)/256,256,0,stream>>>(d_in[12], be1_b, 3072, flag);
  k_cvt<<<(3072+255)/256,256,0,stream>>>(d_in[13], g2_b,  3072, flag);
  k_cvt<<<(3072+255)/256,256,0,stream>>>(d_in[14], be2_b, 3072, flag);
  k_cvt<<<(12288+255)/256,256,0,stream>>>(d_in[16], b1_b, 12288, flag);
  k_cvt<<<(3072+255)/256,256,0,stream>>>(d_in[18], b2_b,  3072, flag);
  k_cvt<<<(2048+255)/256,256,0,stream>>>(d_in[20], bout_b, 2048, flag);
  k_packb<<<(LL*192+255)/256,256,0,stream>>>(d_in[3], d_in[5], d_in[7], bqkv, flag);
  k_tr<<<dim3(2,16,LL),256,0,stream>>>(d_in[2], WqkvT,            512, 64, 512*64, 3*64*512, 512, flag);
  k_tr<<<dim3(2,16,LL),256,0,stream>>>(d_in[4], WqkvT + 64*512,   512, 64, 512*64, 3*64*512, 512, flag);
  k_tr<<<dim3(2,16,LL),256,0,stream>>>(d_in[6], WqkvT + 2*64*512, 512, 64, 512*64, 3*64*512, 512, flag);
  k_tr<<<dim3(64,16,LL),256,0,stream>>>(d_in[15], W1T, 512, 2048, 512*2048, 2048*512, 512, flag);
  k_tr<<<dim3(16,64,LL),256,0,stream>>>(d_in[17], W2T, 2048, 512, 2048*512, 512*2048, 2048, flag);
  k_tr<<<dim3(64,16,1),256,0,stream>>>(d_in[19], WoutT, 512, 2048, 0, 0, 512, flag);
  k_wsumT<<<(LL*32768+255)/256,256,0,stream>>>(d_in[9], wsT_all, flag);

  k_embed<<<BT,256,0,stream>>>(idx, d_in[1], h, flag);

  for(int l=0; l<LL; ++l){
    k_ln<<<BT,256,0,stream>>>(h, g1_b+l*DD, be1_b+l*DD, y);
    // QKV: batched z=3, N=64
    mm<128,64,4,1,0,false,false><<<dim3(64,1,3),256,0,stream>>>(
        y, WqkvT + (size_t)l*3*64*512, QKV, bqkv + l*192,
        BT, 64, 512, 0, 64*512, (long long)BT*64, 64, 1, nullptr);
    // V [16][512][64] -> VbT [16][64][512]
    k_tr<<<dim3(2,16,BB),256,0,stream>>>(QKV + (size_t)2*BT*64, VbT, 512, 64, 512*64, 64*512, 512, nullptr);
    // fused scores+softmax+bucket+PV+relbias (v2: 512 blocks, reg softmax)
    k_attn_fused<<<dim3(32,16),128,0,stream>>>(Qb, Kb, VbT, rel_b + l*33*64, vals);
    // h += vals @ WsumT + bo
    mm<128,64,4,1,1,false,true><<<dim3(512,1,1),256,0,stream>>>(
        vals, wsT_all + (size_t)l*32768, h, bo_b + l*DD, BT, 512, 64, 0,0,0,0, 8, nullptr);
    k_ln<<<BT,256,0,stream>>>(h, g2_b+l*DD, be2_b+l*DD, y);
    // mid = relu(y @ W1 + b1)   (bf16, d_out scratch)
    mm<128,64,4,1,0,true,false><<<dim3(2048,1,1),256,0,stream>>>(
        y, W1T + (size_t)l*2048*512, mid, b1_b + l*FF, BT, 2048, 512, 0,0,0,0, 32, nullptr);
    // h += mid @ W2 + b2
    mm<128,64,4,1,1,false,true><<<dim3(512,1,1),256,0,stream>>>(
        mid, W2T + (size_t)l*512*2048, h, b2_b + l*DD, BT, 512, 2048, 0,0,0,0, 8, nullptr);
  }
  k_f2b<<<(BT*DD+255)/256,256,0,stream>>>(h, hb, BT*DD);
  // out = hb @ Wout + bout (dual store per flag; fully rewrites d_out)
  mm<128,64,4,1,2,false,false><<<dim3(2048,1,1),256,0,stream>>>(
      hb, WoutT, d_out, bout_b, BT, 2048, 512, 0,0,0,0, 32, flag);
}

// Round 11
// 929.171 us; speedup vs baseline: 1.2343x; 1.0124x over previous
//
#include <hip/hip_runtime.h>
#include <hip/hip_bf16.h>
#include <math.h>

#define BB 16
#define TT 512
#define VV 2048
#define DD 512
#define HDD 64
#define LL 6
#define FF 2048
#define BT 8192   // B*T

typedef __hip_bfloat16 bf16;
typedef __attribute__((ext_vector_type(8))) short bf8s;   // 8 bf16 (4 VGPRs)
typedef __attribute__((ext_vector_type(4))) float f4;     // C/D frag

__device__ __forceinline__ float cvt(float x){ return x; }
__device__ __forceinline__ float cvt(bf16 x){ return __bfloat162float(x); }

// async global->LDS, 16B per lane. LDS dest wave-uniform base (+lane*16 by HW).
__device__ __forceinline__ void gl16(const bf16* g, bf16* l){
  __builtin_amdgcn_global_load_lds(
      (const __attribute__((address_space(1))) void*)g,
      (__attribute__((address_space(3))) void*)l,
      16, 0, 0);
}

// ---------------- dtype flag ----------------
__global__ void k_flag(const void* g1, int* flagp){
  if(threadIdx.x==0 && blockIdx.x==0){
    const unsigned short* u = (const unsigned short*)g1;
    *flagp = (u[0] == 0) ? 1 : 0;   // 1 = inputs f32, 0 = bf16
  }
}

// ---------------- one-shot convert of all small tensors + QKV bias pack ----------------
__global__ __launch_bounds__(256) void k_cvt_all(
    const void* rel, const void* bo, const void* g1, const void* be1,
    const void* g2, const void* be2, const void* b1, const void* b2,
    const void* bout, const void* bq, const void* bk, const void* bv,
    bf16* d_rel, bf16* d_bo, bf16* d_g1, bf16* d_be1,
    bf16* d_g2, bf16* d_be2, bf16* d_b1, bf16* d_b2,
    bf16* d_bout, bf16* d_bqkv, const int* __restrict__ flagp){
  int i = blockIdx.x*256 + threadIdx.x;
  bool isf = *flagp;
  auto ld = [&](const void* s, int k)->float{
    return isf ? ((const float*)s)[k] : cvt(((const bf16*)s)[k]);
  };
  if(i < 12672){ d_rel[i] = (bf16)ld(rel, i); return; } i -= 12672;
  if(i < 3072){ d_bo[i]  = (bf16)ld(bo, i);  return; } i -= 3072;
  if(i < 3072){ d_g1[i]  = (bf16)ld(g1, i);  return; } i -= 3072;
  if(i < 3072){ d_be1[i] = (bf16)ld(be1, i); return; } i -= 3072;
  if(i < 3072){ d_g2[i]  = (bf16)ld(g2, i);  return; } i -= 3072;
  if(i < 3072){ d_be2[i] = (bf16)ld(be2, i); return; } i -= 3072;
  if(i < 12288){ d_b1[i] = (bf16)ld(b1, i);  return; } i -= 12288;
  if(i < 3072){ d_b2[i]  = (bf16)ld(b2, i);  return; } i -= 3072;
  if(i < 2048){ d_bout[i]= (bf16)ld(bout, i);return; } i -= 2048;
  if(i < 384){ int l=i>>6, hh=i&63; d_bqkv[l*192 + hh]       = (bf16)ld(bq, i); return; } i -= 384;
  if(i < 384){ int l=i>>6, hh=i&63; d_bqkv[l*192 + 64 + hh]  = (bf16)ld(bk, i); return; } i -= 384;
  if(i < 384){ int l=i>>6, hh=i&63; d_bqkv[l*192 + 128 + hh] = (bf16)ld(bv, i); return; }
}

// ---------------- tiled transpose: src [z][R][C] -> dst [z][C][R(ldD)] bf16 ----------------
__global__ __launch_bounds__(256) void k_tr(const void* __restrict__ src, bf16* __restrict__ dst,
                                            int R, int C, long long sS, long long sD, int ldD,
                                            const int* __restrict__ flagp){
  __shared__ bf16 t[32][33];
  int z = blockIdx.z;
  int c0 = blockIdx.x*32, r0 = blockIdx.y*32;
  int tx = threadIdx.x & 31, ty = threadIdx.x >> 5;
  bool isf = flagp && (*flagp);
  const float* sf = (const float*)src;
  const bf16*  sb = (const bf16*)src;
  for(int i=ty; i<32; i+=8){
    size_t off = (size_t)z*sS + (size_t)(r0+i)*C + (c0+tx);
    float v = isf ? sf[off] : cvt(sb[off]);
    t[i][tx] = (bf16)v;
  }
  __syncthreads();
  for(int i=ty; i<32; i+=8){
    dst[(size_t)z*sD + (size_t)(c0+i)*ldD + (r0+tx)] = t[tx][i];
  }
}

// ---------------- wsT_all[l][d][h] = sum_n Wo[l][n*64+h][d] ----------------
__global__ __launch_bounds__(256) void k_wsumT(const void* __restrict__ Wo,
                                               bf16* __restrict__ wsT,
                                               const int* __restrict__ flagp){
  int i = blockIdx.x*256 + threadIdx.x;
  if(i >= LL*64*512) return;
  int l = i >> 15, j = i & 32767, hh = j>>9, d = j&511;
  size_t loff = (size_t)l*512*512;
  bool isf = *flagp;
  float a = 0.f;
  #pragma unroll
  for(int n=0;n<8;++n){
    size_t idx = loff + (size_t)(n*64+hh)*512 + d;
    a += isf ? ((const float*)Wo)[idx] : cvt(((const bf16*)Wo)[idx]);
  }
  wsT[(size_t)l*32768 + d*64 + hh] = (bf16)a;
}

// ---------------- embed + positional encoding ----------------
__global__ __launch_bounds__(256) void k_embed(const int* __restrict__ idx,
                                               const void* __restrict__ emb,
                                               float* __restrict__ h,
                                               const int* __restrict__ flagp){
  int r = blockIdx.x;
  int t = r & (TT-1);
  int tok = idx[r];
  bool isf = *flagp;
  for(int d = threadIdx.x; d < DD; d += 256){
    int p = d >> 1;
    float ang = (float)t * powf(10000.f, -(float)p * (1.f/128.f));
    float pe = (d & 1) ? cosf(ang) : sinf(ang);
    size_t off = (size_t)tok*DD + d;
    float ev = isf ? ((const float*)emb)[off] : cvt(((const bf16*)emb)[off]);
    h[(size_t)r*DD + d] = 2.f*ev + pe;
  }
}

// ---------------- LayerNorm ----------------
__global__ __launch_bounds__(256) void k_ln(const float* __restrict__ x,
                                            const bf16* __restrict__ g,
                                            const bf16* __restrict__ b,
                                            bf16* __restrict__ y){
  int r = blockIdx.x;
  int tid = threadIdx.x;
  const float* xr = x + (size_t)r*DD;
  float v0 = xr[tid], v1 = xr[tid+256];
  float s = v0+v1, s2 = v0*v0 + v1*v1;
  for(int o=32;o;o>>=1){ s += __shfl_down(s,o); s2 += __shfl_down(s2,o); }
  __shared__ float red[8];
  int wv = tid>>6, ln = tid&63;
  if(ln==0){ red[wv]=s; red[4+wv]=s2; }
  __syncthreads();
  float a  = red[0]+red[1]+red[2]+red[3];
  float a2 = red[4]+red[5]+red[6]+red[7];
  float m  = a*(1.f/DD);
  float var = a2*(1.f/DD) - m*m;
  float inv = rsqrtf(var + 1e-5f);
  y[(size_t)r*DD+tid]     = (bf16)((v0-m)*inv*cvt(g[tid])     + cvt(b[tid]));
  y[(size_t)r*DD+tid+256] = (bf16)((v1-m)*inv*cvt(g[tid+256]) + cvt(b[tid+256]));
}

__global__ __launch_bounds__(256) void k_f2b(const float* __restrict__ x, bf16* __restrict__ o, int n){
  int i = blockIdx.x*256 + threadIdx.x;
  if(i < n) o[i] = (bf16)x[i];
}

// =====================  MFMA GEMM  =====================
// TRV: for z==2 (the V plane of the QKV batch) store C transposed into
// vtr[b][col][t] instead of Cv — fuses the V-transpose into the GEMM.
template<int BM,int BN,int WM,int WN,int CMODE,bool RELU,bool RESID,bool TRV>
__global__ __launch_bounds__(WM*WN*64) void mm(const bf16* __restrict__ A,
                                          const bf16* __restrict__ Bt,
                                          void* __restrict__ Cv,
                                          const bf16* __restrict__ bias,
                                          int M, int N, int K,
                                          long long sA, long long sB, long long sC, int sBias,
                                          int gx,
                                          const int* __restrict__ flagp,
                                          bf16* __restrict__ vtr){
  constexpr int BK  = 64;
  constexpr int NT  = WM*WN*64;          // threads
  constexpr int FM  = BM/(WM*16);
  constexpr int FN  = BN/(WN*16);
  constexpr int S   = (BM+BN)*BK;
  constexpr int CAW = (BM*BK/512)/(NT/64);
  constexpr int CBW = (BN*BK/512)/(NT/64);
  __shared__ bf16 lds[2*S];
  int nwg = gridDim.x, bid = blockIdx.x;
  int q = nwg>>3, rr = nwg&7, xcd = bid&7, ii = bid>>3;
  int wg = (xcd<rr ? xcd*(q+1) : rr*(q+1)+(xcd-rr)*q) + ii;
  int bx = wg % gx, by = wg / gx;
  int z = blockIdx.z;
  A  += (size_t)z*sA;
  Bt += (size_t)z*sB;
  if(bias) bias += (size_t)z*sBias;
  int tid = threadIdx.x, lane = tid&63, w = tid>>6;
  int m0 = by*BM, n0 = bx*BN;
  int wrow = (w/WN)*(FM*16), wcol = (w%WN)*(FN*16);
  int l15 = lane&15, l4 = lane>>4;
  int lrow = lane>>3, lgr = lane&7;
  int nk = K/BK;
  auto stage = [&](int kt, int buf){
    bf16* Ab = lds + buf*S;
    bf16* Bb = Ab + BM*BK;
    const bf16* gA = A + (size_t)m0*K + kt*BK;
    const bf16* gB = Bt + (size_t)n0*K + kt*BK;
    #pragma unroll
    for(int i=0;i<CAW;++i){
      int chunk = w*CAW + i;
      int row = chunk*8 + lrow;
      gl16(gA + (size_t)row*K + ((lgr ^ (row&7))*8), Ab + chunk*512);
    }
    #pragma unroll
    for(int i=0;i<CBW;++i){
      int chunk = w*CBW + i;
      int row = chunk*8 + lrow;
      gl16(gB + (size_t)row*K + ((lgr ^ (row&7))*8), Bb + chunk*512);
    }
  };
  f4 acc[FM][FN] = {};
  stage(0, 0);
  __syncthreads();
  for(int kt=0; kt<nk; ++kt){
    int cur = kt & 1;
    if(kt+1 < nk) stage(kt+1, cur^1);
    const bf16* Ab = lds + cur*S;
    const bf16* Bb = Ab + BM*BK;
    #pragma unroll
    for(int g=0; g<2; ++g){
      bf8s af[FM], bfv[FN];
      #pragma unroll
      for(int i=0;i<FM;++i){
        int r = wrow + i*16 + l15;
        af[i] = *(const bf8s*)(Ab + r*BK + (((g*4+l4) ^ (r&7))*8));
      }
      #pragma unroll
      for(int j=0;j<FN;++j){
        int r = wcol + j*16 + l15;
        bfv[j] = *(const bf8s*)(Bb + r*BK + (((g*4+l4) ^ (r&7))*8));
      }
      #pragma unroll
      for(int i=0;i<FM;++i)
        #pragma unroll
        for(int j=0;j<FN;++j)
          acc[i][j] = __builtin_amdgcn_mfma_f32_16x16x32_bf16(af[i], bfv[j], acc[i][j], 0,0,0);
    }
    __syncthreads();
  }
  bool f32o = (CMODE==2) ? (*flagp != 0) : (CMODE==1);
  bool trv = TRV && (z == 2);
  #pragma unroll
  for(int i=0;i<FM;++i){
    #pragma unroll
    for(int j=0;j<FN;++j){
      int col = n0 + wcol + j*16 + l15;
      float bv = bias ? cvt(bias[col]) : 0.f;
      #pragma unroll
      for(int q2=0;q2<4;++q2){
        int row = m0 + wrow + i*16 + l4*4 + q2;
        float v = acc[i][j][q2] + bv;
        if(trv){
          int b = row >> 9, t = row & 511;
          vtr[(size_t)b*(64*512) + (size_t)col*512 + t] = (bf16)v;
          continue;
        }
        size_t off = (size_t)z*sC + (size_t)row*N + col;
        if(RESID) v += ((const float*)Cv)[off];
        if(RELU)  v = fmaxf(v, 0.f);
        if(CMODE==0)      ((bf16*)Cv)[off] = (bf16)v;
        else if(CMODE==1) ((float*)Cv)[off] = v;
        else { if(f32o) ((float*)Cv)[off] = v; else ((bf16*)Cv)[off] = (bf16)v; }
      }
    }
  }
}

// =====================  FUSED ATTENTION v2 (unchanged from round 10)  =====================
__global__ __launch_bounds__(128) void k_attn_fused(const bf16* __restrict__ Q,
                                                    const bf16* __restrict__ K,
                                                    const bf16* __restrict__ VbT,
                                                    const bf16* __restrict__ rel,  // [33][64]
                                                    bf16* __restrict__ vals){
  int ti = blockIdx.x, b = blockIdx.y;
  int t0 = ti*16;
  int tid = threadIdx.x, lane = tid & 63, wc = tid >> 6;   // wc = s-tile parity
  int l15 = lane & 15, l4 = lane >> 4;
  __shared__ bf16  Plds[16][520];
  __shared__ float qrs[16][17];
  __shared__ float amlds[16][17];
  __shared__ float redmx[2][16];
  __shared__ float redsum[2][16];
  int nj = ti + 1;                    // 16-col s-tiles (causal)
  int KC = (nj*16 + 31) >> 5;         // 32-wide PV k-chunks

  const bf16* Qb = Q + ((size_t)b*512 + t0)*64;
  const bf16* Kb = K + (size_t)b*512*64;
  const bf16* Vb = VbT + (size_t)b*64*512;

  for(int i=tid; i<16*17; i+=128) ((float*)amlds)[i] = 0.f;
  if(nj & 1){
    int r = tid>>3, c = tid&7;
    ((unsigned int*)&Plds[r][nj*16])[c] = 0u;
  }

  bf8s af0 = *(const bf8s*)(Qb + (size_t)l15*64 + l4*8);
  bf8s af1 = *(const bf8s*)(Qb + (size_t)l15*64 + 32 + l4*8);

  {
    f4 qa = {};
    bf8s r0 = *(const bf8s*)(rel + (size_t)(wc*16+l15)*64 + l4*8);
    bf8s r1 = *(const bf8s*)(rel + (size_t)(wc*16+l15)*64 + 32 + l4*8);
    qa = __builtin_amdgcn_mfma_f32_16x16x32_bf16(af0, r0, qa, 0,0,0);
    qa = __builtin_amdgcn_mfma_f32_16x16x32_bf16(af1, r1, qa, 0,0,0);
    int m = wc*16 + l15;
    if(m < 17){
      #pragma unroll
      for(int q=0;q<4;++q) qrs[l4*4+q][m] = qa[q];
    }
  }
  __syncthreads();

  float mx4[4] = {-INFINITY,-INFINITY,-INFINITY,-INFINITY};
  for(int j=wc; j<nj; j+=2){
    f4 sa = {};
    const bf16* kr = Kb + (size_t)(j*16+l15)*64;
    bf8s k0 = *(const bf8s*)(kr + l4*8);
    bf8s k1 = *(const bf8s*)(kr + 32 + l4*8);
    sa = __builtin_amdgcn_mfma_f32_16x16x32_bf16(af0, k0, sa, 0,0,0);
    sa = __builtin_amdgcn_mfma_f32_16x16x32_bf16(af1, k1, sa, 0,0,0);
    int s = j*16 + l15;
    #pragma unroll
    for(int q=0;q<4;++q){
      int row = l4*4+q, t = t0+row;
      float sp = -1e30f;
      if(s <= t){
        int m = s - t + 16; m = m < 0 ? 0 : m;
        sp = (sa[q] + qrs[row][m])*0.125f;
        mx4[q] = fmaxf(mx4[q], sp);
      }
      Plds[row][s] = (bf16)sp;
    }
  }
  #pragma unroll
  for(int q=0;q<4;++q){
    float m = mx4[q];
    m = fmaxf(m, __shfl_xor(m,1)); m = fmaxf(m, __shfl_xor(m,2));
    m = fmaxf(m, __shfl_xor(m,4)); m = fmaxf(m, __shfl_xor(m,8));
    mx4[q] = m;
  }
  if(l15==0){
    #pragma unroll
    for(int q=0;q<4;++q) redmx[wc][l4*4+q] = mx4[q];
  }
  __syncthreads();

  float mxg[4], sum4[4] = {0.f,0.f,0.f,0.f};
  #pragma unroll
  for(int q=0;q<4;++q) mxg[q] = fmaxf(redmx[0][l4*4+q], redmx[1][l4*4+q]);
  for(int j=wc; j<nj; j+=2){
    int s = j*16 + l15;
    #pragma unroll
    for(int q=0;q<4;++q){
      int row = l4*4+q, t = t0+row;
      float e = expf(cvt(Plds[row][s]) - mxg[q]);
      Plds[row][s] = (bf16)e;
      sum4[q] += e;
      int m = s - t + 16;
      if(m >= 1 && m <= 16) amlds[row][m] = e;
    }
  }
  #pragma unroll
  for(int q=0;q<4;++q){
    float s = sum4[q];
    s += __shfl_xor(s,1); s += __shfl_xor(s,2);
    s += __shfl_xor(s,4); s += __shfl_xor(s,8);
    sum4[q] = s;
  }
  if(l15==0){
    #pragma unroll
    for(int q=0;q<4;++q) redsum[wc][l4*4+q] = sum4[q];
  }
  __syncthreads();

  f4 pacc[2] = {{0,0,0,0},{0,0,0,0}};
  for(int ks=0; ks<KC; ++ks){
    bf8s ap = *(const bf8s*)(&Plds[l15][ks*32 + l4*8]);
    #pragma unroll
    for(int jj=0;jj<2;++jj){
      int hb = (wc*2+jj)*16 + l15;
      bf8s bv = *(const bf8s*)(Vb + (size_t)hb*512 + ks*32 + l4*8);
      pacc[jj] = __builtin_amdgcn_mfma_f32_16x16x32_bf16(ap, bv, pacc[jj], 0,0,0);
    }
  }
  #pragma unroll
  for(int q=0;q<4;++q){
    int row = l4*4+q;
    float sum = redsum[0][row] + redsum[1][row];
    float rs = 1.f/sum;
    float a[16];
    float amsum = 0.f;
    #pragma unroll
    for(int m=1;m<=16;++m){ a[m-1] = amlds[row][m]; amsum += a[m-1]; }
    float am0 = sum - amsum;
    #pragma unroll
    for(int jj=0;jj<2;++jj){
      int h = (wc*2+jj)*16 + l15;
      float acc = pacc[jj][q] + am0*cvt(rel[h]);
      #pragma unroll
      for(int m=1;m<=16;++m) acc += a[m-1]*cvt(rel[m*64 + h]);
      vals[((size_t)b*512 + t0 + row)*64 + h] = (bf16)(acc*rs);
    }
  }
}

extern "C" void kernel_launch(void* const* d_in, const int* in_sizes, int n_in,
                              void* d_out, int out_size, void* d_ws, size_t ws_size,
                              hipStream_t stream){
  const int* idx = (const int*)d_in[0];

  char* p = (char*)d_ws;
  auto alloc = [&](size_t bytes)->char*{ char* r = p; p += (bytes + 255) & ~(size_t)255; return r; };

  int*  flag  = (int*)alloc(4);
  bf16* rel_b = (bf16*)alloc(12672*2);
  bf16* bo_b  = (bf16*)alloc(3072*2);
  bf16* g1_b  = (bf16*)alloc(3072*2);
  bf16* be1_b = (bf16*)alloc(3072*2);
  bf16* g2_b  = (bf16*)alloc(3072*2);
  bf16* be2_b = (bf16*)alloc(3072*2);
  bf16* b1_b  = (bf16*)alloc(12288*2);
  bf16* b2_b  = (bf16*)alloc(3072*2);
  bf16* bout_b= (bf16*)alloc(2048*2);
  bf16* bqkv  = (bf16*)alloc(LL*192*2);
  bf16* WqkvT = (bf16*)alloc((size_t)LL*3*64*512*2);    // [L][3][64][512]
  bf16* W1T   = (bf16*)alloc((size_t)LL*2048*512*2);    // [L][2048][512]
  bf16* W2T   = (bf16*)alloc((size_t)LL*512*2048*2);    // [L][512][2048]
  bf16* WoutT = (bf16*)alloc((size_t)2048*512*2);       // [2048][512]
  bf16* wsT_all=(bf16*)alloc((size_t)LL*512*64*2);      // [L][512][64]
  float* h    = (float*)alloc((size_t)BT*DD*4);         // 16 MB
  bf16*  y    = (bf16*) alloc((size_t)BT*DD*2);         //  8 MB
  bf16*  hb   = y;                                      // f2b output (y dead by then)
  bf16*  QKV  = (bf16*) alloc((size_t)3*BT*64*2);       // Q|K|V contiguous
  bf16*  vals = (bf16*) alloc((size_t)BT*64*2);
  bf16*  VbT  = (bf16*) alloc((size_t)BB*64*512*2);     // [16][64][512]
  bf16*  mid  = (bf16*)d_out;                           // FFN scratch in d_out
  bf16*  Qb = QKV, *Kb = QKV + (size_t)BT*64;

  // ---- setup ----
  k_flag<<<1,64,0,stream>>>(d_in[11], flag);
  k_cvt_all<<<(46592+255)/256,256,0,stream>>>(
      d_in[8], d_in[10], d_in[11], d_in[12], d_in[13], d_in[14],
      d_in[16], d_in[18], d_in[20], d_in[3], d_in[5], d_in[7],
      rel_b, bo_b, g1_b, be1_b, g2_b, be2_b, b1_b, b2_b, bout_b, bqkv, flag);
  k_tr<<<dim3(2,16,LL),256,0,stream>>>(d_in[2], WqkvT,            512, 64, 512*64, 3*64*512, 512, flag);
  k_tr<<<dim3(2,16,LL),256,0,stream>>>(d_in[4], WqkvT + 64*512,   512, 64, 512*64, 3*64*512, 512, flag);
  k_tr<<<dim3(2,16,LL),256,0,stream>>>(d_in[6], WqkvT + 2*64*512, 512, 64, 512*64, 3*64*512, 512, flag);
  k_tr<<<dim3(64,16,LL),256,0,stream>>>(d_in[15], W1T, 512, 2048, 512*2048, 2048*512, 512, flag);
  k_tr<<<dim3(16,64,LL),256,0,stream>>>(d_in[17], W2T, 2048, 512, 2048*512, 512*2048, 2048, flag);
  k_tr<<<dim3(64,16,1),256,0,stream>>>(d_in[19], WoutT, 512, 2048, 0, 0, 512, flag);
  k_wsumT<<<(LL*32768+255)/256,256,0,stream>>>(d_in[9], wsT_all, flag);

  k_embed<<<BT,256,0,stream>>>(idx, d_in[1], h, flag);

  for(int l=0; l<LL; ++l){
    k_ln<<<BT,256,0,stream>>>(h, g1_b+l*DD, be1_b+l*DD, y);
    // QKV: batched z=3; V plane (z=2) stored transposed into VbT (TRV)
    mm<128,64,4,1,0,false,false,true><<<dim3(64,1,3),256,0,stream>>>(
        y, WqkvT + (size_t)l*3*64*512, QKV, bqkv + l*192,
        BT, 64, 512, 0, 64*512, (long long)BT*64, 64, 1, nullptr, VbT);
    // fused scores+softmax+bucket+PV+relbias
    k_attn_fused<<<dim3(32,16),128,0,stream>>>(Qb, Kb, VbT, rel_b + l*33*64, vals);
    // h += vals @ WsumT + bo
    mm<128,64,4,1,1,false,true,false><<<dim3(512,1,1),256,0,stream>>>(
        vals, wsT_all + (size_t)l*32768, h, bo_b + l*DD, BT, 512, 64, 0,0,0,0, 8, nullptr, nullptr);
    k_ln<<<BT,256,0,stream>>>(h, g2_b+l*DD, be2_b+l*DD, y);
    // mid = relu(y @ W1 + b1)   (bf16, d_out scratch) — 128x128 tile
    mm<128,128,2,2,0,true,false,false><<<dim3(1024,1,1),256,0,stream>>>(
        y, W1T + (size_t)l*2048*512, mid, b1_b + l*FF, BT, 2048, 512, 0,0,0,0, 16, nullptr, nullptr);
    // h += mid @ W2 + b2
    mm<128,64,4,1,1,false,true,false><<<dim3(512,1,1),256,0,stream>>>(
        mid, W2T + (size_t)l*512*2048, h, b2_b + l*DD, BT, 512, 2048, 0,0,0,0, 8, nullptr, nullptr);
  }
  k_f2b<<<(BT*DD+255)/256,256,0,stream>>>(h, hb, BT*DD);
  // out = hb @ Wout + bout (dual store per flag) — 128x128 tile
  mm<128,128,2,2,2,false,false,false><<<dim3(1024,1,1),256,0,stream>>>(
      hb, WoutT, d_out, bout_b, BT, 2048, 512, 0,0,0,0, 16, flag, nullptr);
}

// Round 12
// 853.775 us; speedup vs baseline: 1.3433x; 1.0883x over previous
//
#include <hip/hip_runtime.h>
#include <hip/hip_bf16.h>
#include <math.h>

#define BB 16
#define TT 512
#define VV 2048
#define DD 512
#define HDD 64
#define LL 6
#define FF 2048
#define BT 8192   // B*T

typedef __hip_bfloat16 bf16;
typedef __attribute__((ext_vector_type(8))) short bf8s;   // 8 bf16 (4 VGPRs)
typedef __attribute__((ext_vector_type(4))) float f4;     // C/D frag

__device__ __forceinline__ float cvt(float x){ return x; }
__device__ __forceinline__ float cvt(bf16 x){ return __bfloat162float(x); }

// async global->LDS, 16B per lane. LDS dest wave-uniform base (+lane*16 by HW).
__device__ __forceinline__ void gl16(const bf16* g, bf16* l){
  __builtin_amdgcn_global_load_lds(
      (const __attribute__((address_space(1))) void*)g,
      (__attribute__((address_space(3))) void*)l,
      16, 0, 0);
}

// ---------------- dtype flag ----------------
__global__ void k_flag(const void* g1, int* flagp){
  if(threadIdx.x==0 && blockIdx.x==0){
    const unsigned short* u = (const unsigned short*)g1;
    *flagp = (u[0] == 0) ? 1 : 0;   // 1 = inputs f32, 0 = bf16
  }
}

// ---------------- one-shot convert of all small tensors + QKV bias pack ----------------
__global__ __launch_bounds__(256) void k_cvt_all(
    const void* rel, const void* bo, const void* g1, const void* be1,
    const void* g2, const void* be2, const void* b1, const void* b2,
    const void* bout, const void* bq, const void* bk, const void* bv,
    bf16* d_rel, bf16* d_bo, bf16* d_g1, bf16* d_be1,
    bf16* d_g2, bf16* d_be2, bf16* d_b1, bf16* d_b2,
    bf16* d_bout, bf16* d_bqkv, const int* __restrict__ flagp){
  int i = blockIdx.x*256 + threadIdx.x;
  bool isf = *flagp;
  auto ld = [&](const void* s, int k)->float{
    return isf ? ((const float*)s)[k] : cvt(((const bf16*)s)[k]);
  };
  if(i < 12672){ d_rel[i] = (bf16)ld(rel, i); return; } i -= 12672;
  if(i < 3072){ d_bo[i]  = (bf16)ld(bo, i);  return; } i -= 3072;
  if(i < 3072){ d_g1[i]  = (bf16)ld(g1, i);  return; } i -= 3072;
  if(i < 3072){ d_be1[i] = (bf16)ld(be1, i); return; } i -= 3072;
  if(i < 3072){ d_g2[i]  = (bf16)ld(g2, i);  return; } i -= 3072;
  if(i < 3072){ d_be2[i] = (bf16)ld(be2, i); return; } i -= 3072;
  if(i < 12288){ d_b1[i] = (bf16)ld(b1, i);  return; } i -= 12288;
  if(i < 3072){ d_b2[i]  = (bf16)ld(b2, i);  return; } i -= 3072;
  if(i < 2048){ d_bout[i]= (bf16)ld(bout, i);return; } i -= 2048;
  if(i < 384){ int l=i>>6, hh=i&63; d_bqkv[l*192 + hh]       = (bf16)ld(bq, i); return; } i -= 384;
  if(i < 384){ int l=i>>6, hh=i&63; d_bqkv[l*192 + 64 + hh]  = (bf16)ld(bk, i); return; } i -= 384;
  if(i < 384){ int l=i>>6, hh=i&63; d_bqkv[l*192 + 128 + hh] = (bf16)ld(bv, i); return; }
}

// ---------------- tiled transpose: src [z][R][C] -> dst [z][C][R(ldD)] bf16 ----------------
__global__ __launch_bounds__(256) void k_tr(const void* __restrict__ src, bf16* __restrict__ dst,
                                            int R, int C, long long sS, long long sD, int ldD,
                                            const int* __restrict__ flagp){
  __shared__ bf16 t[32][33];
  int z = blockIdx.z;
  int c0 = blockIdx.x*32, r0 = blockIdx.y*32;
  int tx = threadIdx.x & 31, ty = threadIdx.x >> 5;
  bool isf = flagp && (*flagp);
  const float* sf = (const float*)src;
  const bf16*  sb = (const bf16*)src;
  for(int i=ty; i<32; i+=8){
    size_t off = (size_t)z*sS + (size_t)(r0+i)*C + (c0+tx);
    float v = isf ? sf[off] : cvt(sb[off]);
    t[i][tx] = (bf16)v;
  }
  __syncthreads();
  for(int i=ty; i<32; i+=8){
    dst[(size_t)z*sD + (size_t)(c0+i)*ldD + (r0+tx)] = t[tx][i];
  }
}

// ---------------- wsT_all[l][d][h] = sum_n Wo[l][n*64+h][d] ----------------
__global__ __launch_bounds__(256) void k_wsumT(const void* __restrict__ Wo,
                                               bf16* __restrict__ wsT,
                                               const int* __restrict__ flagp){
  int i = blockIdx.x*256 + threadIdx.x;
  if(i >= LL*64*512) return;
  int l = i >> 15, j = i & 32767, hh = j>>9, d = j&511;
  size_t loff = (size_t)l*512*512;
  bool isf = *flagp;
  float a = 0.f;
  #pragma unroll
  for(int n=0;n<8;++n){
    size_t idx = loff + (size_t)(n*64+hh)*512 + d;
    a += isf ? ((const float*)Wo)[idx] : cvt(((const bf16*)Wo)[idx]);
  }
  wsT[(size_t)l*32768 + d*64 + hh] = (bf16)a;
}

// ---------------- embed + positional encoding ----------------
__global__ __launch_bounds__(256) void k_embed(const int* __restrict__ idx,
                                               const void* __restrict__ emb,
                                               float* __restrict__ h,
                                               const int* __restrict__ flagp){
  int r = blockIdx.x;
  int t = r & (TT-1);
  int tok = idx[r];
  bool isf = *flagp;
  for(int d = threadIdx.x; d < DD; d += 256){
    int p = d >> 1;
    float ang = (float)t * powf(10000.f, -(float)p * (1.f/128.f));
    float pe = (d & 1) ? cosf(ang) : sinf(ang);
    size_t off = (size_t)tok*DD + d;
    float ev = isf ? ((const float*)emb)[off] : cvt(((const bf16*)emb)[off]);
    h[(size_t)r*DD + d] = 2.f*ev + pe;
  }
}

// ---------------- LayerNorm ----------------
__global__ __launch_bounds__(256) void k_ln(const float* __restrict__ x,
                                            const bf16* __restrict__ g,
                                            const bf16* __restrict__ b,
                                            bf16* __restrict__ y){
  int r = blockIdx.x;
  int tid = threadIdx.x;
  const float* xr = x + (size_t)r*DD;
  float v0 = xr[tid], v1 = xr[tid+256];
  float s = v0+v1, s2 = v0*v0 + v1*v1;
  for(int o=32;o;o>>=1){ s += __shfl_down(s,o); s2 += __shfl_down(s2,o); }
  __shared__ float red[8];
  int wv = tid>>6, ln = tid&63;
  if(ln==0){ red[wv]=s; red[4+wv]=s2; }
  __syncthreads();
  float a  = red[0]+red[1]+red[2]+red[3];
  float a2 = red[4]+red[5]+red[6]+red[7];
  float m  = a*(1.f/DD);
  float var = a2*(1.f/DD) - m*m;
  float inv = rsqrtf(var + 1e-5f);
  y[(size_t)r*DD+tid]     = (bf16)((v0-m)*inv*cvt(g[tid])     + cvt(b[tid]));
  y[(size_t)r*DD+tid+256] = (bf16)((v1-m)*inv*cvt(g[tid+256]) + cvt(b[tid+256]));
}

__global__ __launch_bounds__(256) void k_f2b(const float* __restrict__ x, bf16* __restrict__ o, int n){
  int i = blockIdx.x*256 + threadIdx.x;
  if(i < n) o[i] = (bf16)x[i];
}

// =====================  MFMA GEMM  =====================
template<int BM,int BN,int WM,int WN,int CMODE,bool RELU,bool RESID,bool TRV>
__global__ __launch_bounds__(WM*WN*64) void mm(const bf16* __restrict__ A,
                                          const bf16* __restrict__ Bt,
                                          void* __restrict__ Cv,
                                          const bf16* __restrict__ bias,
                                          int M, int N, int K,
                                          long long sA, long long sB, long long sC, int sBias,
                                          int gx,
                                          const int* __restrict__ flagp,
                                          bf16* __restrict__ vtr){
  constexpr int BK  = 64;
  constexpr int NT  = WM*WN*64;
  constexpr int FM  = BM/(WM*16);
  constexpr int FN  = BN/(WN*16);
  constexpr int S   = (BM+BN)*BK;
  constexpr int CAW = (BM*BK/512)/(NT/64);
  constexpr int CBW = (BN*BK/512)/(NT/64);
  __shared__ bf16 lds[2*S];
  int nwg = gridDim.x, bid = blockIdx.x;
  int q = nwg>>3, rr = nwg&7, xcd = bid&7, ii = bid>>3;
  int wg = (xcd<rr ? xcd*(q+1) : rr*(q+1)+(xcd-rr)*q) + ii;
  int bx = wg % gx, by = wg / gx;
  int z = blockIdx.z;
  A  += (size_t)z*sA;
  Bt += (size_t)z*sB;
  if(bias) bias += (size_t)z*sBias;
  int tid = threadIdx.x, lane = tid&63, w = tid>>6;
  int m0 = by*BM, n0 = bx*BN;
  int wrow = (w/WN)*(FM*16), wcol = (w%WN)*(FN*16);
  int l15 = lane&15, l4 = lane>>4;
  int lrow = lane>>3, lgr = lane&7;
  int nk = K/BK;
  auto stage = [&](int kt, int buf){
    bf16* Ab = lds + buf*S;
    bf16* Bb = Ab + BM*BK;
    const bf16* gA = A + (size_t)m0*K + kt*BK;
    const bf16* gB = Bt + (size_t)n0*K + kt*BK;
    #pragma unroll
    for(int i=0;i<CAW;++i){
      int chunk = w*CAW + i;
      int row = chunk*8 + lrow;
      gl16(gA + (size_t)row*K + ((lgr ^ (row&7))*8), Ab + chunk*512);
    }
    #pragma unroll
    for(int i=0;i<CBW;++i){
      int chunk = w*CBW + i;
      int row = chunk*8 + lrow;
      gl16(gB + (size_t)row*K + ((lgr ^ (row&7))*8), Bb + chunk*512);
    }
  };
  f4 acc[FM][FN] = {};
  stage(0, 0);
  __syncthreads();
  for(int kt=0; kt<nk; ++kt){
    int cur = kt & 1;
    if(kt+1 < nk) stage(kt+1, cur^1);
    const bf16* Ab = lds + cur*S;
    const bf16* Bb = Ab + BM*BK;
    #pragma unroll
    for(int g=0; g<2; ++g){
      bf8s af[FM], bfv[FN];
      #pragma unroll
      for(int i=0;i<FM;++i){
        int r = wrow + i*16 + l15;
        af[i] = *(const bf8s*)(Ab + r*BK + (((g*4+l4) ^ (r&7))*8));
      }
      #pragma unroll
      for(int j=0;j<FN;++j){
        int r = wcol + j*16 + l15;
        bfv[j] = *(const bf8s*)(Bb + r*BK + (((g*4+l4) ^ (r&7))*8));
      }
      #pragma unroll
      for(int i=0;i<FM;++i)
        #pragma unroll
        for(int j=0;j<FN;++j)
          acc[i][j] = __builtin_amdgcn_mfma_f32_16x16x32_bf16(af[i], bfv[j], acc[i][j], 0,0,0);
    }
    __syncthreads();
  }
  bool f32o = (CMODE==2) ? (*flagp != 0) : (CMODE==1);
  bool trv = TRV && (z == 2);
  #pragma unroll
  for(int i=0;i<FM;++i){
    #pragma unroll
    for(int j=0;j<FN;++j){
      int col = n0 + wcol + j*16 + l15;
      float bv = bias ? cvt(bias[col]) : 0.f;
      #pragma unroll
      for(int q2=0;q2<4;++q2){
        int row = m0 + wrow + i*16 + l4*4 + q2;
        float v = acc[i][j][q2] + bv;
        if(trv){
          int b = row >> 9, t = row & 511;
          vtr[(size_t)b*(64*512) + (size_t)col*512 + t] = (bf16)v;
          continue;
        }
        size_t off = (size_t)z*sC + (size_t)row*N + col;
        if(RESID) v += ((const float*)Cv)[off];
        if(RELU)  v = fmaxf(v, 0.f);
        if(CMODE==0)      ((bf16*)Cv)[off] = (bf16)v;
        else if(CMODE==1) ((float*)Cv)[off] = v;
        else { if(f32o) ((float*)Cv)[off] = v; else ((bf16*)Cv)[off] = (bf16)v; }
      }
    }
  }
}

// =====================  FUSED PROJ + RESID + LN2  =====================
// h[32x512] += vals[32x64] @ wsT[512x64]^T + bo ; y = LN(h)*g+be.
// Block: 32 rows x full 512 cols, 256 thr = 4 waves, wave w owns cols w*128..+127.
// K=64 = single staged step (no dbuf). LDS: A 4KB + B 64KB + reduce 1KB.
__global__ __launch_bounds__(256) void k_projln(const bf16* __restrict__ vals,
                                                const bf16* __restrict__ wsT,
                                                const bf16* __restrict__ bo,
                                                const bf16* __restrict__ g,
                                                const bf16* __restrict__ be,
                                                float* __restrict__ h,
                                                bf16* __restrict__ y){
  __shared__ bf16 Al[32*64];
  __shared__ bf16 Bl[512*64];
  __shared__ float rs[4][32], rs2[4][32];
  int m0 = blockIdx.x*32;
  int tid = threadIdx.x, lane = tid&63, w = tid>>6;
  int l15 = lane&15, l4 = lane>>4;
  int lrow = lane>>3, lgr = lane&7;
  // stage A (4 chunks, 1 per wave) + B (64 chunks, 16 per wave)
  {
    int row = w*8 + lrow;
    gl16(vals + (size_t)(m0+row)*64 + ((lgr ^ (row&7))*8), Al + w*512);
  }
  #pragma unroll
  for(int i=0;i<16;++i){
    int chunk = w*16 + i;
    int row = chunk*8 + lrow;
    gl16(wsT + (size_t)row*64 + ((lgr ^ (row&7))*8), Bl + chunk*512);
  }
  __syncthreads();
  int wcol = w*128;
  f4 acc[2][8] = {};
  #pragma unroll
  for(int g2=0; g2<2; ++g2){
    bf8s af[2], bfv[8];
    #pragma unroll
    for(int i=0;i<2;++i){
      int r = i*16 + l15;
      af[i] = *(const bf8s*)(Al + r*64 + (((g2*4+l4) ^ (r&7))*8));
    }
    #pragma unroll
    for(int j=0;j<8;++j){
      int r = wcol + j*16 + l15;
      bfv[j] = *(const bf8s*)(Bl + r*64 + (((g2*4+l4) ^ (r&7))*8));
    }
    #pragma unroll
    for(int i=0;i<2;++i)
      #pragma unroll
      for(int j=0;j<8;++j)
        acc[i][j] = __builtin_amdgcn_mfma_f32_16x16x32_bf16(af[i], bfv[j], acc[i][j], 0,0,0);
  }
  // epilogue: + bias + resid -> h (f32), accumulate row sums
  #pragma unroll
  for(int i=0;i<2;++i){
    float s[4] = {0,0,0,0}, s2[4] = {0,0,0,0};
    #pragma unroll
    for(int j=0;j<8;++j){
      int col = wcol + j*16 + l15;
      float bv = cvt(bo[col]);
      #pragma unroll
      for(int q=0;q<4;++q){
        int row = m0 + i*16 + l4*4 + q;
        size_t off = (size_t)row*512 + col;
        float v = acc[i][j][q] + bv + h[off];
        acc[i][j][q] = v;
        h[off] = v;
        s[q] += v; s2[q] += v*v;
      }
    }
    #pragma unroll
    for(int q=0;q<4;++q){
      #pragma unroll
      for(int o=1;o<16;o<<=1){ s[q] += __shfl_xor(s[q],o); s2[q] += __shfl_xor(s2[q],o); }
      if(l15==0){ rs[w][i*16+l4*4+q] = s[q]; rs2[w][i*16+l4*4+q] = s2[q]; }
    }
  }
  __syncthreads();
  // LN and y write
  #pragma unroll
  for(int i=0;i<2;++i){
    #pragma unroll
    for(int q=0;q<4;++q){
      int rloc = i*16 + l4*4 + q;
      float a  = rs[0][rloc]+rs[1][rloc]+rs[2][rloc]+rs[3][rloc];
      float a2 = rs2[0][rloc]+rs2[1][rloc]+rs2[2][rloc]+rs2[3][rloc];
      float mean = a*(1.f/512.f);
      float var  = a2*(1.f/512.f) - mean*mean;
      float inv  = rsqrtf(var + 1e-5f);
      int row = m0 + rloc;
      #pragma unroll
      for(int j=0;j<8;++j){
        int col = wcol + j*16 + l15;
        y[(size_t)row*512+col] = (bf16)((acc[i][j][q]-mean)*inv*cvt(g[col]) + cvt(be[col]));
      }
    }
  }
}

// =====================  FUSED ATTENTION v2 (unchanged)  =====================
__global__ __launch_bounds__(128) void k_attn_fused(const bf16* __restrict__ Q,
                                                    const bf16* __restrict__ K,
                                                    const bf16* __restrict__ VbT,
                                                    const bf16* __restrict__ rel,  // [33][64]
                                                    bf16* __restrict__ vals){
  int ti = blockIdx.x, b = blockIdx.y;
  int t0 = ti*16;
  int tid = threadIdx.x, lane = tid & 63, wc = tid >> 6;
  int l15 = lane & 15, l4 = lane >> 4;
  __shared__ bf16  Plds[16][520];
  __shared__ float qrs[16][17];
  __shared__ float amlds[16][17];
  __shared__ float redmx[2][16];
  __shared__ float redsum[2][16];
  int nj = ti + 1;
  int KC = (nj*16 + 31) >> 5;

  const bf16* Qb = Q + ((size_t)b*512 + t0)*64;
  const bf16* Kb = K + (size_t)b*512*64;
  const bf16* Vb = VbT + (size_t)b*64*512;

  for(int i=tid; i<16*17; i+=128) ((float*)amlds)[i] = 0.f;
  if(nj & 1){
    int r = tid>>3, c = tid&7;
    ((unsigned int*)&Plds[r][nj*16])[c] = 0u;
  }

  bf8s af0 = *(const bf8s*)(Qb + (size_t)l15*64 + l4*8);
  bf8s af1 = *(const bf8s*)(Qb + (size_t)l15*64 + 32 + l4*8);

  {
    f4 qa = {};
    bf8s r0 = *(const bf8s*)(rel + (size_t)(wc*16+l15)*64 + l4*8);
    bf8s r1 = *(const bf8s*)(rel + (size_t)(wc*16+l15)*64 + 32 + l4*8);
    qa = __builtin_amdgcn_mfma_f32_16x16x32_bf16(af0, r0, qa, 0,0,0);
    qa = __builtin_amdgcn_mfma_f32_16x16x32_bf16(af1, r1, qa, 0,0,0);
    int m = wc*16 + l15;
    if(m < 17){
      #pragma unroll
      for(int q=0;q<4;++q) qrs[l4*4+q][m] = qa[q];
    }
  }
  __syncthreads();

  float mx4[4] = {-INFINITY,-INFINITY,-INFINITY,-INFINITY};
  for(int j=wc; j<nj; j+=2){
    f4 sa = {};
    const bf16* kr = Kb + (size_t)(j*16+l15)*64;
    bf8s k0 = *(const bf8s*)(kr + l4*8);
    bf8s k1 = *(const bf8s*)(kr + 32 + l4*8);
    sa = __builtin_amdgcn_mfma_f32_16x16x32_bf16(af0, k0, sa, 0,0,0);
    sa = __builtin_amdgcn_mfma_f32_16x16x32_bf16(af1, k1, sa, 0,0,0);
    int s = j*16 + l15;
    #pragma unroll
    for(int q=0;q<4;++q){
      int row = l4*4+q, t = t0+row;
      float sp = -1e30f;
      if(s <= t){
        int m = s - t + 16; m = m < 0 ? 0 : m;
        sp = (sa[q] + qrs[row][m])*0.125f;
        mx4[q] = fmaxf(mx4[q], sp);
      }
      Plds[row][s] = (bf16)sp;
    }
  }
  #pragma unroll
  for(int q=0;q<4;++q){
    float m = mx4[q];
    m = fmaxf(m, __shfl_xor(m,1)); m = fmaxf(m, __shfl_xor(m,2));
    m = fmaxf(m, __shfl_xor(m,4)); m = fmaxf(m, __shfl_xor(m,8));
    mx4[q] = m;
  }
  if(l15==0){
    #pragma unroll
    for(int q=0;q<4;++q) redmx[wc][l4*4+q] = mx4[q];
  }
  __syncthreads();

  float mxg[4], sum4[4] = {0.f,0.f,0.f,0.f};
  #pragma unroll
  for(int q=0;q<4;++q) mxg[q] = fmaxf(redmx[0][l4*4+q], redmx[1][l4*4+q]);
  for(int j=wc; j<nj; j+=2){
    int s = j*16 + l15;
    #pragma unroll
    for(int q=0;q<4;++q){
      int row = l4*4+q, t = t0+row;
      float e = expf(cvt(Plds[row][s]) - mxg[q]);
      Plds[row][s] = (bf16)e;
      sum4[q] += e;
      int m = s - t + 16;
      if(m >= 1 && m <= 16) amlds[row][m] = e;
    }
  }
  #pragma unroll
  for(int q=0;q<4;++q){
    float s = sum4[q];
    s += __shfl_xor(s,1); s += __shfl_xor(s,2);
    s += __shfl_xor(s,4); s += __shfl_xor(s,8);
    sum4[q] = s;
  }
  if(l15==0){
    #pragma unroll
    for(int q=0;q<4;++q) redsum[wc][l4*4+q] = sum4[q];
  }
  __syncthreads();

  f4 pacc[2] = {{0,0,0,0},{0,0,0,0}};
  for(int ks=0; ks<KC; ++ks){
    bf8s ap = *(const bf8s*)(&Plds[l15][ks*32 + l4*8]);
    #pragma unroll
    for(int jj=0;jj<2;++jj){
      int hb = (wc*2+jj)*16 + l15;
      bf8s bv = *(const bf8s*)(Vb + (size_t)hb*512 + ks*32 + l4*8);
      pacc[jj] = __builtin_amdgcn_mfma_f32_16x16x32_bf16(ap, bv, pacc[jj], 0,0,0);
    }
  }
  #pragma unroll
  for(int q=0;q<4;++q){
    int row = l4*4+q;
    float sum = redsum[0][row] + redsum[1][row];
    float rs = 1.f/sum;
    float a[16];
    float amsum = 0.f;
    #pragma unroll
    for(int m=1;m<=16;++m){ a[m-1] = amlds[row][m]; amsum += a[m-1]; }
    float am0 = sum - amsum;
    #pragma unroll
    for(int jj=0;jj<2;++jj){
      int h = (wc*2+jj)*16 + l15;
      float acc = pacc[jj][q] + am0*cvt(rel[h]);
      #pragma unroll
      for(int m=1;m<=16;++m) acc += a[m-1]*cvt(rel[m*64 + h]);
      vals[((size_t)b*512 + t0 + row)*64 + h] = (bf16)(acc*rs);
    }
  }
}

extern "C" void kernel_launch(void* const* d_in, const int* in_sizes, int n_in,
                              void* d_out, int out_size, void* d_ws, size_t ws_size,
                              hipStream_t stream){
  const int* idx = (const int*)d_in[0];

  char* p = (char*)d_ws;
  auto alloc = [&](size_t bytes)->char*{ char* r = p; p += (bytes + 255) & ~(size_t)255; return r; };

  int*  flag  = (int*)alloc(4);
  bf16* rel_b = (bf16*)alloc(12672*2);
  bf16* bo_b  = (bf16*)alloc(3072*2);
  bf16* g1_b  = (bf16*)alloc(3072*2);
  bf16* be1_b = (bf16*)alloc(3072*2);
  bf16* g2_b  = (bf16*)alloc(3072*2);
  bf16* be2_b = (bf16*)alloc(3072*2);
  bf16* b1_b  = (bf16*)alloc(12288*2);
  bf16* b2_b  = (bf16*)alloc(3072*2);
  bf16* bout_b= (bf16*)alloc(2048*2);
  bf16* bqkv  = (bf16*)alloc(LL*192*2);
  bf16* WqkvT = (bf16*)alloc((size_t)LL*3*64*512*2);    // [L][3][64][512]
  bf16* W1T   = (bf16*)alloc((size_t)LL*2048*512*2);    // [L][2048][512]
  bf16* W2T   = (bf16*)alloc((size_t)LL*512*2048*2);    // [L][512][2048]
  bf16* WoutT = (bf16*)alloc((size_t)2048*512*2);       // [2048][512]
  bf16* wsT_all=(bf16*)alloc((size_t)LL*512*64*2);      // [L][512][64]
  float* h    = (float*)alloc((size_t)BT*DD*4);         // 16 MB
  bf16*  y    = (bf16*) alloc((size_t)BT*DD*2);         //  8 MB
  bf16*  hb   = y;                                      // f2b output (y dead by then)
  bf16*  QKV  = (bf16*) alloc((size_t)3*BT*64*2);       // Q|K|V contiguous
  bf16*  vals = (bf16*) alloc((size_t)BT*64*2);
  bf16*  VbT  = (bf16*) alloc((size_t)BB*64*512*2);     // [16][64][512]
  bf16*  mid  = (bf16*)d_out;                           // FFN scratch in d_out
  bf16*  Qb = QKV, *Kb = QKV + (size_t)BT*64;

  // ---- setup ----
  k_flag<<<1,64,0,stream>>>(d_in[11], flag);
  k_cvt_all<<<(46592+255)/256,256,0,stream>>>(
      d_in[8], d_in[10], d_in[11], d_in[12], d_in[13], d_in[14],
      d_in[16], d_in[18], d_in[20], d_in[3], d_in[5], d_in[7],
      rel_b, bo_b, g1_b, be1_b, g2_b, be2_b, b1_b, b2_b, bout_b, bqkv, flag);
  k_tr<<<dim3(2,16,LL),256,0,stream>>>(d_in[2], WqkvT,            512, 64, 512*64, 3*64*512, 512, flag);
  k_tr<<<dim3(2,16,LL),256,0,stream>>>(d_in[4], WqkvT + 64*512,   512, 64, 512*64, 3*64*512, 512, flag);
  k_tr<<<dim3(2,16,LL),256,0,stream>>>(d_in[6], WqkvT + 2*64*512, 512, 64, 512*64, 3*64*512, 512, flag);
  k_tr<<<dim3(64,16,LL),256,0,stream>>>(d_in[15], W1T, 512, 2048, 512*2048, 2048*512, 512, flag);
  k_tr<<<dim3(16,64,LL),256,0,stream>>>(d_in[17], W2T, 2048, 512, 2048*512, 512*2048, 2048, flag);
  k_tr<<<dim3(64,16,1),256,0,stream>>>(d_in[19], WoutT, 512, 2048, 0, 0, 512, flag);
  k_wsumT<<<(LL*32768+255)/256,256,0,stream>>>(d_in[9], wsT_all, flag);

  k_embed<<<BT,256,0,stream>>>(idx, d_in[1], h, flag);

  for(int l=0; l<LL; ++l){
    k_ln<<<BT,256,0,stream>>>(h, g1_b+l*DD, be1_b+l*DD, y);
    // QKV: batched z=3, 64x64 tile -> 384 wgs; V plane stored transposed (TRV)
    mm<64,64,2,2,0,false,false,true><<<dim3(128,1,3),256,0,stream>>>(
        y, WqkvT + (size_t)l*3*64*512, QKV, bqkv + l*192,
        BT, 64, 512, 0, 64*512, (long long)BT*64, 64, 1, nullptr, VbT);
    // fused scores+softmax+bucket+PV+relbias
    k_attn_fused<<<dim3(32,16),128,0,stream>>>(Qb, Kb, VbT, rel_b + l*33*64, vals);
    // fused proj + resid + LN2 -> h, y
    k_projln<<<256,256,0,stream>>>(vals, wsT_all + (size_t)l*32768,
                                   bo_b + l*DD, g2_b + l*DD, be2_b + l*DD, h, y);
    // mid = relu(y @ W1 + b1)   (bf16, d_out scratch) — 128x128 tile
    mm<128,128,2,2,0,true,false,false><<<dim3(1024,1,1),256,0,stream>>>(
        y, W1T + (size_t)l*2048*512, mid, b1_b + l*FF, BT, 2048, 512, 0,0,0,0, 16, nullptr, nullptr);
    // h += mid @ W2 + b2
    mm<128,64,4,1,1,false,true,false><<<dim3(512,1,1),256,0,stream>>>(
        mid, W2T + (size_t)l*512*2048, h, b2_b + l*DD, BT, 512, 2048, 0,0,0,0, 8, nullptr, nullptr);
  }
  k_f2b<<<(BT*DD+255)/256,256,0,stream>>>(h, hb, BT*DD);
  // out = hb @ Wout + bout (dual store per flag) — 128x128 tile
  mm<128,128,2,2,2,false,false,false><<<dim3(1024,1,1),256,0,stream>>>(
      hb, WoutT, d_out, bout_b, BT, 2048, 512, 0,0,0,0, 16, flag, nullptr);
}

// Round 13
// 756.595 us; speedup vs baseline: 1.5158x; 1.1284x over previous
//
#include <hip/hip_runtime.h>
#include <hip/hip_bf16.h>
#include <math.h>

#define BB 16
#define TT 512
#define VV 2048
#define DD 512
#define HDD 64
#define LL 6
#define FF 2048
#define BT 8192   // B*T

typedef __hip_bfloat16 bf16;
typedef __attribute__((ext_vector_type(8))) short bf8s;   // 8 bf16 (4 VGPRs)
typedef __attribute__((ext_vector_type(4))) float f4;     // C/D frag

__device__ __forceinline__ float cvt(float x){ return x; }
__device__ __forceinline__ float cvt(bf16 x){ return __bfloat162float(x); }

// async global->LDS, 16B per lane. LDS dest wave-uniform base (+lane*16 by HW).
__device__ __forceinline__ void gl16(const bf16* g, bf16* l){
  __builtin_amdgcn_global_load_lds(
      (const __attribute__((address_space(1))) void*)g,
      (__attribute__((address_space(3))) void*)l,
      16, 0, 0);
}

// ---------------- dtype flag ----------------
__global__ void k_flag(const void* g1, int* flagp){
  if(threadIdx.x==0 && blockIdx.x==0){
    const unsigned short* u = (const unsigned short*)g1;
    *flagp = (u[0] == 0) ? 1 : 0;   // 1 = inputs f32, 0 = bf16
  }
}

// ---------------- one-shot convert of all small tensors + QKV bias pack ----------------
__global__ __launch_bounds__(256) void k_cvt_all(
    const void* rel, const void* bo, const void* g1, const void* be1,
    const void* g2, const void* be2, const void* b1, const void* b2,
    const void* bout, const void* bq, const void* bk, const void* bv,
    bf16* d_rel, bf16* d_bo, bf16* d_g1, bf16* d_be1,
    bf16* d_g2, bf16* d_be2, bf16* d_b1, bf16* d_b2,
    bf16* d_bout, bf16* d_bqkv, const int* __restrict__ flagp){
  int i = blockIdx.x*256 + threadIdx.x;
  bool isf = *flagp;
  auto ld = [&](const void* s, int k)->float{
    return isf ? ((const float*)s)[k] : cvt(((const bf16*)s)[k]);
  };
  if(i < 12672){ d_rel[i] = (bf16)ld(rel, i); return; } i -= 12672;
  if(i < 3072){ d_bo[i]  = (bf16)ld(bo, i);  return; } i -= 3072;
  if(i < 3072){ d_g1[i]  = (bf16)ld(g1, i);  return; } i -= 3072;
  if(i < 3072){ d_be1[i] = (bf16)ld(be1, i); return; } i -= 3072;
  if(i < 3072){ d_g2[i]  = (bf16)ld(g2, i);  return; } i -= 3072;
  if(i < 3072){ d_be2[i] = (bf16)ld(be2, i); return; } i -= 3072;
  if(i < 12288){ d_b1[i] = (bf16)ld(b1, i);  return; } i -= 12288;
  if(i < 3072){ d_b2[i]  = (bf16)ld(b2, i);  return; } i -= 3072;
  if(i < 2048){ d_bout[i]= (bf16)ld(bout, i);return; } i -= 2048;
  if(i < 384){ int l=i>>6, hh=i&63; d_bqkv[l*192 + hh]       = (bf16)ld(bq, i); return; } i -= 384;
  if(i < 384){ int l=i>>6, hh=i&63; d_bqkv[l*192 + 64 + hh]  = (bf16)ld(bk, i); return; } i -= 384;
  if(i < 384){ int l=i>>6, hh=i&63; d_bqkv[l*192 + 128 + hh] = (bf16)ld(bv, i); return; }
}

// ---------------- tiled transpose: src [z][R][C] -> dst [z][C][R(ldD)] bf16 ----------------
__global__ __launch_bounds__(256) void k_tr(const void* __restrict__ src, bf16* __restrict__ dst,
                                            int R, int C, long long sS, long long sD, int ldD,
                                            const int* __restrict__ flagp){
  __shared__ bf16 t[32][33];
  int z = blockIdx.z;
  int c0 = blockIdx.x*32, r0 = blockIdx.y*32;
  int tx = threadIdx.x & 31, ty = threadIdx.x >> 5;
  bool isf = flagp && (*flagp);
  const float* sf = (const float*)src;
  const bf16*  sb = (const bf16*)src;
  for(int i=ty; i<32; i+=8){
    size_t off = (size_t)z*sS + (size_t)(r0+i)*C + (c0+tx);
    float v = isf ? sf[off] : cvt(sb[off]);
    t[i][tx] = (bf16)v;
  }
  __syncthreads();
  for(int i=ty; i<32; i+=8){
    dst[(size_t)z*sD + (size_t)(c0+i)*ldD + (r0+tx)] = t[tx][i];
  }
}

// ---------------- wsT_all[l][d][h] = sum_n Wo[l][n*64+h][d] ----------------
__global__ __launch_bounds__(256) void k_wsumT(const void* __restrict__ Wo,
                                               bf16* __restrict__ wsT,
                                               const int* __restrict__ flagp){
  int i = blockIdx.x*256 + threadIdx.x;
  if(i >= LL*64*512) return;
  int l = i >> 15, j = i & 32767, hh = j>>9, d = j&511;
  size_t loff = (size_t)l*512*512;
  bool isf = *flagp;
  float a = 0.f;
  #pragma unroll
  for(int n=0;n<8;++n){
    size_t idx = loff + (size_t)(n*64+hh)*512 + d;
    a += isf ? ((const float*)Wo)[idx] : cvt(((const bf16*)Wo)[idx]);
  }
  wsT[(size_t)l*32768 + d*64 + hh] = (bf16)a;
}

// ---------------- embed + positional encoding ----------------
__global__ __launch_bounds__(256) void k_embed(const int* __restrict__ idx,
                                               const void* __restrict__ emb,
                                               float* __restrict__ h,
                                               const int* __restrict__ flagp){
  int r = blockIdx.x;
  int t = r & (TT-1);
  int tok = idx[r];
  bool isf = *flagp;
  for(int d = threadIdx.x; d < DD; d += 256){
    int p = d >> 1;
    float ang = (float)t * powf(10000.f, -(float)p * (1.f/128.f));
    float pe = (d & 1) ? cosf(ang) : sinf(ang);
    size_t off = (size_t)tok*DD + d;
    float ev = isf ? ((const float*)emb)[off] : cvt(((const bf16*)emb)[off]);
    h[(size_t)r*DD + d] = 2.f*ev + pe;
  }
}

// ---------------- LayerNorm ----------------
__global__ __launch_bounds__(256) void k_ln(const float* __restrict__ x,
                                            const bf16* __restrict__ g,
                                            const bf16* __restrict__ b,
                                            bf16* __restrict__ y){
  int r = blockIdx.x;
  int tid = threadIdx.x;
  const float* xr = x + (size_t)r*DD;
  float v0 = xr[tid], v1 = xr[tid+256];
  float s = v0+v1, s2 = v0*v0 + v1*v1;
  for(int o=32;o;o>>=1){ s += __shfl_down(s,o); s2 += __shfl_down(s2,o); }
  __shared__ float red[8];
  int wv = tid>>6, ln = tid&63;
  if(ln==0){ red[wv]=s; red[4+wv]=s2; }
  __syncthreads();
  float a  = red[0]+red[1]+red[2]+red[3];
  float a2 = red[4]+red[5]+red[6]+red[7];
  float m  = a*(1.f/DD);
  float var = a2*(1.f/DD) - m*m;
  float inv = rsqrtf(var + 1e-5f);
  y[(size_t)r*DD+tid]     = (bf16)((v0-m)*inv*cvt(g[tid])     + cvt(b[tid]));
  y[(size_t)r*DD+tid+256] = (bf16)((v1-m)*inv*cvt(g[tid+256]) + cvt(b[tid+256]));
}

// =====================  MFMA GEMM  =====================
// CMODE: 0 bf16 store, 1 f32 store, 2 dual via flag, 3 = f32-resid read + bf16 store to vtr.
template<int BM,int BN,int WM,int WN,int CMODE,bool RELU,bool RESID,bool TRV>
__global__ __launch_bounds__(WM*WN*64) void mm(const bf16* __restrict__ A,
                                          const bf16* __restrict__ Bt,
                                          void* __restrict__ Cv,
                                          const bf16* __restrict__ bias,
                                          int M, int N, int K,
                                          long long sA, long long sB, long long sC, int sBias,
                                          int gx,
                                          const int* __restrict__ flagp,
                                          bf16* __restrict__ vtr){
  constexpr int BK  = 64;
  constexpr int NT  = WM*WN*64;
  constexpr int FM  = BM/(WM*16);
  constexpr int FN  = BN/(WN*16);
  constexpr int S   = (BM+BN)*BK;
  constexpr int CAW = (BM*BK/512)/(NT/64);
  constexpr int CBW = (BN*BK/512)/(NT/64);
  __shared__ bf16 lds[2*S];
  int nwg = gridDim.x, bid = blockIdx.x;
  int q = nwg>>3, rr = nwg&7, xcd = bid&7, ii = bid>>3;
  int wg = (xcd<rr ? xcd*(q+1) : rr*(q+1)+(xcd-rr)*q) + ii;
  int bx = wg % gx, by = wg / gx;
  int z = blockIdx.z;
  A  += (size_t)z*sA;
  Bt += (size_t)z*sB;
  if(bias) bias += (size_t)z*sBias;
  int tid = threadIdx.x, lane = tid&63, w = tid>>6;
  int m0 = by*BM, n0 = bx*BN;
  int wrow = (w/WN)*(FM*16), wcol = (w%WN)*(FN*16);
  int l15 = lane&15, l4 = lane>>4;
  int lrow = lane>>3, lgr = lane&7;
  int nk = K/BK;
  auto stage = [&](int kt, int buf){
    bf16* Ab = lds + buf*S;
    bf16* Bb = Ab + BM*BK;
    const bf16* gA = A + (size_t)m0*K + kt*BK;
    const bf16* gB = Bt + (size_t)n0*K + kt*BK;
    #pragma unroll
    for(int i=0;i<CAW;++i){
      int chunk = w*CAW + i;
      int row = chunk*8 + lrow;
      gl16(gA + (size_t)row*K + ((lgr ^ (row&7))*8), Ab + chunk*512);
    }
    #pragma unroll
    for(int i=0;i<CBW;++i){
      int chunk = w*CBW + i;
      int row = chunk*8 + lrow;
      gl16(gB + (size_t)row*K + ((lgr ^ (row&7))*8), Bb + chunk*512);
    }
  };
  f4 acc[FM][FN] = {};
  stage(0, 0);
  __syncthreads();
  for(int kt=0; kt<nk; ++kt){
    int cur = kt & 1;
    if(kt+1 < nk) stage(kt+1, cur^1);
    const bf16* Ab = lds + cur*S;
    const bf16* Bb = Ab + BM*BK;
    #pragma unroll
    for(int g=0; g<2; ++g){
      bf8s af[FM], bfv[FN];
      #pragma unroll
      for(int i=0;i<FM;++i){
        int r = wrow + i*16 + l15;
        af[i] = *(const bf8s*)(Ab + r*BK + (((g*4+l4) ^ (r&7))*8));
      }
      #pragma unroll
      for(int j=0;j<FN;++j){
        int r = wcol + j*16 + l15;
        bfv[j] = *(const bf8s*)(Bb + r*BK + (((g*4+l4) ^ (r&7))*8));
      }
      #pragma unroll
      for(int i=0;i<FM;++i)
        #pragma unroll
        for(int j=0;j<FN;++j)
          acc[i][j] = __builtin_amdgcn_mfma_f32_16x16x32_bf16(af[i], bfv[j], acc[i][j], 0,0,0);
    }
    __syncthreads();
  }
  bool f32o = (CMODE==2) ? (*flagp != 0) : (CMODE==1);
  bool trv = TRV && (z == 2);
  #pragma unroll
  for(int i=0;i<FM;++i){
    #pragma unroll
    for(int j=0;j<FN;++j){
      int col = n0 + wcol + j*16 + l15;
      float bv = bias ? cvt(bias[col]) : 0.f;
      #pragma unroll
      for(int q2=0;q2<4;++q2){
        int row = m0 + wrow + i*16 + l4*4 + q2;
        float v = acc[i][j][q2] + bv;
        if(trv){
          int b = row >> 9, t = row & 511;
          vtr[(size_t)b*(64*512) + (size_t)col*512 + t] = (bf16)v;
          continue;
        }
        size_t off = (size_t)z*sC + (size_t)row*N + col;
        if(RESID) v += ((const float*)Cv)[off];
        if(RELU)  v = fmaxf(v, 0.f);
        if(CMODE==0)      ((bf16*)Cv)[off] = (bf16)v;
        else if(CMODE==1) ((float*)Cv)[off] = v;
        else if(CMODE==3) vtr[off] = (bf16)v;   // resid-read f32, bf16 store (no h write)
        else { if(f32o) ((float*)Cv)[off] = v; else ((bf16*)Cv)[off] = (bf16)v; }
      }
    }
  }
}

// =====================  FUSED PROJ + RESID + LN2 (unchanged)  =====================
__global__ __launch_bounds__(256) void k_projln(const bf16* __restrict__ vals,
                                                const bf16* __restrict__ wsT,
                                                const bf16* __restrict__ bo,
                                                const bf16* __restrict__ g,
                                                const bf16* __restrict__ be,
                                                float* __restrict__ h,
                                                bf16* __restrict__ y){
  __shared__ bf16 Al[32*64];
  __shared__ bf16 Bl[512*64];
  __shared__ float rs[4][32], rs2[4][32];
  int m0 = blockIdx.x*32;
  int tid = threadIdx.x, lane = tid&63, w = tid>>6;
  int l15 = lane&15, l4 = lane>>4;
  int lrow = lane>>3, lgr = lane&7;
  {
    int row = w*8 + lrow;
    gl16(vals + (size_t)(m0+row)*64 + ((lgr ^ (row&7))*8), Al + w*512);
  }
  #pragma unroll
  for(int i=0;i<16;++i){
    int chunk = w*16 + i;
    int row = chunk*8 + lrow;
    gl16(wsT + (size_t)row*64 + ((lgr ^ (row&7))*8), Bl + chunk*512);
  }
  __syncthreads();
  int wcol = w*128;
  f4 acc[2][8] = {};
  #pragma unroll
  for(int g2=0; g2<2; ++g2){
    bf8s af[2], bfv[8];
    #pragma unroll
    for(int i=0;i<2;++i){
      int r = i*16 + l15;
      af[i] = *(const bf8s*)(Al + r*64 + (((g2*4+l4) ^ (r&7))*8));
    }
    #pragma unroll
    for(int j=0;j<8;++j){
      int r = wcol + j*16 + l15;
      bfv[j] = *(const bf8s*)(Bl + r*64 + (((g2*4+l4) ^ (r&7))*8));
    }
    #pragma unroll
    for(int i=0;i<2;++i)
      #pragma unroll
      for(int j=0;j<8;++j)
        acc[i][j] = __builtin_amdgcn_mfma_f32_16x16x32_bf16(af[i], bfv[j], acc[i][j], 0,0,0);
  }
  #pragma unroll
  for(int i=0;i<2;++i){
    float s[4] = {0,0,0,0}, s2[4] = {0,0,0,0};
    #pragma unroll
    for(int j=0;j<8;++j){
      int col = wcol + j*16 + l15;
      float bv = cvt(bo[col]);
      #pragma unroll
      for(int q=0;q<4;++q){
        int row = m0 + i*16 + l4*4 + q;
        size_t off = (size_t)row*512 + col;
        float v = acc[i][j][q] + bv + h[off];
        acc[i][j][q] = v;
        h[off] = v;
        s[q] += v; s2[q] += v*v;
      }
    }
    #pragma unroll
    for(int q=0;q<4;++q){
      #pragma unroll
      for(int o=1;o<16;o<<=1){ s[q] += __shfl_xor(s[q],o); s2[q] += __shfl_xor(s2[q],o); }
      if(l15==0){ rs[w][i*16+l4*4+q] = s[q]; rs2[w][i*16+l4*4+q] = s2[q]; }
    }
  }
  __syncthreads();
  #pragma unroll
  for(int i=0;i<2;++i){
    #pragma unroll
    for(int q=0;q<4;++q){
      int rloc = i*16 + l4*4 + q;
      float a  = rs[0][rloc]+rs[1][rloc]+rs[2][rloc]+rs[3][rloc];
      float a2 = rs2[0][rloc]+rs2[1][rloc]+rs2[2][rloc]+rs2[3][rloc];
      float mean = a*(1.f/512.f);
      float var  = a2*(1.f/512.f) - mean*mean;
      float inv  = rsqrtf(var + 1e-5f);
      int row = m0 + rloc;
      #pragma unroll
      for(int j=0;j<8;++j){
        int col = wcol + j*16 + l15;
        y[(size_t)row*512+col] = (bf16)((acc[i][j][q]-mean)*inv*cvt(g[col]) + cvt(be[col]));
      }
    }
  }
}

// =====================  FUSED ATTENTION v3: 4 waves, s-tiles split 4-way  =====================
__global__ __launch_bounds__(256) void k_attn_fused(const bf16* __restrict__ Q,
                                                    const bf16* __restrict__ K,
                                                    const bf16* __restrict__ VbT,
                                                    const bf16* __restrict__ rel,  // [33][64]
                                                    bf16* __restrict__ vals){
  int ti = blockIdx.x, b = blockIdx.y;
  int t0 = ti*16;
  int tid = threadIdx.x, lane = tid & 63, wc = tid >> 6;   // wc in 0..3
  int l15 = lane & 15, l4 = lane >> 4;
  __shared__ bf16  Plds[16][520];
  __shared__ float qrs[16][17];
  __shared__ float amlds[16][17];
  __shared__ float redmx[4][16];
  __shared__ float redsum[4][16];
  int nj = ti + 1;                    // 16-col s-tiles (causal)
  int KC = (nj*16 + 31) >> 5;         // 32-wide PV k-chunks

  const bf16* Qb = Q + ((size_t)b*512 + t0)*64;
  const bf16* Kb = K + (size_t)b*512*64;
  const bf16* Vb = VbT + (size_t)b*64*512;

  for(int i=tid; i<16*17; i+=256) ((float*)amlds)[i] = 0.f;
  if(nj & 1) Plds[tid>>4][nj*16 + (tid&15)] = (bf16)0.f;   // zero trailing tile

  bf8s af0 = *(const bf8s*)(Qb + (size_t)l15*64 + l4*8);
  bf8s af1 = *(const bf8s*)(Qb + (size_t)l15*64 + 32 + l4*8);

  // qrel: waves 0,1 compute m-tiles 0,1 (only m<17 kept)
  if(wc < 2){
    f4 qa = {};
    bf8s r0 = *(const bf8s*)(rel + (size_t)(wc*16+l15)*64 + l4*8);
    bf8s r1 = *(const bf8s*)(rel + (size_t)(wc*16+l15)*64 + 32 + l4*8);
    qa = __builtin_amdgcn_mfma_f32_16x16x32_bf16(af0, r0, qa, 0,0,0);
    qa = __builtin_amdgcn_mfma_f32_16x16x32_bf16(af1, r1, qa, 0,0,0);
    int m = wc*16 + l15;
    if(m < 17){
      #pragma unroll
      for(int q=0;q<4;++q) qrs[l4*4+q][m] = qa[q];
    }
  }
  __syncthreads();

  // pass1: QK^T + bias + scale -> bf16 LDS, max in-register; wave wc does tiles j = wc, wc+4, ...
  float mx4[4] = {-INFINITY,-INFINITY,-INFINITY,-INFINITY};
  for(int j=wc; j<nj; j+=4){
    f4 sa = {};
    const bf16* kr = Kb + (size_t)(j*16+l15)*64;
    bf8s k0 = *(const bf8s*)(kr + l4*8);
    bf8s k1 = *(const bf8s*)(kr + 32 + l4*8);
    sa = __builtin_amdgcn_mfma_f32_16x16x32_bf16(af0, k0, sa, 0,0,0);
    sa = __builtin_amdgcn_mfma_f32_16x16x32_bf16(af1, k1, sa, 0,0,0);
    int s = j*16 + l15;
    #pragma unroll
    for(int q=0;q<4;++q){
      int row = l4*4+q, t = t0+row;
      float sp = -1e30f;
      if(s <= t){
        int m = s - t + 16; m = m < 0 ? 0 : m;
        sp = (sa[q] + qrs[row][m])*0.125f;
        mx4[q] = fmaxf(mx4[q], sp);
      }
      Plds[row][s] = (bf16)sp;
    }
  }
  #pragma unroll
  for(int q=0;q<4;++q){
    float m = mx4[q];
    m = fmaxf(m, __shfl_xor(m,1)); m = fmaxf(m, __shfl_xor(m,2));
    m = fmaxf(m, __shfl_xor(m,4)); m = fmaxf(m, __shfl_xor(m,8));
    mx4[q] = m;
  }
  if(l15==0){
    #pragma unroll
    for(int q=0;q<4;++q) redmx[wc][l4*4+q] = mx4[q];
  }
  __syncthreads();

  // pass2: e = exp(S'-mx) (unnormalized), sums, diagonal buckets
  float mxg[4], sum4[4] = {0.f,0.f,0.f,0.f};
  #pragma unroll
  for(int q=0;q<4;++q){
    int rloc = l4*4+q;
    mxg[q] = fmaxf(fmaxf(redmx[0][rloc], redmx[1][rloc]),
                   fmaxf(redmx[2][rloc], redmx[3][rloc]));
  }
  for(int j=wc; j<nj; j+=4){
    int s = j*16 + l15;
    #pragma unroll
    for(int q=0;q<4;++q){
      int row = l4*4+q, t = t0+row;
      float e = expf(cvt(Plds[row][s]) - mxg[q]);   // masked: exp(-1e30-mx)=0
      Plds[row][s] = (bf16)e;
      sum4[q] += e;
      int m = s - t + 16;
      if(m >= 1 && m <= 16) amlds[row][m] = e;      // unique owner
    }
  }
  #pragma unroll
  for(int q=0;q<4;++q){
    float s = sum4[q];
    s += __shfl_xor(s,1); s += __shfl_xor(s,2);
    s += __shfl_xor(s,4); s += __shfl_xor(s,8);
    sum4[q] = s;
  }
  if(l15==0){
    #pragma unroll
    for(int q=0;q<4;++q) redsum[wc][l4*4+q] = sum4[q];
  }
  __syncthreads();

  // PV: wave wc owns h-tile wc (16 cols)
  f4 pacc = {0,0,0,0};
  for(int ks=0; ks<KC; ++ks){
    bf8s ap = *(const bf8s*)(&Plds[l15][ks*32 + l4*8]);
    bf8s bv = *(const bf8s*)(Vb + (size_t)(wc*16+l15)*512 + ks*32 + l4*8);
    pacc = __builtin_amdgcn_mfma_f32_16x16x32_bf16(ap, bv, pacc, 0,0,0);
  }
  // epilogue: v = (pacc + am0*rel[0][h] + sum_m am[m]*rel[m][h]) / sum
  #pragma unroll
  for(int q=0;q<4;++q){
    int row = l4*4+q;
    float sum = redsum[0][row]+redsum[1][row]+redsum[2][row]+redsum[3][row];
    float rsv = 1.f/sum;
    float a[16];
    float amsum = 0.f;
    #pragma unroll
    for(int m=1;m<=16;++m){ a[m-1] = amlds[row][m]; amsum += a[m-1]; }
    float am0 = sum - amsum;
    int h = wc*16 + l15;
    float acc = pacc[q] + am0*cvt(rel[h]);
    #pragma unroll
    for(int m=1;m<=16;++m) acc += a[m-1]*cvt(rel[m*64 + h]);
    vals[((size_t)b*512 + t0 + row)*64 + h] = (bf16)(acc*rsv);
  }
}

extern "C" void kernel_launch(void* const* d_in, const int* in_sizes, int n_in,
                              void* d_out, int out_size, void* d_ws, size_t ws_size,
                              hipStream_t stream){
  const int* idx = (const int*)d_in[0];

  char* p = (char*)d_ws;
  auto alloc = [&](size_t bytes)->char*{ char* r = p; p += (bytes + 255) & ~(size_t)255; return r; };

  int*  flag  = (int*)alloc(4);
  bf16* rel_b = (bf16*)alloc(12672*2);
  bf16* bo_b  = (bf16*)alloc(3072*2);
  bf16* g1_b  = (bf16*)alloc(3072*2);
  bf16* be1_b = (bf16*)alloc(3072*2);
  bf16* g2_b  = (bf16*)alloc(3072*2);
  bf16* be2_b = (bf16*)alloc(3072*2);
  bf16* b1_b  = (bf16*)alloc(12288*2);
  bf16* b2_b  = (bf16*)alloc(3072*2);
  bf16* bout_b= (bf16*)alloc(2048*2);
  bf16* bqkv  = (bf16*)alloc(LL*192*2);
  bf16* WqkvT = (bf16*)alloc((size_t)LL*3*64*512*2);    // [L][3][64][512]
  bf16* W1T   = (bf16*)alloc((size_t)LL*2048*512*2);    // [L][2048][512]
  bf16* W2T   = (bf16*)alloc((size_t)LL*512*2048*2);    // [L][512][2048]
  bf16* WoutT = (bf16*)alloc((size_t)2048*512*2);       // [2048][512]
  bf16* wsT_all=(bf16*)alloc((size_t)LL*512*64*2);      // [L][512][64]
  float* h    = (float*)alloc((size_t)BT*DD*4);         // 16 MB
  bf16*  y    = (bf16*) alloc((size_t)BT*DD*2);         //  8 MB
  bf16*  hb   = y;                                      // last-FFN2 bf16 out (y dead by then)
  bf16*  QKV  = (bf16*) alloc((size_t)3*BT*64*2);       // Q|K|V contiguous
  bf16*  vals = (bf16*) alloc((size_t)BT*64*2);
  bf16*  VbT  = (bf16*) alloc((size_t)BB*64*512*2);     // [16][64][512]
  bf16*  mid  = (bf16*)d_out;                           // FFN scratch in d_out
  bf16*  Qb = QKV, *Kb = QKV + (size_t)BT*64;

  // ---- setup ----
  k_flag<<<1,64,0,stream>>>(d_in[11], flag);
  k_cvt_all<<<(46592+255)/256,256,0,stream>>>(
      d_in[8], d_in[10], d_in[11], d_in[12], d_in[13], d_in[14],
      d_in[16], d_in[18], d_in[20], d_in[3], d_in[5], d_in[7],
      rel_b, bo_b, g1_b, be1_b, g2_b, be2_b, b1_b, b2_b, bout_b, bqkv, flag);
  k_tr<<<dim3(2,16,LL),256,0,stream>>>(d_in[2], WqkvT,            512, 64, 512*64, 3*64*512, 512, flag);
  k_tr<<<dim3(2,16,LL),256,0,stream>>>(d_in[4], WqkvT + 64*512,   512, 64, 512*64, 3*64*512, 512, flag);
  k_tr<<<dim3(2,16,LL),256,0,stream>>>(d_in[6], WqkvT + 2*64*512, 512, 64, 512*64, 3*64*512, 512, flag);
  k_tr<<<dim3(64,16,LL),256,0,stream>>>(d_in[15], W1T, 512, 2048, 512*2048, 2048*512, 512, flag);
  k_tr<<<dim3(16,64,LL),256,0,stream>>>(d_in[17], W2T, 2048, 512, 2048*512, 512*2048, 2048, flag);
  k_tr<<<dim3(64,16,1),256,0,stream>>>(d_in[19], WoutT, 512, 2048, 0, 0, 512, flag);
  k_wsumT<<<(LL*32768+255)/256,256,0,stream>>>(d_in[9], wsT_all, flag);

  k_embed<<<BT,256,0,stream>>>(idx, d_in[1], h, flag);

  for(int l=0; l<LL; ++l){
    k_ln<<<BT,256,0,stream>>>(h, g1_b+l*DD, be1_b+l*DD, y);
    // QKV: batched z=3, 64x64 tile -> 384 wgs; V plane stored transposed (TRV)
    mm<64,64,2,2,0,false,false,true><<<dim3(128,1,3),256,0,stream>>>(
        y, WqkvT + (size_t)l*3*64*512, QKV, bqkv + l*192,
        BT, 64, 512, 0, 64*512, (long long)BT*64, 64, 1, nullptr, VbT);
    // fused scores+softmax+bucket+PV+relbias (v3: 4 waves)
    k_attn_fused<<<dim3(32,16),256,0,stream>>>(Qb, Kb, VbT, rel_b + l*33*64, vals);
    // fused proj + resid + LN2 -> h, y
    k_projln<<<256,256,0,stream>>>(vals, wsT_all + (size_t)l*32768,
                                   bo_b + l*DD, g2_b + l*DD, be2_b + l*DD, h, y);
    // mid = relu(y @ W1 + b1)   (bf16, d_out scratch) — 128x128 tile
    mm<128,128,2,2,0,true,false,false><<<dim3(1024,1,1),256,0,stream>>>(
        y, W1T + (size_t)l*2048*512, mid, b1_b + l*FF, BT, 2048, 512, 0,0,0,0, 16, nullptr, nullptr);
    if(l < LL-1){
      // h += mid @ W2 + b2 (f32)
      mm<128,64,4,1,1,false,true,false><<<dim3(512,1,1),256,0,stream>>>(
          mid, W2T + (size_t)l*512*2048, h, b2_b + l*DD, BT, 512, 2048, 0,0,0,0, 8, nullptr, nullptr);
    } else {
      // last layer: h-resid read + bf16 store straight to hb (f2b fused away)
      mm<128,64,4,1,3,false,true,false><<<dim3(512,1,1),256,0,stream>>>(
          mid, W2T + (size_t)l*512*2048, h, b2_b + l*DD, BT, 512, 2048, 0,0,0,0, 8, nullptr, hb);
    }
  }
  // out = hb @ Wout + bout (dual store per flag) — 128x128 tile
  mm<128,128,2,2,2,false,false,false><<<dim3(1024,1,1),256,0,stream>>>(
      hb, WoutT, d_out, bout_b, BT, 2048, 512, 0,0,0,0, 16, flag, nullptr);
}

// Round 14
// 721.300 us; speedup vs baseline: 1.5900x; 1.0489x over previous
//
#include <hip/hip_runtime.h>
#include <hip/hip_bf16.h>
#include <math.h>

#define BB 16
#define TT 512
#define VV 2048
#define DD 512
#define HDD 64
#define LL 6
#define FF 2048
#define BT 8192   // B*T

typedef __hip_bfloat16 bf16;
typedef __attribute__((ext_vector_type(8))) short bf8s;   // 8 bf16 (4 VGPRs)
typedef __attribute__((ext_vector_type(4))) float f4;     // C/D frag

__device__ __forceinline__ float cvt(float x){ return x; }
__device__ __forceinline__ float cvt(bf16 x){ return __bfloat162float(x); }

// async global->LDS, 16B per lane. LDS dest wave-uniform base (+lane*16 by HW).
__device__ __forceinline__ void gl16(const bf16* g, bf16* l){
  __builtin_amdgcn_global_load_lds(
      (const __attribute__((address_space(1))) void*)g,
      (__attribute__((address_space(3))) void*)l,
      16, 0, 0);
}

// ---------------- dtype flag ----------------
__global__ void k_flag(const void* g1, int* flagp){
  if(threadIdx.x==0 && blockIdx.x==0){
    const unsigned short* u = (const unsigned short*)g1;
    *flagp = (u[0] == 0) ? 1 : 0;   // 1 = inputs f32, 0 = bf16
  }
}

// ---------------- one-shot convert of all small tensors + QKV bias pack ----------------
__global__ __launch_bounds__(256) void k_cvt_all(
    const void* rel, const void* bo, const void* g1, const void* be1,
    const void* g2, const void* be2, const void* b1, const void* b2,
    const void* bout, const void* bq, const void* bk, const void* bv,
    bf16* d_rel, bf16* d_bo, bf16* d_g1, bf16* d_be1,
    bf16* d_g2, bf16* d_be2, bf16* d_b1, bf16* d_b2,
    bf16* d_bout, bf16* d_bqkv, const int* __restrict__ flagp){
  int i = blockIdx.x*256 + threadIdx.x;
  bool isf = *flagp;
  auto ld = [&](const void* s, int k)->float{
    return isf ? ((const float*)s)[k] : cvt(((const bf16*)s)[k]);
  };
  if(i < 12672){ d_rel[i] = (bf16)ld(rel, i); return; } i -= 12672;
  if(i < 3072){ d_bo[i]  = (bf16)ld(bo, i);  return; } i -= 3072;
  if(i < 3072){ d_g1[i]  = (bf16)ld(g1, i);  return; } i -= 3072;
  if(i < 3072){ d_be1[i] = (bf16)ld(be1, i); return; } i -= 3072;
  if(i < 3072){ d_g2[i]  = (bf16)ld(g2, i);  return; } i -= 3072;
  if(i < 3072){ d_be2[i] = (bf16)ld(be2, i); return; } i -= 3072;
  if(i < 12288){ d_b1[i] = (bf16)ld(b1, i);  return; } i -= 12288;
  if(i < 3072){ d_b2[i]  = (bf16)ld(b2, i);  return; } i -= 3072;
  if(i < 2048){ d_bout[i]= (bf16)ld(bout, i);return; } i -= 2048;
  if(i < 384){ int l=i>>6, hh=i&63; d_bqkv[l*192 + hh]       = (bf16)ld(bq, i); return; } i -= 384;
  if(i < 384){ int l=i>>6, hh=i&63; d_bqkv[l*192 + 64 + hh]  = (bf16)ld(bk, i); return; } i -= 384;
  if(i < 384){ int l=i>>6, hh=i&63; d_bqkv[l*192 + 128 + hh] = (bf16)ld(bv, i); return; }
}

// ---------------- tiled transpose: src [z][R][C] -> dst [z][C][R(ldD)] bf16 ----------------
__global__ __launch_bounds__(256) void k_tr(const void* __restrict__ src, bf16* __restrict__ dst,
                                            int R, int C, long long sS, long long sD, int ldD,
                                            const int* __restrict__ flagp){
  __shared__ bf16 t[32][33];
  int z = blockIdx.z;
  int c0 = blockIdx.x*32, r0 = blockIdx.y*32;
  int tx = threadIdx.x & 31, ty = threadIdx.x >> 5;
  bool isf = flagp && (*flagp);
  const float* sf = (const float*)src;
  const bf16*  sb = (const bf16*)src;
  for(int i=ty; i<32; i+=8){
    size_t off = (size_t)z*sS + (size_t)(r0+i)*C + (c0+tx);
    float v = isf ? sf[off] : cvt(sb[off]);
    t[i][tx] = (bf16)v;
  }
  __syncthreads();
  for(int i=ty; i<32; i+=8){
    dst[(size_t)z*sD + (size_t)(c0+i)*ldD + (r0+tx)] = t[tx][i];
  }
}

// ---------------- all QKV weights in one launch: z = l*3+j, [512][64] -> [l][j][64][512] ----------------
__global__ __launch_bounds__(256) void k_tr3(const void* __restrict__ Wq, const void* __restrict__ Wk,
                                             const void* __restrict__ Wv, bf16* __restrict__ dst,
                                             const int* __restrict__ flagp){
  __shared__ bf16 t[32][33];
  int z = blockIdx.z;
  int j = z % 3, lz = z / 3;
  const void* src = (j==0) ? Wq : ((j==1) ? Wk : Wv);
  int c0 = blockIdx.x*32, r0 = blockIdx.y*32;
  int tx = threadIdx.x & 31, ty = threadIdx.x >> 5;
  bool isf = (*flagp);
  const float* sf = (const float*)src;
  const bf16*  sb = (const bf16*)src;
  for(int i=ty; i<32; i+=8){
    size_t off = (size_t)lz*512*64 + (size_t)(r0+i)*64 + (c0+tx);
    float v = isf ? sf[off] : cvt(sb[off]);
    t[i][tx] = (bf16)v;
  }
  __syncthreads();
  for(int i=ty; i<32; i+=8){
    dst[(size_t)lz*3*64*512 + (size_t)j*64*512 + (size_t)(c0+i)*512 + (r0+tx)] = t[tx][i];
  }
}

// ---------------- wsT_all[l][d][h] = sum_n Wo[l][n*64+h][d] ----------------
__global__ __launch_bounds__(256) void k_wsumT(const void* __restrict__ Wo,
                                               bf16* __restrict__ wsT,
                                               const int* __restrict__ flagp){
  int i = blockIdx.x*256 + threadIdx.x;
  if(i >= LL*64*512) return;
  int l = i >> 15, j = i & 32767, hh = j>>9, d = j&511;
  size_t loff = (size_t)l*512*512;
  bool isf = *flagp;
  float a = 0.f;
  #pragma unroll
  for(int n=0;n<8;++n){
    size_t idx = loff + (size_t)(n*64+hh)*512 + d;
    a += isf ? ((const float*)Wo)[idx] : cvt(((const bf16*)Wo)[idx]);
  }
  wsT[(size_t)l*32768 + d*64 + hh] = (bf16)a;
}

// ---------------- embed + positional encoding ----------------
__global__ __launch_bounds__(256) void k_embed(const int* __restrict__ idx,
                                               const void* __restrict__ emb,
                                               float* __restrict__ h,
                                               const int* __restrict__ flagp){
  int r = blockIdx.x;
  int t = r & (TT-1);
  int tok = idx[r];
  bool isf = *flagp;
  for(int d = threadIdx.x; d < DD; d += 256){
    int p = d >> 1;
    float ang = (float)t * powf(10000.f, -(float)p * (1.f/128.f));
    float pe = (d & 1) ? cosf(ang) : sinf(ang);
    size_t off = (size_t)tok*DD + d;
    float ev = isf ? ((const float*)emb)[off] : cvt(((const bf16*)emb)[off]);
    h[(size_t)r*DD + d] = 2.f*ev + pe;
  }
}

// ---------------- LayerNorm ----------------
__global__ __launch_bounds__(256) void k_ln(const float* __restrict__ x,
                                            const bf16* __restrict__ g,
                                            const bf16* __restrict__ b,
                                            bf16* __restrict__ y){
  int r = blockIdx.x;
  int tid = threadIdx.x;
  const float* xr = x + (size_t)r*DD;
  float v0 = xr[tid], v1 = xr[tid+256];
  float s = v0+v1, s2 = v0*v0 + v1*v1;
  for(int o=32;o;o>>=1){ s += __shfl_down(s,o); s2 += __shfl_down(s2,o); }
  __shared__ float red[8];
  int wv = tid>>6, ln = tid&63;
  if(ln==0){ red[wv]=s; red[4+wv]=s2; }
  __syncthreads();
  float a  = red[0]+red[1]+red[2]+red[3];
  float a2 = red[4]+red[5]+red[6]+red[7];
  float m  = a*(1.f/DD);
  float var = a2*(1.f/DD) - m*m;
  float inv = rsqrtf(var + 1e-5f);
  y[(size_t)r*DD+tid]     = (bf16)((v0-m)*inv*cvt(g[tid])     + cvt(b[tid]));
  y[(size_t)r*DD+tid+256] = (bf16)((v1-m)*inv*cvt(g[tid+256]) + cvt(b[tid+256]));
}

// =====================  MFMA GEMM  =====================
// CMODE: 0 bf16 store, 1 f32 store, 2 dual via flag, 3 = f32-resid read + bf16 store to vtr.
template<int BM,int BN,int WM,int WN,int CMODE,bool RELU,bool RESID,bool TRV>
__global__ __launch_bounds__(WM*WN*64) void mm(const bf16* __restrict__ A,
                                          const bf16* __restrict__ Bt,
                                          void* __restrict__ Cv,
                                          const bf16* __restrict__ bias,
                                          int M, int N, int K,
                                          long long sA, long long sB, long long sC, int sBias,
                                          int gx,
                                          const int* __restrict__ flagp,
                                          bf16* __restrict__ vtr){
  constexpr int BK  = 64;
  constexpr int NT  = WM*WN*64;
  constexpr int FM  = BM/(WM*16);
  constexpr int FN  = BN/(WN*16);
  constexpr int S   = (BM+BN)*BK;
  constexpr int CAW = (BM*BK/512)/(NT/64);
  constexpr int CBW = (BN*BK/512)/(NT/64);
  __shared__ bf16 lds[2*S];
  int nwg = gridDim.x, bid = blockIdx.x;
  int q = nwg>>3, rr = nwg&7, xcd = bid&7, ii = bid>>3;
  int wg = (xcd<rr ? xcd*(q+1) : rr*(q+1)+(xcd-rr)*q) + ii;
  int bx = wg % gx, by = wg / gx;
  int z = blockIdx.z;
  A  += (size_t)z*sA;
  Bt += (size_t)z*sB;
  if(bias) bias += (size_t)z*sBias;
  int tid = threadIdx.x, lane = tid&63, w = tid>>6;
  int m0 = by*BM, n0 = bx*BN;
  int wrow = (w/WN)*(FM*16), wcol = (w%WN)*(FN*16);
  int l15 = lane&15, l4 = lane>>4;
  int lrow = lane>>3, lgr = lane&7;
  int nk = K/BK;
  auto stage = [&](int kt, int buf){
    bf16* Ab = lds + buf*S;
    bf16* Bb = Ab + BM*BK;
    const bf16* gA = A + (size_t)m0*K + kt*BK;
    const bf16* gB = Bt + (size_t)n0*K + kt*BK;
    #pragma unroll
    for(int i=0;i<CAW;++i){
      int chunk = w*CAW + i;
      int row = chunk*8 + lrow;
      gl16(gA + (size_t)row*K + ((lgr ^ (row&7))*8), Ab + chunk*512);
    }
    #pragma unroll
    for(int i=0;i<CBW;++i){
      int chunk = w*CBW + i;
      int row = chunk*8 + lrow;
      gl16(gB + (size_t)row*K + ((lgr ^ (row&7))*8), Bb + chunk*512);
    }
  };
  f4 acc[FM][FN] = {};
  stage(0, 0);
  __syncthreads();
  for(int kt=0; kt<nk; ++kt){
    int cur = kt & 1;
    if(kt+1 < nk) stage(kt+1, cur^1);
    const bf16* Ab = lds + cur*S;
    const bf16* Bb = Ab + BM*BK;
    #pragma unroll
    for(int g=0; g<2; ++g){
      bf8s af[FM], bfv[FN];
      #pragma unroll
      for(int i=0;i<FM;++i){
        int r = wrow + i*16 + l15;
        af[i] = *(const bf8s*)(Ab + r*BK + (((g*4+l4) ^ (r&7))*8));
      }
      #pragma unroll
      for(int j=0;j<FN;++j){
        int r = wcol + j*16 + l15;
        bfv[j] = *(const bf8s*)(Bb + r*BK + (((g*4+l4) ^ (r&7))*8));
      }
      #pragma unroll
      for(int i=0;i<FM;++i)
        #pragma unroll
        for(int j=0;j<FN;++j)
          acc[i][j] = __builtin_amdgcn_mfma_f32_16x16x32_bf16(af[i], bfv[j], acc[i][j], 0,0,0);
    }
    __syncthreads();
  }
  bool f32o = (CMODE==2) ? (*flagp != 0) : (CMODE==1);
  bool trv = TRV && (z == 2);
  #pragma unroll
  for(int i=0;i<FM;++i){
    #pragma unroll
    for(int j=0;j<FN;++j){
      int col = n0 + wcol + j*16 + l15;
      float bv = bias ? cvt(bias[col]) : 0.f;
      #pragma unroll
      for(int q2=0;q2<4;++q2){
        int row = m0 + wrow + i*16 + l4*4 + q2;
        float v = acc[i][j][q2] + bv;
        if(trv){
          int b = row >> 9, t = row & 511;
          vtr[(size_t)b*(64*512) + (size_t)col*512 + t] = (bf16)v;
          continue;
        }
        size_t off = (size_t)z*sC + (size_t)row*N + col;
        if(RESID) v += ((const float*)Cv)[off];
        if(RELU)  v = fmaxf(v, 0.f);
        if(CMODE==0)      ((bf16*)Cv)[off] = (bf16)v;
        else if(CMODE==1) ((float*)Cv)[off] = v;
        else if(CMODE==3) vtr[off] = (bf16)v;   // resid-read f32, bf16 store (no h write)
        else { if(f32o) ((float*)Cv)[off] = v; else ((bf16*)Cv)[off] = (bf16)v; }
      }
    }
  }
}

// =====================  FUSED ATTENTION + PROJ + RESID + LN2  =====================
// Block = (ti16, b): 16 q-rows, 256 thr = 4 waves.
// Phase A (= attn v3): QK^T+qrel+softmax+buckets+PV+rel-bias -> vals in LDS (bf16).
// Phase B: out[16x512] = vals @ wsT^T + bo + h (resid) -> h; LN2 -> y.
//          A-frags from LDS vals, B-frags (wsT, 64KB L2-resident) from global.
__global__ __launch_bounds__(256) void k_attnproj(const bf16* __restrict__ Q,
                                                  const bf16* __restrict__ K,
                                                  const bf16* __restrict__ VbT,
                                                  const bf16* __restrict__ rel,  // [33][64]
                                                  const bf16* __restrict__ wsT,  // [512][64]
                                                  const bf16* __restrict__ bo,
                                                  const bf16* __restrict__ g,
                                                  const bf16* __restrict__ be,
                                                  float* __restrict__ h,
                                                  bf16* __restrict__ y){
  int ti = blockIdx.x, b = blockIdx.y;
  int t0 = ti*16;
  int tid = threadIdx.x, lane = tid & 63, wc = tid >> 6;   // wc in 0..3
  int l15 = lane & 15, l4 = lane >> 4;
  __shared__ bf16  Plds[16][520];
  __shared__ bf16  vlds[16][68];
  __shared__ float qrs[16][17];
  __shared__ float amlds[16][17];
  __shared__ float redmx[4][16];
  __shared__ float redsum[4][16];
  __shared__ float rs[4][16], rs2[4][16];
  int nj = ti + 1;                    // 16-col s-tiles (causal)
  int KC = (nj*16 + 31) >> 5;         // 32-wide PV k-chunks

  const bf16* Qb = Q + ((size_t)b*512 + t0)*64;
  const bf16* Kb = K + (size_t)b*512*64;
  const bf16* Vb = VbT + (size_t)b*64*512;

  for(int i=tid; i<16*17; i+=256) ((float*)amlds)[i] = 0.f;
  if(nj & 1) Plds[tid>>4][nj*16 + (tid&15)] = (bf16)0.f;   // zero trailing tile

  bf8s af0 = *(const bf8s*)(Qb + (size_t)l15*64 + l4*8);
  bf8s af1 = *(const bf8s*)(Qb + (size_t)l15*64 + 32 + l4*8);

  // qrel: waves 0,1 compute m-tiles 0,1 (only m<17 kept)
  if(wc < 2){
    f4 qa = {};
    bf8s r0 = *(const bf8s*)(rel + (size_t)(wc*16+l15)*64 + l4*8);
    bf8s r1 = *(const bf8s*)(rel + (size_t)(wc*16+l15)*64 + 32 + l4*8);
    qa = __builtin_amdgcn_mfma_f32_16x16x32_bf16(af0, r0, qa, 0,0,0);
    qa = __builtin_amdgcn_mfma_f32_16x16x32_bf16(af1, r1, qa, 0,0,0);
    int m = wc*16 + l15;
    if(m < 17){
      #pragma unroll
      for(int q=0;q<4;++q) qrs[l4*4+q][m] = qa[q];
    }
  }
  __syncthreads();

  // pass1: QK^T + bias + scale -> bf16 LDS, max in-register; wave wc: tiles j = wc, wc+4, ...
  float mx4[4] = {-INFINITY,-INFINITY,-INFINITY,-INFINITY};
  for(int j=wc; j<nj; j+=4){
    f4 sa = {};
    const bf16* kr = Kb + (size_t)(j*16+l15)*64;
    bf8s k0 = *(const bf8s*)(kr + l4*8);
    bf8s k1 = *(const bf8s*)(kr + 32 + l4*8);
    sa = __builtin_amdgcn_mfma_f32_16x16x32_bf16(af0, k0, sa, 0,0,0);
    sa = __builtin_amdgcn_mfma_f32_16x16x32_bf16(af1, k1, sa, 0,0,0);
    int s = j*16 + l15;
    #pragma unroll
    for(int q=0;q<4;++q){
      int row = l4*4+q, t = t0+row;
      float sp = -1e30f;
      if(s <= t){
        int m = s - t + 16; m = m < 0 ? 0 : m;
        sp = (sa[q] + qrs[row][m])*0.125f;
        mx4[q] = fmaxf(mx4[q], sp);
      }
      Plds[row][s] = (bf16)sp;
    }
  }
  #pragma unroll
  for(int q=0;q<4;++q){
    float m = mx4[q];
    m = fmaxf(m, __shfl_xor(m,1)); m = fmaxf(m, __shfl_xor(m,2));
    m = fmaxf(m, __shfl_xor(m,4)); m = fmaxf(m, __shfl_xor(m,8));
    mx4[q] = m;
  }
  if(l15==0){
    #pragma unroll
    for(int q=0;q<4;++q) redmx[wc][l4*4+q] = mx4[q];
  }
  __syncthreads();

  // pass2: e = exp(S'-mx) (unnormalized), sums, diagonal buckets
  float mxg[4], sum4[4] = {0.f,0.f,0.f,0.f};
  #pragma unroll
  for(int q=0;q<4;++q){
    int rloc = l4*4+q;
    mxg[q] = fmaxf(fmaxf(redmx[0][rloc], redmx[1][rloc]),
                   fmaxf(redmx[2][rloc], redmx[3][rloc]));
  }
  for(int j=wc; j<nj; j+=4){
    int s = j*16 + l15;
    #pragma unroll
    for(int q=0;q<4;++q){
      int row = l4*4+q, t = t0+row;
      float e = expf(cvt(Plds[row][s]) - mxg[q]);   // masked: exp(-1e30-mx)=0
      Plds[row][s] = (bf16)e;
      sum4[q] += e;
      int m = s - t + 16;
      if(m >= 1 && m <= 16) amlds[row][m] = e;      // unique owner
    }
  }
  #pragma unroll
  for(int q=0;q<4;++q){
    float s = sum4[q];
    s += __shfl_xor(s,1); s += __shfl_xor(s,2);
    s += __shfl_xor(s,4); s += __shfl_xor(s,8);
    sum4[q] = s;
  }
  if(l15==0){
    #pragma unroll
    for(int q=0;q<4;++q) redsum[wc][l4*4+q] = sum4[q];
  }
  __syncthreads();

  // PV: wave wc owns h-tile wc (16 cols)
  f4 pacc = {0,0,0,0};
  for(int ks=0; ks<KC; ++ks){
    bf8s ap = *(const bf8s*)(&Plds[l15][ks*32 + l4*8]);
    bf8s bv = *(const bf8s*)(Vb + (size_t)(wc*16+l15)*512 + ks*32 + l4*8);
    pacc = __builtin_amdgcn_mfma_f32_16x16x32_bf16(ap, bv, pacc, 0,0,0);
  }
  // attn epilogue -> vals into LDS
  #pragma unroll
  for(int q=0;q<4;++q){
    int row = l4*4+q;
    float sum = redsum[0][row]+redsum[1][row]+redsum[2][row]+redsum[3][row];
    float rsv = 1.f/sum;
    float a[16];
    float amsum = 0.f;
    #pragma unroll
    for(int m=1;m<=16;++m){ a[m-1] = amlds[row][m]; amsum += a[m-1]; }
    float am0 = sum - amsum;
    int hh = wc*16 + l15;
    float acc = pacc[q] + am0*cvt(rel[hh]);
    #pragma unroll
    for(int m=1;m<=16;++m) acc += a[m-1]*cvt(rel[m*64 + hh]);
    vlds[row][hh] = (bf16)(acc*rsv);
  }
  __syncthreads();

  // ---- Phase B: proj (vals @ wsT^T) + bo + resid -> h; LN2 -> y ----
  // wave wc owns n-tiles nn = wc*8 + j (cols nn*16 .. +15)
  bf8s pa0 = *(const bf8s*)(&vlds[l15][l4*8]);         // g=0: k = l4*8
  bf8s pa1 = *(const bf8s*)(&vlds[l15][32 + l4*8]);    // g=1
  f4 acc2[8] = {};
  #pragma unroll
  for(int j=0;j<8;++j){
    int nn = wc*8 + j;
    bf8s bv0 = *(const bf8s*)(wsT + (size_t)(nn*16+l15)*64 + l4*8);
    bf8s bv1 = *(const bf8s*)(wsT + (size_t)(nn*16+l15)*64 + 32 + l4*8);
    acc2[j] = __builtin_amdgcn_mfma_f32_16x16x32_bf16(pa0, bv0, acc2[j], 0,0,0);
    acc2[j] = __builtin_amdgcn_mfma_f32_16x16x32_bf16(pa1, bv1, acc2[j], 0,0,0);
  }
  // epilogue: + bias + resid -> h, row partial sums
  float s4[4] = {0,0,0,0}, s24[4] = {0,0,0,0};
  #pragma unroll
  for(int j=0;j<8;++j){
    int col = (wc*8+j)*16 + l15;
    float bv = cvt(bo[col]);
    #pragma unroll
    for(int q=0;q<4;++q){
      int row = t0 + l4*4 + q;
      size_t off = ((size_t)b*512 + row)*512 + col;
      float v = acc2[j][q] + bv + h[off];
      acc2[j][q] = v;
      h[off] = v;
      s4[q] += v; s24[q] += v*v;
    }
  }
  #pragma unroll
  for(int q=0;q<4;++q){
    #pragma unroll
    for(int o=1;o<16;o<<=1){ s4[q] += __shfl_xor(s4[q],o); s24[q] += __shfl_xor(s24[q],o); }
    if(l15==0){ rs[wc][l4*4+q] = s4[q]; rs2[wc][l4*4+q] = s24[q]; }
  }
  __syncthreads();
  #pragma unroll
  for(int q=0;q<4;++q){
    int rloc = l4*4+q;
    float a  = rs[0][rloc]+rs[1][rloc]+rs[2][rloc]+rs[3][rloc];
    float a2 = rs2[0][rloc]+rs2[1][rloc]+rs2[2][rloc]+rs2[3][rloc];
    float mean = a*(1.f/512.f);
    float var  = a2*(1.f/512.f) - mean*mean;
    float inv  = rsqrtf(var + 1e-5f);
    int row = t0 + rloc;
    #pragma unroll
    for(int j=0;j<8;++j){
      int col = (wc*8+j)*16 + l15;
      y[((size_t)b*512 + row)*512 + col] =
          (bf16)((acc2[j][q]-mean)*inv*cvt(g[col]) + cvt(be[col]));
    }
  }
}

extern "C" void kernel_launch(void* const* d_in, const int* in_sizes, int n_in,
                              void* d_out, int out_size, void* d_ws, size_t ws_size,
                              hipStream_t stream){
  const int* idx = (const int*)d_in[0];

  char* p = (char*)d_ws;
  auto alloc = [&](size_t bytes)->char*{ char* r = p; p += (bytes + 255) & ~(size_t)255; return r; };

  int*  flag  = (int*)alloc(4);
  bf16* rel_b = (bf16*)alloc(12672*2);
  bf16* bo_b  = (bf16*)alloc(3072*2);
  bf16* g1_b  = (bf16*)alloc(3072*2);
  bf16* be1_b = (bf16*)alloc(3072*2);
  bf16* g2_b  = (bf16*)alloc(3072*2);
  bf16* be2_b = (bf16*)alloc(3072*2);
  bf16* b1_b  = (bf16*)alloc(12288*2);
  bf16* b2_b  = (bf16*)alloc(3072*2);
  bf16* bout_b= (bf16*)alloc(2048*2);
  bf16* bqkv  = (bf16*)alloc(LL*192*2);
  bf16* WqkvT = (bf16*)alloc((size_t)LL*3*64*512*2);    // [L][3][64][512]
  bf16* W1T   = (bf16*)alloc((size_t)LL*2048*512*2);    // [L][2048][512]
  bf16* W2T   = (bf16*)alloc((size_t)LL*512*2048*2);    // [L][512][2048]
  bf16* WoutT = (bf16*)alloc((size_t)2048*512*2);       // [2048][512]
  bf16* wsT_all=(bf16*)alloc((size_t)LL*512*64*2);      // [L][512][64]
  float* h    = (float*)alloc((size_t)BT*DD*4);         // 16 MB
  bf16*  y    = (bf16*) alloc((size_t)BT*DD*2);         //  8 MB
  bf16*  hb   = y;                                      // last-FFN2 bf16 out (y dead by then)
  bf16*  QKV  = (bf16*) alloc((size_t)3*BT*64*2);       // Q|K|V contiguous
  bf16*  VbT  = (bf16*) alloc((size_t)BB*64*512*2);     // [16][64][512]
  bf16*  mid  = (bf16*)d_out;                           // FFN scratch in d_out
  bf16*  Qb = QKV, *Kb = QKV + (size_t)BT*64;

  // ---- setup ----
  k_flag<<<1,64,0,stream>>>(d_in[11], flag);
  k_cvt_all<<<(46592+255)/256,256,0,stream>>>(
      d_in[8], d_in[10], d_in[11], d_in[12], d_in[13], d_in[14],
      d_in[16], d_in[18], d_in[20], d_in[3], d_in[5], d_in[7],
      rel_b, bo_b, g1_b, be1_b, g2_b, be2_b, b1_b, b2_b, bout_b, bqkv, flag);
  k_tr3<<<dim3(2,16,3*LL),256,0,stream>>>(d_in[2], d_in[4], d_in[6], WqkvT, flag);
  k_tr<<<dim3(64,16,LL),256,0,stream>>>(d_in[15], W1T, 512, 2048, 512*2048, 2048*512, 512, flag);
  k_tr<<<dim3(16,64,LL),256,0,stream>>>(d_in[17], W2T, 2048, 512, 2048*512, 512*2048, 2048, flag);
  k_tr<<<dim3(64,16,1),256,0,stream>>>(d_in[19], WoutT, 512, 2048, 0, 0, 512, flag);
  k_wsumT<<<(LL*32768+255)/256,256,0,stream>>>(d_in[9], wsT_all, flag);

  k_embed<<<BT,256,0,stream>>>(idx, d_in[1], h, flag);

  for(int l=0; l<LL; ++l){
    k_ln<<<BT,256,0,stream>>>(h, g1_b+l*DD, be1_b+l*DD, y);
    // QKV: batched z=3, 32x64 tile -> 768 wgs; V plane stored transposed (TRV)
    mm<32,64,2,2,0,false,false,true><<<dim3(256,1,3),256,0,stream>>>(
        y, WqkvT + (size_t)l*3*64*512, QKV, bqkv + l*192,
        BT, 64, 512, 0, 64*512, (long long)BT*64, 64, 1, nullptr, VbT);
    // fused attn + proj + resid + LN2 -> h, y
    k_attnproj<<<dim3(32,16),256,0,stream>>>(Qb, Kb, VbT, rel_b + l*33*64,
                                             wsT_all + (size_t)l*32768,
                                             bo_b + l*DD, g2_b + l*DD, be2_b + l*DD, h, y);
    // mid = relu(y @ W1 + b1)   (bf16, d_out scratch) — 128x128 tile
    mm<128,128,2,2,0,true,false,false><<<dim3(1024,1,1),256,0,stream>>>(
        y, W1T + (size_t)l*2048*512, mid, b1_b + l*FF, BT, 2048, 512, 0,0,0,0, 16, nullptr, nullptr);
    if(l < LL-1){
      // h += mid @ W2 + b2 (f32)
      mm<128,64,4,1,1,false,true,false><<<dim3(512,1,1),256,0,stream>>>(
          mid, W2T + (size_t)l*512*2048, h, b2_b + l*DD, BT, 512, 2048, 0,0,0,0, 8, nullptr, nullptr);
    } else {
      // last layer: h-resid read + bf16 store straight to hb (f2b fused away)
      mm<128,64,4,1,3,false,true,false><<<dim3(512,1,1),256,0,stream>>>(
          mid, W2T + (size_t)l*512*2048, h, b2_b + l*DD, BT, 512, 2048, 0,0,0,0, 8, nullptr, hb);
    }
  }
  // out = hb @ Wout + bout (dual store per flag) — 128x128 tile
  mm<128,128,2,2,2,false,false,false><<<dim3(1024,1,1),256,0,stream>>>(
      hb, WoutT, d_out, bout_b, BT, 2048, 512, 0,0,0,0, 16, flag, nullptr);
}

// Round 15
// 714.671 us; speedup vs baseline: 1.6048x; 1.0093x over previous
//
#include <hip/hip_runtime.h>
#include <hip/hip_bf16.h>
#include <math.h>

#define BB 16
#define TT 512
#define VV 2048
#define DD 512
#define HDD 64
#define LL 6
#define FF 2048
#define BT 8192   // B*T

typedef __hip_bfloat16 bf16;
typedef __attribute__((ext_vector_type(8))) short bf8s;   // 8 bf16 (4 VGPRs)
typedef __attribute__((ext_vector_type(4))) float f4;     // C/D frag

__device__ __forceinline__ float cvt(float x){ return x; }
__device__ __forceinline__ float cvt(bf16 x){ return __bfloat162float(x); }

// async global->LDS, 16B per lane. LDS dest wave-uniform base (+lane*16 by HW).
__device__ __forceinline__ void gl16(const void* g, void* l){
  __builtin_amdgcn_global_load_lds(
      (const __attribute__((address_space(1))) void*)g,
      (__attribute__((address_space(3))) void*)l,
      16, 0, 0);
}

// ---------------- dtype flag ----------------
__global__ void k_flag(const void* g1, int* flagp){
  if(threadIdx.x==0 && blockIdx.x==0){
    const unsigned short* u = (const unsigned short*)g1;
    *flagp = (u[0] == 0) ? 1 : 0;   // 1 = inputs f32, 0 = bf16
  }
}

// ---------------- one-shot convert of all small tensors + QKV bias pack ----------------
__global__ __launch_bounds__(256) void k_cvt_all(
    const void* rel, const void* bo, const void* g1, const void* be1,
    const void* g2, const void* be2, const void* b1, const void* b2,
    const void* bout, const void* bq, const void* bk, const void* bv,
    bf16* d_rel, bf16* d_bo, bf16* d_g1, bf16* d_be1,
    bf16* d_g2, bf16* d_be2, bf16* d_b1, bf16* d_b2,
    bf16* d_bout, bf16* d_bqkv, const int* __restrict__ flagp){
  int i = blockIdx.x*256 + threadIdx.x;
  bool isf = *flagp;
  auto ld = [&](const void* s, int k)->float{
    return isf ? ((const float*)s)[k] : cvt(((const bf16*)s)[k]);
  };
  if(i < 12672){ d_rel[i] = (bf16)ld(rel, i); return; } i -= 12672;
  if(i < 3072){ d_bo[i]  = (bf16)ld(bo, i);  return; } i -= 3072;
  if(i < 3072){ d_g1[i]  = (bf16)ld(g1, i);  return; } i -= 3072;
  if(i < 3072){ d_be1[i] = (bf16)ld(be1, i); return; } i -= 3072;
  if(i < 3072){ d_g2[i]  = (bf16)ld(g2, i);  return; } i -= 3072;
  if(i < 3072){ d_be2[i] = (bf16)ld(be2, i); return; } i -= 3072;
  if(i < 12288){ d_b1[i] = (bf16)ld(b1, i);  return; } i -= 12288;
  if(i < 3072){ d_b2[i]  = (bf16)ld(b2, i);  return; } i -= 3072;
  if(i < 2048){ d_bout[i]= (bf16)ld(bout, i);return; } i -= 2048;
  if(i < 384){ int l=i>>6, hh=i&63; d_bqkv[l*192 + hh]       = (bf16)ld(bq, i); return; } i -= 384;
  if(i < 384){ int l=i>>6, hh=i&63; d_bqkv[l*192 + 64 + hh]  = (bf16)ld(bk, i); return; } i -= 384;
  if(i < 384){ int l=i>>6, hh=i&63; d_bqkv[l*192 + 128 + hh] = (bf16)ld(bv, i); return; }
}

// ---------------- tiled transpose: src [z][R][C] -> dst [z][C][R(ldD)] bf16 ----------------
__global__ __launch_bounds__(256) void k_tr(const void* __restrict__ src, bf16* __restrict__ dst,
                                            int R, int C, long long sS, long long sD, int ldD,
                                            const int* __restrict__ flagp){
  __shared__ bf16 t[32][33];
  int z = blockIdx.z;
  int c0 = blockIdx.x*32, r0 = blockIdx.y*32;
  int tx = threadIdx.x & 31, ty = threadIdx.x >> 5;
  bool isf = flagp && (*flagp);
  const float* sf = (const float*)src;
  const bf16*  sb = (const bf16*)src;
  for(int i=ty; i<32; i+=8){
    size_t off = (size_t)z*sS + (size_t)(r0+i)*C + (c0+tx);
    float v = isf ? sf[off] : cvt(sb[off]);
    t[i][tx] = (bf16)v;
  }
  __syncthreads();
  for(int i=ty; i<32; i+=8){
    dst[(size_t)z*sD + (size_t)(c0+i)*ldD + (r0+tx)] = t[tx][i];
  }
}

// ---------------- all QKV weights in one launch: z = l*3+j, [512][64] -> [l][j][64][512] ----------------
__global__ __launch_bounds__(256) void k_tr3(const void* __restrict__ Wq, const void* __restrict__ Wk,
                                             const void* __restrict__ Wv, bf16* __restrict__ dst,
                                             const int* __restrict__ flagp){
  __shared__ bf16 t[32][33];
  int z = blockIdx.z;
  int j = z % 3, lz = z / 3;
  const void* src = (j==0) ? Wq : ((j==1) ? Wk : Wv);
  int c0 = blockIdx.x*32, r0 = blockIdx.y*32;
  int tx = threadIdx.x & 31, ty = threadIdx.x >> 5;
  bool isf = (*flagp);
  const float* sf = (const float*)src;
  const bf16*  sb = (const bf16*)src;
  for(int i=ty; i<32; i+=8){
    size_t off = (size_t)lz*512*64 + (size_t)(r0+i)*64 + (c0+tx);
    float v = isf ? sf[off] : cvt(sb[off]);
    t[i][tx] = (bf16)v;
  }
  __syncthreads();
  for(int i=ty; i<32; i+=8){
    dst[(size_t)lz*3*64*512 + (size_t)j*64*512 + (size_t)(c0+i)*512 + (r0+tx)] = t[tx][i];
  }
}

// ---------------- wsT_all[l][d][h] = sum_n Wo[l][n*64+h][d] ----------------
__global__ __launch_bounds__(256) void k_wsumT(const void* __restrict__ Wo,
                                               bf16* __restrict__ wsT,
                                               const int* __restrict__ flagp){
  int i = blockIdx.x*256 + threadIdx.x;
  if(i >= LL*64*512) return;
  int l = i >> 15, j = i & 32767, hh = j>>9, d = j&511;
  size_t loff = (size_t)l*512*512;
  bool isf = *flagp;
  float a = 0.f;
  #pragma unroll
  for(int n=0;n<8;++n){
    size_t idx = loff + (size_t)(n*64+hh)*512 + d;
    a += isf ? ((const float*)Wo)[idx] : cvt(((const bf16*)Wo)[idx]);
  }
  wsT[(size_t)l*32768 + d*64 + hh] = (bf16)a;
}

// ---------------- embed + positional encoding ----------------
__global__ __launch_bounds__(256) void k_embed(const int* __restrict__ idx,
                                               const void* __restrict__ emb,
                                               float* __restrict__ h,
                                               const int* __restrict__ flagp){
  int r = blockIdx.x;
  int t = r & (TT-1);
  int tok = idx[r];
  bool isf = *flagp;
  for(int d = threadIdx.x; d < DD; d += 256){
    int p = d >> 1;
    float ang = (float)t * powf(10000.f, -(float)p * (1.f/128.f));
    float pe = (d & 1) ? cosf(ang) : sinf(ang);
    size_t off = (size_t)tok*DD + d;
    float ev = isf ? ((const float*)emb)[off] : cvt(((const bf16*)emb)[off]);
    h[(size_t)r*DD + d] = 2.f*ev + pe;
  }
}

// =====================  MFMA GEMM  =====================
// CMODE: 0 bf16 store, 1 f32 store, 2 dual via flag, 3 = f32-resid read + bf16 store to vtr.
template<int BM,int BN,int WM,int WN,int CMODE,bool RELU,bool RESID,bool TRV>
__global__ __launch_bounds__(WM*WN*64) void mm(const bf16* __restrict__ A,
                                          const bf16* __restrict__ Bt,
                                          void* __restrict__ Cv,
                                          const bf16* __restrict__ bias,
                                          int M, int N, int K,
                                          long long sA, long long sB, long long sC, int sBias,
                                          int gx,
                                          const int* __restrict__ flagp,
                                          bf16* __restrict__ vtr){
  constexpr int BK  = 64;
  constexpr int NT  = WM*WN*64;
  constexpr int FM  = BM/(WM*16);
  constexpr int FN  = BN/(WN*16);
  constexpr int S   = (BM+BN)*BK;
  constexpr int CAW = (BM*BK/512)/(NT/64);
  constexpr int CBW = (BN*BK/512)/(NT/64);
  __shared__ bf16 lds[2*S];
  int nwg = gridDim.x, bid = blockIdx.x;
  int q = nwg>>3, rr = nwg&7, xcd = bid&7, ii = bid>>3;
  int wg = (xcd<rr ? xcd*(q+1) : rr*(q+1)+(xcd-rr)*q) + ii;
  int bx = wg % gx, by = wg / gx;
  int z = blockIdx.z;
  A  += (size_t)z*sA;
  Bt += (size_t)z*sB;
  if(bias) bias += (size_t)z*sBias;
  int tid = threadIdx.x, lane = tid&63, w = tid>>6;
  int m0 = by*BM, n0 = bx*BN;
  int wrow = (w/WN)*(FM*16), wcol = (w%WN)*(FN*16);
  int l15 = lane&15, l4 = lane>>4;
  int lrow = lane>>3, lgr = lane&7;
  int nk = K/BK;
  auto stage = [&](int kt, int buf){
    bf16* Ab = lds + buf*S;
    bf16* Bb = Ab + BM*BK;
    const bf16* gA = A + (size_t)m0*K + kt*BK;
    const bf16* gB = Bt + (size_t)n0*K + kt*BK;
    #pragma unroll
    for(int i=0;i<CAW;++i){
      int chunk = w*CAW + i;
      int row = chunk*8 + lrow;
      gl16(gA + (size_t)row*K + ((lgr ^ (row&7))*8), Ab + chunk*512);
    }
    #pragma unroll
    for(int i=0;i<CBW;++i){
      int chunk = w*CBW + i;
      int row = chunk*8 + lrow;
      gl16(gB + (size_t)row*K + ((lgr ^ (row&7))*8), Bb + chunk*512);
    }
  };
  f4 acc[FM][FN] = {};
  stage(0, 0);
  __syncthreads();
  for(int kt=0; kt<nk; ++kt){
    int cur = kt & 1;
    if(kt+1 < nk) stage(kt+1, cur^1);
    const bf16* Ab = lds + cur*S;
    const bf16* Bb = Ab + BM*BK;
    #pragma unroll
    for(int g=0; g<2; ++g){
      bf8s af[FM], bfv[FN];
      #pragma unroll
      for(int i=0;i<FM;++i){
        int r = wrow + i*16 + l15;
        af[i] = *(const bf8s*)(Ab + r*BK + (((g*4+l4) ^ (r&7))*8));
      }
      #pragma unroll
      for(int j=0;j<FN;++j){
        int r = wcol + j*16 + l15;
        bfv[j] = *(const bf8s*)(Bb + r*BK + (((g*4+l4) ^ (r&7))*8));
      }
      #pragma unroll
      for(int i=0;i<FM;++i)
        #pragma unroll
        for(int j=0;j<FN;++j)
          acc[i][j] = __builtin_amdgcn_mfma_f32_16x16x32_bf16(af[i], bfv[j], acc[i][j], 0,0,0);
    }
    __syncthreads();
  }
  bool f32o = (CMODE==2) ? (*flagp != 0) : (CMODE==1);
  bool trv = TRV && (z == 2);
  #pragma unroll
  for(int i=0;i<FM;++i){
    #pragma unroll
    for(int j=0;j<FN;++j){
      int col = n0 + wcol + j*16 + l15;
      float bv = bias ? cvt(bias[col]) : 0.f;
      #pragma unroll
      for(int q2=0;q2<4;++q2){
        int row = m0 + wrow + i*16 + l4*4 + q2;
        float v = acc[i][j][q2] + bv;
        if(trv){
          int b = row >> 9, t = row & 511;
          vtr[(size_t)b*(64*512) + (size_t)col*512 + t] = (bf16)v;
          continue;
        }
        size_t off = (size_t)z*sC + (size_t)row*N + col;
        if(RESID) v += ((const float*)Cv)[off];
        if(RELU)  v = fmaxf(v, 0.f);
        if(CMODE==0)      ((bf16*)Cv)[off] = (bf16)v;
        else if(CMODE==1) ((float*)Cv)[off] = v;
        else if(CMODE==3) vtr[off] = (bf16)v;   // resid-read f32, bf16 store (no h write)
        else { if(f32o) ((float*)Cv)[off] = v; else ((bf16*)Cv)[off] = (bf16)v; }
      }
    }
  }
}

// =====================  FUSED LN1 + QKV (+V transpose)  =====================
// Block = 32 rows (grid 256). Phase 0: per-thread 64-col h segment, 8-lane shfl row
// stats, normalize -> bf16 y-tile in LDS with the mm granule-XOR swizzle (slot
// g^(row&7) holds granule g). Phase 1: QKV GEMM, A-frags from LDS (mm read pattern),
// B-frags streamed from L2-resident WqkvT [192][512]; Q/K stored planar, V transposed.
__global__ __launch_bounds__(256) void k_lnqkv(const float* __restrict__ h,
                                               const bf16* __restrict__ g,
                                               const bf16* __restrict__ be,
                                               const bf16* __restrict__ Wt,   // [192][512]
                                               const bf16* __restrict__ bqkv, // [192]
                                               bf16* __restrict__ QKV,
                                               bf16* __restrict__ VbT){
  __shared__ bf16 Al[32*512];
  int m0 = blockIdx.x*32;
  int tid = threadIdx.x, lane = tid&63, w = tid>>6;
  int l15 = lane&15, l4 = lane>>4;
  int row = tid>>3, s8 = tid&7;       // row 0..31, 64-col segment 0..7
  const float* hr = h + (size_t)(m0+row)*512 + s8*64;
  float hv[64];
  float s=0.f, s2=0.f;
  #pragma unroll
  for(int i=0;i<64;++i){ float v = hr[i]; hv[i]=v; s+=v; s2+=v*v; }
  s += __shfl_xor(s,1); s2 += __shfl_xor(s2,1);
  s += __shfl_xor(s,2); s2 += __shfl_xor(s2,2);
  s += __shfl_xor(s,4); s2 += __shfl_xor(s2,4);
  float mean = s*(1.f/512.f);
  float var  = s2*(1.f/512.f) - mean*mean;
  float inv  = rsqrtf(var + 1e-5f);
  #pragma unroll
  for(int j=0;j<8;++j){
    int gidx = s8*8 + j;              // granule 0..63
    bf8s pack;
    #pragma unroll
    for(int e=0;e<8;++e){
      int col = s8*64 + j*8 + e;
      bf16 yb = (bf16)((hv[j*8+e]-mean)*inv*cvt(g[col]) + cvt(be[col]));
      short sb; __builtin_memcpy(&sb, &yb, 2);
      pack[e] = sb;
    }
    *(bf8s*)(&Al[row*512 + ((gidx ^ (row&7))*8)]) = pack;
  }
  __syncthreads();
  // GEMM: wave w owns n-tiles w*3 + {0,1,2} (N=192), K=512 in 16 chunks of 32
  f4 acc[2][3] = {};
  for(int kc=0; kc<16; ++kc){
    bf8s af[2];
    #pragma unroll
    for(int i=0;i<2;++i){
      int r = i*16 + l15;
      af[i] = *(const bf8s*)(&Al[r*512 + (((kc*4+l4) ^ (r&7))*8)]);
    }
    #pragma unroll
    for(int j=0;j<3;++j){
      int n = (w*3+j)*16 + l15;
      bf8s bv = *(const bf8s*)(Wt + (size_t)n*512 + kc*32 + l4*8);
      #pragma unroll
      for(int i=0;i<2;++i)
        acc[i][j] = __builtin_amdgcn_mfma_f32_16x16x32_bf16(af[i], bv, acc[i][j], 0,0,0);
    }
  }
  #pragma unroll
  for(int j=0;j<3;++j){
    int n = (w*3+j)*16 + l15;
    int plane = n >> 6, hh = n & 63;
    float bias = cvt(bqkv[n]);
    #pragma unroll
    for(int i=0;i<2;++i){
      #pragma unroll
      for(int q=0;q<4;++q){
        int rg = m0 + i*16 + l4*4 + q;
        float v = acc[i][j][q] + bias;
        if(plane == 2){
          int b = rg >> 9, t = rg & 511;
          VbT[(size_t)b*64*512 + (size_t)hh*512 + t] = (bf16)v;
        } else {
          QKV[(size_t)plane*BT*64 + (size_t)rg*64 + hh] = (bf16)v;
        }
      }
    }
  }
}

// =====================  FUSED ATTENTION + PROJ + RESID + LN2 (unchanged)  =====================
__global__ __launch_bounds__(256) void k_attnproj(const bf16* __restrict__ Q,
                                                  const bf16* __restrict__ K,
                                                  const bf16* __restrict__ VbT,
                                                  const bf16* __restrict__ rel,  // [33][64]
                                                  const bf16* __restrict__ wsT,  // [512][64]
                                                  const bf16* __restrict__ bo,
                                                  const bf16* __restrict__ g,
                                                  const bf16* __restrict__ be,
                                                  float* __restrict__ h,
                                                  bf16* __restrict__ y){
  int ti = blockIdx.x, b = blockIdx.y;
  int t0 = ti*16;
  int tid = threadIdx.x, lane = tid & 63, wc = tid >> 6;   // wc in 0..3
  int l15 = lane & 15, l4 = lane >> 4;
  __shared__ bf16  Plds[16][520];
  __shared__ bf16  vlds[16][68];
  __shared__ float qrs[16][17];
  __shared__ float amlds[16][17];
  __shared__ float redmx[4][16];
  __shared__ float redsum[4][16];
  __shared__ float rs[4][16], rs2[4][16];
  int nj = ti + 1;                    // 16-col s-tiles (causal)
  int KC = (nj*16 + 31) >> 5;         // 32-wide PV k-chunks

  const bf16* Qb = Q + ((size_t)b*512 + t0)*64;
  const bf16* Kb = K + (size_t)b*512*64;
  const bf16* Vb = VbT + (size_t)b*64*512;

  for(int i=tid; i<16*17; i+=256) ((float*)amlds)[i] = 0.f;
  if(nj & 1) Plds[tid>>4][nj*16 + (tid&15)] = (bf16)0.f;   // zero trailing tile

  bf8s af0 = *(const bf8s*)(Qb + (size_t)l15*64 + l4*8);
  bf8s af1 = *(const bf8s*)(Qb + (size_t)l15*64 + 32 + l4*8);

  if(wc < 2){
    f4 qa = {};
    bf8s r0 = *(const bf8s*)(rel + (size_t)(wc*16+l15)*64 + l4*8);
    bf8s r1 = *(const bf8s*)(rel + (size_t)(wc*16+l15)*64 + 32 + l4*8);
    qa = __builtin_amdgcn_mfma_f32_16x16x32_bf16(af0, r0, qa, 0,0,0);
    qa = __builtin_amdgcn_mfma_f32_16x16x32_bf16(af1, r1, qa, 0,0,0);
    int m = wc*16 + l15;
    if(m < 17){
      #pragma unroll
      for(int q=0;q<4;++q) qrs[l4*4+q][m] = qa[q];
    }
  }
  __syncthreads();

  float mx4[4] = {-INFINITY,-INFINITY,-INFINITY,-INFINITY};
  for(int j=wc; j<nj; j+=4){
    f4 sa = {};
    const bf16* kr = Kb + (size_t)(j*16+l15)*64;
    bf8s k0 = *(const bf8s*)(kr + l4*8);
    bf8s k1 = *(const bf8s*)(kr + 32 + l4*8);
    sa = __builtin_amdgcn_mfma_f32_16x16x32_bf16(af0, k0, sa, 0,0,0);
    sa = __builtin_amdgcn_mfma_f32_16x16x32_bf16(af1, k1, sa, 0,0,0);
    int s = j*16 + l15;
    #pragma unroll
    for(int q=0;q<4;++q){
      int row = l4*4+q, t = t0+row;
      float sp = -1e30f;
      if(s <= t){
        int m = s - t + 16; m = m < 0 ? 0 : m;
        sp = (sa[q] + qrs[row][m])*0.125f;
        mx4[q] = fmaxf(mx4[q], sp);
      }
      Plds[row][s] = (bf16)sp;
    }
  }
  #pragma unroll
  for(int q=0;q<4;++q){
    float m = mx4[q];
    m = fmaxf(m, __shfl_xor(m,1)); m = fmaxf(m, __shfl_xor(m,2));
    m = fmaxf(m, __shfl_xor(m,4)); m = fmaxf(m, __shfl_xor(m,8));
    mx4[q] = m;
  }
  if(l15==0){
    #pragma unroll
    for(int q=0;q<4;++q) redmx[wc][l4*4+q] = mx4[q];
  }
  __syncthreads();

  float mxg[4], sum4[4] = {0.f,0.f,0.f,0.f};
  #pragma unroll
  for(int q=0;q<4;++q){
    int rloc = l4*4+q;
    mxg[q] = fmaxf(fmaxf(redmx[0][rloc], redmx[1][rloc]),
                   fmaxf(redmx[2][rloc], redmx[3][rloc]));
  }
  for(int j=wc; j<nj; j+=4){
    int s = j*16 + l15;
    #pragma unroll
    for(int q=0;q<4;++q){
      int row = l4*4+q, t = t0+row;
      float e = expf(cvt(Plds[row][s]) - mxg[q]);   // masked: exp(-1e30-mx)=0
      Plds[row][s] = (bf16)e;
      sum4[q] += e;
      int m = s - t + 16;
      if(m >= 1 && m <= 16) amlds[row][m] = e;      // unique owner
    }
  }
  #pragma unroll
  for(int q=0;q<4;++q){
    float s = sum4[q];
    s += __shfl_xor(s,1); s += __shfl_xor(s,2);
    s += __shfl_xor(s,4); s += __shfl_xor(s,8);
    sum4[q] = s;
  }
  if(l15==0){
    #pragma unroll
    for(int q=0;q<4;++q) redsum[wc][l4*4+q] = sum4[q];
  }
  __syncthreads();

  f4 pacc = {0,0,0,0};
  for(int ks=0; ks<KC; ++ks){
    bf8s ap = *(const bf8s*)(&Plds[l15][ks*32 + l4*8]);
    bf8s bv = *(const bf8s*)(Vb + (size_t)(wc*16+l15)*512 + ks*32 + l4*8);
    pacc = __builtin_amdgcn_mfma_f32_16x16x32_bf16(ap, bv, pacc, 0,0,0);
  }
  #pragma unroll
  for(int q=0;q<4;++q){
    int row = l4*4+q;
    float sum = redsum[0][row]+redsum[1][row]+redsum[2][row]+redsum[3][row];
    float rsv = 1.f/sum;
    float a[16];
    float amsum = 0.f;
    #pragma unroll
    for(int m=1;m<=16;++m){ a[m-1] = amlds[row][m]; amsum += a[m-1]; }
    float am0 = sum - amsum;
    int hh = wc*16 + l15;
    float acc = pacc[q] + am0*cvt(rel[hh]);
    #pragma unroll
    for(int m=1;m<=16;++m) acc += a[m-1]*cvt(rel[m*64 + hh]);
    vlds[row][hh] = (bf16)(acc*rsv);
  }
  __syncthreads();

  // ---- Phase B: proj (vals @ wsT^T) + bo + resid -> h; LN2 -> y ----
  bf8s pa0 = *(const bf8s*)(&vlds[l15][l4*8]);
  bf8s pa1 = *(const bf8s*)(&vlds[l15][32 + l4*8]);
  f4 acc2[8] = {};
  #pragma unroll
  for(int j=0;j<8;++j){
    int nn = wc*8 + j;
    bf8s bv0 = *(const bf8s*)(wsT + (size_t)(nn*16+l15)*64 + l4*8);
    bf8s bv1 = *(const bf8s*)(wsT + (size_t)(nn*16+l15)*64 + 32 + l4*8);
    acc2[j] = __builtin_amdgcn_mfma_f32_16x16x32_bf16(pa0, bv0, acc2[j], 0,0,0);
    acc2[j] = __builtin_amdgcn_mfma_f32_16x16x32_bf16(pa1, bv1, acc2[j], 0,0,0);
  }
  float s4[4] = {0,0,0,0}, s24[4] = {0,0,0,0};
  #pragma unroll
  for(int j=0;j<8;++j){
    int col = (wc*8+j)*16 + l15;
    float bv = cvt(bo[col]);
    #pragma unroll
    for(int q=0;q<4;++q){
      int row = t0 + l4*4 + q;
      size_t off = ((size_t)b*512 + row)*512 + col;
      float v = acc2[j][q] + bv + h[off];
      acc2[j][q] = v;
      h[off] = v;
      s4[q] += v; s24[q] += v*v;
    }
  }
  #pragma unroll
  for(int q=0;q<4;++q){
    #pragma unroll
    for(int o=1;o<16;o<<=1){ s4[q] += __shfl_xor(s4[q],o); s24[q] += __shfl_xor(s24[q],o); }
    if(l15==0){ rs[wc][l4*4+q] = s4[q]; rs2[wc][l4*4+q] = s24[q]; }
  }
  __syncthreads();
  #pragma unroll
  for(int q=0;q<4;++q){
    int rloc = l4*4+q;
    float a  = rs[0][rloc]+rs[1][rloc]+rs[2][rloc]+rs[3][rloc];
    float a2 = rs2[0][rloc]+rs2[1][rloc]+rs2[2][rloc]+rs2[3][rloc];
    float mean = a*(1.f/512.f);
    float var  = a2*(1.f/512.f) - mean*mean;
    float inv  = rsqrtf(var + 1e-5f);
    int row = t0 + rloc;
    #pragma unroll
    for(int j=0;j<8;++j){
      int col = (wc*8+j)*16 + l15;
      y[((size_t)b*512 + row)*512 + col] =
          (bf16)((acc2[j][q]-mean)*inv*cvt(g[col]) + cvt(be[col]));
    }
  }
}

extern "C" void kernel_launch(void* const* d_in, const int* in_sizes, int n_in,
                              void* d_out, int out_size, void* d_ws, size_t ws_size,
                              hipStream_t stream){
  const int* idx = (const int*)d_in[0];

  char* p = (char*)d_ws;
  auto alloc = [&](size_t bytes)->char*{ char* r = p; p += (bytes + 255) & ~(size_t)255; return r; };

  int*  flag  = (int*)alloc(4);
  bf16* rel_b = (bf16*)alloc(12672*2);
  bf16* bo_b  = (bf16*)alloc(3072*2);
  bf16* g1_b  = (bf16*)alloc(3072*2);
  bf16* be1_b = (bf16*)alloc(3072*2);
  bf16* g2_b  = (bf16*)alloc(3072*2);
  bf16* be2_b = (bf16*)alloc(3072*2);
  bf16* b1_b  = (bf16*)alloc(12288*2);
  bf16* b2_b  = (bf16*)alloc(3072*2);
  bf16* bout_b= (bf16*)alloc(2048*2);
  bf16* bqkv  = (bf16*)alloc(LL*192*2);
  bf16* WqkvT = (bf16*)alloc((size_t)LL*3*64*512*2);    // [L][3][64][512] = [L][192][512]
  bf16* W1T   = (bf16*)alloc((size_t)LL*2048*512*2);    // [L][2048][512]
  bf16* W2T   = (bf16*)alloc((size_t)LL*512*2048*2);    // [L][512][2048]
  bf16* WoutT = (bf16*)alloc((size_t)2048*512*2);       // [2048][512]
  bf16* wsT_all=(bf16*)alloc((size_t)LL*512*64*2);      // [L][512][64]
  float* h    = (float*)alloc((size_t)BT*DD*4);         // 16 MB
  bf16*  y    = (bf16*) alloc((size_t)BT*DD*2);         //  8 MB (ln2 out)
  bf16*  hb   = y;                                      // last-FFN2 bf16 out (y dead by then)
  bf16*  QKV  = (bf16*) alloc((size_t)3*BT*64*2);       // Q|K planes (V unused slot kept)
  bf16*  VbT  = (bf16*) alloc((size_t)BB*64*512*2);     // [16][64][512]
  bf16*  mid  = (bf16*)d_out;                           // FFN scratch in d_out
  bf16*  Qb = QKV, *Kb = QKV + (size_t)BT*64;

  // ---- setup ----
  k_flag<<<1,64,0,stream>>>(d_in[11], flag);
  k_cvt_all<<<(46592+255)/256,256,0,stream>>>(
      d_in[8], d_in[10], d_in[11], d_in[12], d_in[13], d_in[14],
      d_in[16], d_in[18], d_in[20], d_in[3], d_in[5], d_in[7],
      rel_b, bo_b, g1_b, be1_b, g2_b, be2_b, b1_b, b2_b, bout_b, bqkv, flag);
  k_tr3<<<dim3(2,16,3*LL),256,0,stream>>>(d_in[2], d_in[4], d_in[6], WqkvT, flag);
  k_tr<<<dim3(64,16,LL),256,0,stream>>>(d_in[15], W1T, 512, 2048, 512*2048, 2048*512, 512, flag);
  k_tr<<<dim3(16,64,LL),256,0,stream>>>(d_in[17], W2T, 2048, 512, 2048*512, 512*2048, 2048, flag);
  k_tr<<<dim3(64,16,1),256,0,stream>>>(d_in[19], WoutT, 512, 2048, 0, 0, 512, flag);
  k_wsumT<<<(LL*32768+255)/256,256,0,stream>>>(d_in[9], wsT_all, flag);

  k_embed<<<BT,256,0,stream>>>(idx, d_in[1], h, flag);

  for(int l=0; l<LL; ++l){
    // fused LN1 + QKV (+V transpose)
    k_lnqkv<<<256,256,0,stream>>>(h, g1_b+l*DD, be1_b+l*DD,
                                  WqkvT + (size_t)l*3*64*512, bqkv + l*192, QKV, VbT);
    // fused attn + proj + resid + LN2 -> h, y
    k_attnproj<<<dim3(32,16),256,0,stream>>>(Qb, Kb, VbT, rel_b + l*33*64,
                                             wsT_all + (size_t)l*32768,
                                             bo_b + l*DD, g2_b + l*DD, be2_b + l*DD, h, y);
    // mid = relu(y @ W1 + b1)   (bf16, d_out scratch) — 128x128 tile
    mm<128,128,2,2,0,true,false,false><<<dim3(1024,1,1),256,0,stream>>>(
        y, W1T + (size_t)l*2048*512, mid, b1_b + l*FF, BT, 2048, 512, 0,0,0,0, 16, nullptr, nullptr);
    if(l < LL-1){
      // h += mid @ W2 + b2 (f32)
      mm<128,64,4,1,1,false,true,false><<<dim3(512,1,1),256,0,stream>>>(
          mid, W2T + (size_t)l*512*2048, h, b2_b + l*DD, BT, 512, 2048, 0,0,0,0, 8, nullptr, nullptr);
    } else {
      // last layer: h-resid read + bf16 store straight to hb
      mm<128,64,4,1,3,false,true,false><<<dim3(512,1,1),256,0,stream>>>(
          mid, W2T + (size_t)l*512*2048, h, b2_b + l*DD, BT, 512, 2048, 0,0,0,0, 8, nullptr, hb);
    }
  }
  // out = hb @ Wout + bout (dual store per flag) — 128x128 tile
  mm<128,128,2,2,2,false,false,false><<<dim3(1024,1,1),256,0,stream>>>(
      hb, WoutT, d_out, bout_b, BT, 2048, 512, 0,0,0,0, 16, flag, nullptr);
}

// Round 16
// 705.027 us; speedup vs baseline: 1.6267x; 1.0137x over previous
//
#include <hip/hip_runtime.h>
#include <hip/hip_bf16.h>
#include <math.h>

#define BB 16
#define TT 512
#define VV 2048
#define DD 512
#define HDD 64
#define LL 6
#define FF 2048
#define BT 8192   // B*T

typedef __hip_bfloat16 bf16;
typedef __attribute__((ext_vector_type(8))) short bf8s;   // 8 bf16 (4 VGPRs)
typedef __attribute__((ext_vector_type(4))) float f4;     // C/D frag

__device__ __forceinline__ float cvt(float x){ return x; }
__device__ __forceinline__ float cvt(bf16 x){ return __bfloat162float(x); }

// async global->LDS, 16B per lane. LDS dest wave-uniform base (+lane*16 by HW).
__device__ __forceinline__ void gl16(const void* g, void* l){
  __builtin_amdgcn_global_load_lds(
      (const __attribute__((address_space(1))) void*)g,
      (__attribute__((address_space(3))) void*)l,
      16, 0, 0);
}

// ---------------- dtype flag ----------------
__global__ void k_flag(const void* g1, int* flagp){
  if(threadIdx.x==0 && blockIdx.x==0){
    const unsigned short* u = (const unsigned short*)g1;
    *flagp = (u[0] == 0) ? 1 : 0;   // 1 = inputs f32, 0 = bf16
  }
}

// ---------------- one-shot convert of all small tensors + QKV bias pack ----------------
__global__ __launch_bounds__(256) void k_cvt_all(
    const void* rel, const void* bo, const void* g1, const void* be1,
    const void* g2, const void* be2, const void* b1, const void* b2,
    const void* bout, const void* bq, const void* bk, const void* bv,
    bf16* d_rel, bf16* d_bo, bf16* d_g1, bf16* d_be1,
    bf16* d_g2, bf16* d_be2, bf16* d_b1, bf16* d_b2,
    bf16* d_bout, bf16* d_bqkv, const int* __restrict__ flagp){
  int i = blockIdx.x*256 + threadIdx.x;
  bool isf = *flagp;
  auto ld = [&](const void* s, int k)->float{
    return isf ? ((const float*)s)[k] : cvt(((const bf16*)s)[k]);
  };
  if(i < 12672){ d_rel[i] = (bf16)ld(rel, i); return; } i -= 12672;
  if(i < 3072){ d_bo[i]  = (bf16)ld(bo, i);  return; } i -= 3072;
  if(i < 3072){ d_g1[i]  = (bf16)ld(g1, i);  return; } i -= 3072;
  if(i < 3072){ d_be1[i] = (bf16)ld(be1, i); return; } i -= 3072;
  if(i < 3072){ d_g2[i]  = (bf16)ld(g2, i);  return; } i -= 3072;
  if(i < 3072){ d_be2[i] = (bf16)ld(be2, i); return; } i -= 3072;
  if(i < 12288){ d_b1[i] = (bf16)ld(b1, i);  return; } i -= 12288;
  if(i < 3072){ d_b2[i]  = (bf16)ld(b2, i);  return; } i -= 3072;
  if(i < 2048){ d_bout[i]= (bf16)ld(bout, i);return; } i -= 2048;
  if(i < 384){ int l=i>>6, hh=i&63; d_bqkv[l*192 + hh]       = (bf16)ld(bq, i); return; } i -= 384;
  if(i < 384){ int l=i>>6, hh=i&63; d_bqkv[l*192 + 64 + hh]  = (bf16)ld(bk, i); return; } i -= 384;
  if(i < 384){ int l=i>>6, hh=i&63; d_bqkv[l*192 + 128 + hh] = (bf16)ld(bv, i); return; }
}

// ---------------- positional-encoding table: pe[t][d], bitwise-identical expr ----------------
__global__ __launch_bounds__(256) void k_petab(float* __restrict__ pe){
  int t = blockIdx.x;
  for(int d = threadIdx.x; d < DD; d += 256){
    int p = d >> 1;
    float ang = (float)t * powf(10000.f, -(float)p * (1.f/128.f));
    pe[(size_t)t*DD + d] = (d & 1) ? cosf(ang) : sinf(ang);
  }
}

// ---------------- tiled transpose: src [z][R][C] -> dst [z][C][R(ldD)] bf16 ----------------
__global__ __launch_bounds__(256) void k_tr(const void* __restrict__ src, bf16* __restrict__ dst,
                                            int R, int C, long long sS, long long sD, int ldD,
                                            const int* __restrict__ flagp){
  __shared__ bf16 t[32][33];
  int z = blockIdx.z;
  int c0 = blockIdx.x*32, r0 = blockIdx.y*32;
  int tx = threadIdx.x & 31, ty = threadIdx.x >> 5;
  bool isf = flagp && (*flagp);
  const float* sf = (const float*)src;
  const bf16*  sb = (const bf16*)src;
  for(int i=ty; i<32; i+=8){
    size_t off = (size_t)z*sS + (size_t)(r0+i)*C + (c0+tx);
    float v = isf ? sf[off] : cvt(sb[off]);
    t[i][tx] = (bf16)v;
  }
  __syncthreads();
  for(int i=ty; i<32; i+=8){
    dst[(size_t)z*sD + (size_t)(c0+i)*ldD + (r0+tx)] = t[tx][i];
  }
}

// ---------------- all QKV weights in one launch: z = l*3+j, [512][64] -> [l][j][64][512] ----------------
__global__ __launch_bounds__(256) void k_tr3(const void* __restrict__ Wq, const void* __restrict__ Wk,
                                             const void* __restrict__ Wv, bf16* __restrict__ dst,
                                             const int* __restrict__ flagp){
  __shared__ bf16 t[32][33];
  int z = blockIdx.z;
  int j = z % 3, lz = z / 3;
  const void* src = (j==0) ? Wq : ((j==1) ? Wk : Wv);
  int c0 = blockIdx.x*32, r0 = blockIdx.y*32;
  int tx = threadIdx.x & 31, ty = threadIdx.x >> 5;
  bool isf = (*flagp);
  const float* sf = (const float*)src;
  const bf16*  sb = (const bf16*)src;
  for(int i=ty; i<32; i+=8){
    size_t off = (size_t)lz*512*64 + (size_t)(r0+i)*64 + (c0+tx);
    float v = isf ? sf[off] : cvt(sb[off]);
    t[i][tx] = (bf16)v;
  }
  __syncthreads();
  for(int i=ty; i<32; i+=8){
    dst[(size_t)lz*3*64*512 + (size_t)j*64*512 + (size_t)(c0+i)*512 + (r0+tx)] = t[tx][i];
  }
}

// ---------------- wsT_all[l][d][h] = sum_n Wo[l][n*64+h][d] ----------------
__global__ __launch_bounds__(256) void k_wsumT(const void* __restrict__ Wo,
                                               bf16* __restrict__ wsT,
                                               const int* __restrict__ flagp){
  int i = blockIdx.x*256 + threadIdx.x;
  if(i >= LL*64*512) return;
  int l = i >> 15, j = i & 32767, hh = j>>9, d = j&511;
  size_t loff = (size_t)l*512*512;
  bool isf = *flagp;
  float a = 0.f;
  #pragma unroll
  for(int n=0;n<8;++n){
    size_t idx = loff + (size_t)(n*64+hh)*512 + d;
    a += isf ? ((const float*)Wo)[idx] : cvt(((const bf16*)Wo)[idx]);
  }
  wsT[(size_t)l*32768 + d*64 + hh] = (bf16)a;
}

// ---------------- embed + positional encoding (pe from table) ----------------
__global__ __launch_bounds__(256) void k_embed(const int* __restrict__ idx,
                                               const void* __restrict__ emb,
                                               const float* __restrict__ pe,
                                               float* __restrict__ h,
                                               const int* __restrict__ flagp){
  int r = blockIdx.x;
  int t = r & (TT-1);
  int tok = idx[r];
  bool isf = *flagp;
  const float* per = pe + (size_t)t*DD;
  #pragma unroll
  for(int k=0;k<2;++k){
    int d = threadIdx.x + k*256;
    size_t off = (size_t)tok*DD + d;
    float ev = isf ? ((const float*)emb)[off] : cvt(((const bf16*)emb)[off]);
    h[(size_t)r*DD + d] = 2.f*ev + per[d];
  }
}

// =====================  MFMA GEMM  =====================
// CMODE: 0 bf16 store, 1 f32 store, 2 dual via flag, 3 = f32-resid read + bf16 store to vtr.
template<int BM,int BN,int WM,int WN,int CMODE,bool RELU,bool RESID,bool TRV>
__global__ __launch_bounds__(WM*WN*64) void mm(const bf16* __restrict__ A,
                                          const bf16* __restrict__ Bt,
                                          void* __restrict__ Cv,
                                          const bf16* __restrict__ bias,
                                          int M, int N, int K,
                                          long long sA, long long sB, long long sC, int sBias,
                                          int gx,
                                          const int* __restrict__ flagp,
                                          bf16* __restrict__ vtr){
  constexpr int BK  = 64;
  constexpr int NT  = WM*WN*64;
  constexpr int FM  = BM/(WM*16);
  constexpr int FN  = BN/(WN*16);
  constexpr int S   = (BM+BN)*BK;
  constexpr int CAW = (BM*BK/512)/(NT/64);
  constexpr int CBW = (BN*BK/512)/(NT/64);
  __shared__ bf16 lds[2*S];
  int nwg = gridDim.x, bid = blockIdx.x;
  int q = nwg>>3, rr = nwg&7, xcd = bid&7, ii = bid>>3;
  int wg = (xcd<rr ? xcd*(q+1) : rr*(q+1)+(xcd-rr)*q) + ii;
  int bx = wg % gx, by = wg / gx;
  int z = blockIdx.z;
  A  += (size_t)z*sA;
  Bt += (size_t)z*sB;
  if(bias) bias += (size_t)z*sBias;
  int tid = threadIdx.x, lane = tid&63, w = tid>>6;
  int m0 = by*BM, n0 = bx*BN;
  int wrow = (w/WN)*(FM*16), wcol = (w%WN)*(FN*16);
  int l15 = lane&15, l4 = lane>>4;
  int lrow = lane>>3, lgr = lane&7;
  int nk = K/BK;
  auto stage = [&](int kt, int buf){
    bf16* Ab = lds + buf*S;
    bf16* Bb = Ab + BM*BK;
    const bf16* gA = A + (size_t)m0*K + kt*BK;
    const bf16* gB = Bt + (size_t)n0*K + kt*BK;
    #pragma unroll
    for(int i=0;i<CAW;++i){
      int chunk = w*CAW + i;
      int row = chunk*8 + lrow;
      gl16(gA + (size_t)row*K + ((lgr ^ (row&7))*8), Ab + chunk*512);
    }
    #pragma unroll
    for(int i=0;i<CBW;++i){
      int chunk = w*CBW + i;
      int row = chunk*8 + lrow;
      gl16(gB + (size_t)row*K + ((lgr ^ (row&7))*8), Bb + chunk*512);
    }
  };
  f4 acc[FM][FN] = {};
  stage(0, 0);
  __syncthreads();
  for(int kt=0; kt<nk; ++kt){
    int cur = kt & 1;
    if(kt+1 < nk) stage(kt+1, cur^1);
    const bf16* Ab = lds + cur*S;
    const bf16* Bb = Ab + BM*BK;
    #pragma unroll
    for(int g=0; g<2; ++g){
      bf8s af[FM], bfv[FN];
      #pragma unroll
      for(int i=0;i<FM;++i){
        int r = wrow + i*16 + l15;
        af[i] = *(const bf8s*)(Ab + r*BK + (((g*4+l4) ^ (r&7))*8));
      }
      #pragma unroll
      for(int j=0;j<FN;++j){
        int r = wcol + j*16 + l15;
        bfv[j] = *(const bf8s*)(Bb + r*BK + (((g*4+l4) ^ (r&7))*8));
      }
      #pragma unroll
      for(int i=0;i<FM;++i)
        #pragma unroll
        for(int j=0;j<FN;++j)
          acc[i][j] = __builtin_amdgcn_mfma_f32_16x16x32_bf16(af[i], bfv[j], acc[i][j], 0,0,0);
    }
    __syncthreads();
  }
  bool f32o = (CMODE==2) ? (*flagp != 0) : (CMODE==1);
  bool trv = TRV && (z == 2);
  #pragma unroll
  for(int i=0;i<FM;++i){
    #pragma unroll
    for(int j=0;j<FN;++j){
      int col = n0 + wcol + j*16 + l15;
      float bv = bias ? cvt(bias[col]) : 0.f;
      #pragma unroll
      for(int q2=0;q2<4;++q2){
        int row = m0 + wrow + i*16 + l4*4 + q2;
        float v = acc[i][j][q2] + bv;
        if(trv){
          int b = row >> 9, t = row & 511;
          vtr[(size_t)b*(64*512) + (size_t)col*512 + t] = (bf16)v;
          continue;
        }
        size_t off = (size_t)z*sC + (size_t)row*N + col;
        if(RESID) v += ((const float*)Cv)[off];
        if(RELU)  v = fmaxf(v, 0.f);
        if(CMODE==0)      ((bf16*)Cv)[off] = (bf16)v;
        else if(CMODE==1) ((float*)Cv)[off] = v;
        else if(CMODE==3) vtr[off] = (bf16)v;   // resid-read f32, bf16 store (no h write)
        else { if(f32o) ((float*)Cv)[off] = v; else ((bf16*)Cv)[off] = (bf16)v; }
      }
    }
  }
}

// =====================  FUSED LN1 + QKV (+V transpose)  =====================
// Phase 0 now uses explicit float4 loads (f4 hv4[16]).
__global__ __launch_bounds__(256) void k_lnqkv(const float* __restrict__ h,
                                               const bf16* __restrict__ g,
                                               const bf16* __restrict__ be,
                                               const bf16* __restrict__ Wt,   // [192][512]
                                               const bf16* __restrict__ bqkv, // [192]
                                               bf16* __restrict__ QKV,
                                               bf16* __restrict__ VbT){
  __shared__ bf16 Al[32*512];
  int m0 = blockIdx.x*32;
  int tid = threadIdx.x, lane = tid&63, w = tid>>6;
  int l15 = lane&15, l4 = lane>>4;
  int row = tid>>3, s8 = tid&7;       // row 0..31, 64-col segment 0..7
  const f4* hr = (const f4*)(h + (size_t)(m0+row)*512 + s8*64);
  f4 hv4[16];
  float s=0.f, s2=0.f;
  #pragma unroll
  for(int i=0;i<16;++i){
    f4 v = hr[i]; hv4[i]=v;
    s  += v[0]+v[1]+v[2]+v[3];
    s2 += v[0]*v[0]+v[1]*v[1]+v[2]*v[2]+v[3]*v[3];
  }
  s += __shfl_xor(s,1); s2 += __shfl_xor(s2,1);
  s += __shfl_xor(s,2); s2 += __shfl_xor(s2,2);
  s += __shfl_xor(s,4); s2 += __shfl_xor(s2,4);
  float mean = s*(1.f/512.f);
  float var  = s2*(1.f/512.f) - mean*mean;
  float inv  = rsqrtf(var + 1e-5f);
  #pragma unroll
  for(int j=0;j<8;++j){
    int gidx = s8*8 + j;              // granule 0..63
    bf8s pack;
    #pragma unroll
    for(int e=0;e<8;++e){
      int col = s8*64 + j*8 + e;
      float hvv = hv4[j*2 + (e>>2)][e&3];
      bf16 yb = (bf16)((hvv-mean)*inv*cvt(g[col]) + cvt(be[col]));
      short sb; __builtin_memcpy(&sb, &yb, 2);
      pack[e] = sb;
    }
    *(bf8s*)(&Al[row*512 + ((gidx ^ (row&7))*8)]) = pack;
  }
  __syncthreads();
  // GEMM: wave w owns n-tiles w*3 + {0,1,2} (N=192), K=512 in 16 chunks of 32
  f4 acc[2][3] = {};
  for(int kc=0; kc<16; ++kc){
    bf8s af[2];
    #pragma unroll
    for(int i=0;i<2;++i){
      int r = i*16 + l15;
      af[i] = *(const bf8s*)(&Al[r*512 + (((kc*4+l4) ^ (r&7))*8)]);
    }
    #pragma unroll
    for(int j=0;j<3;++j){
      int n = (w*3+j)*16 + l15;
      bf8s bv = *(const bf8s*)(Wt + (size_t)n*512 + kc*32 + l4*8);
      #pragma unroll
      for(int i=0;i<2;++i)
        acc[i][j] = __builtin_amdgcn_mfma_f32_16x16x32_bf16(af[i], bv, acc[i][j], 0,0,0);
    }
  }
  #pragma unroll
  for(int j=0;j<3;++j){
    int n = (w*3+j)*16 + l15;
    int plane = n >> 6, hh = n & 63;
    float bias = cvt(bqkv[n]);
    #pragma unroll
    for(int i=0;i<2;++i){
      #pragma unroll
      for(int q=0;q<4;++q){
        int rg = m0 + i*16 + l4*4 + q;
        float v = acc[i][j][q] + bias;
        if(plane == 2){
          int b = rg >> 9, t = rg & 511;
          VbT[(size_t)b*64*512 + (size_t)hh*512 + t] = (bf16)v;
        } else {
          QKV[(size_t)plane*BT*64 + (size_t)rg*64 + hh] = (bf16)v;
        }
      }
    }
  }
}

// =====================  FUSED ATTENTION + PROJ + RESID + LN2 (unchanged)  =====================
__global__ __launch_bounds__(256) void k_attnproj(const bf16* __restrict__ Q,
                                                  const bf16* __restrict__ K,
                                                  const bf16* __restrict__ VbT,
                                                  const bf16* __restrict__ rel,  // [33][64]
                                                  const bf16* __restrict__ wsT,  // [512][64]
                                                  const bf16* __restrict__ bo,
                                                  const bf16* __restrict__ g,
                                                  const bf16* __restrict__ be,
                                                  float* __restrict__ h,
                                                  bf16* __restrict__ y){
  int ti = blockIdx.x, b = blockIdx.y;
  int t0 = ti*16;
  int tid = threadIdx.x, lane = tid & 63, wc = tid >> 6;   // wc in 0..3
  int l15 = lane & 15, l4 = lane >> 4;
  __shared__ bf16  Plds[16][520];
  __shared__ bf16  vlds[16][68];
  __shared__ float qrs[16][17];
  __shared__ float amlds[16][17];
  __shared__ float redmx[4][16];
  __shared__ float redsum[4][16];
  __shared__ float rs[4][16], rs2[4][16];
  int nj = ti + 1;                    // 16-col s-tiles (causal)
  int KC = (nj*16 + 31) >> 5;         // 32-wide PV k-chunks

  const bf16* Qb = Q + ((size_t)b*512 + t0)*64;
  const bf16* Kb = K + (size_t)b*512*64;
  const bf16* Vb = VbT + (size_t)b*64*512;

  for(int i=tid; i<16*17; i+=256) ((float*)amlds)[i] = 0.f;
  if(nj & 1) Plds[tid>>4][nj*16 + (tid&15)] = (bf16)0.f;   // zero trailing tile

  bf8s af0 = *(const bf8s*)(Qb + (size_t)l15*64 + l4*8);
  bf8s af1 = *(const bf8s*)(Qb + (size_t)l15*64 + 32 + l4*8);

  if(wc < 2){
    f4 qa = {};
    bf8s r0 = *(const bf8s*)(rel + (size_t)(wc*16+l15)*64 + l4*8);
    bf8s r1 = *(const bf8s*)(rel + (size_t)(wc*16+l15)*64 + 32 + l4*8);
    qa = __builtin_amdgcn_mfma_f32_16x16x32_bf16(af0, r0, qa, 0,0,0);
    qa = __builtin_amdgcn_mfma_f32_16x16x32_bf16(af1, r1, qa, 0,0,0);
    int m = wc*16 + l15;
    if(m < 17){
      #pragma unroll
      for(int q=0;q<4;++q) qrs[l4*4+q][m] = qa[q];
    }
  }
  __syncthreads();

  float mx4[4] = {-INFINITY,-INFINITY,-INFINITY,-INFINITY};
  for(int j=wc; j<nj; j+=4){
    f4 sa = {};
    const bf16* kr = Kb + (size_t)(j*16+l15)*64;
    bf8s k0 = *(const bf8s*)(kr + l4*8);
    bf8s k1 = *(const bf8s*)(kr + 32 + l4*8);
    sa = __builtin_amdgcn_mfma_f32_16x16x32_bf16(af0, k0, sa, 0,0,0);
    sa = __builtin_amdgcn_mfma_f32_16x16x32_bf16(af1, k1, sa, 0,0,0);
    int s = j*16 + l15;
    #pragma unroll
    for(int q=0;q<4;++q){
      int row = l4*4+q, t = t0+row;
      float sp = -1e30f;
      if(s <= t){
        int m = s - t + 16; m = m < 0 ? 0 : m;
        sp = (sa[q] + qrs[row][m])*0.125f;
        mx4[q] = fmaxf(mx4[q], sp);
      }
      Plds[row][s] = (bf16)sp;
    }
  }
  #pragma unroll
  for(int q=0;q<4;++q){
    float m = mx4[q];
    m = fmaxf(m, __shfl_xor(m,1)); m = fmaxf(m, __shfl_xor(m,2));
    m = fmaxf(m, __shfl_xor(m,4)); m = fmaxf(m, __shfl_xor(m,8));
    mx4[q] = m;
  }
  if(l15==0){
    #pragma unroll
    for(int q=0;q<4;++q) redmx[wc][l4*4+q] = mx4[q];
  }
  __syncthreads();

  float mxg[4], sum4[4] = {0.f,0.f,0.f,0.f};
  #pragma unroll
  for(int q=0;q<4;++q){
    int rloc = l4*4+q;
    mxg[q] = fmaxf(fmaxf(redmx[0][rloc], redmx[1][rloc]),
                   fmaxf(redmx[2][rloc], redmx[3][rloc]));
  }
  for(int j=wc; j<nj; j+=4){
    int s = j*16 + l15;
    #pragma unroll
    for(int q=0;q<4;++q){
      int row = l4*4+q, t = t0+row;
      float e = expf(cvt(Plds[row][s]) - mxg[q]);   // masked: exp(-1e30-mx)=0
      Plds[row][s] = (bf16)e;
      sum4[q] += e;
      int m = s - t + 16;
      if(m >= 1 && m <= 16) amlds[row][m] = e;      // unique owner
    }
  }
  #pragma unroll
  for(int q=0;q<4;++q){
    float s = sum4[q];
    s += __shfl_xor(s,1); s += __shfl_xor(s,2);
    s += __shfl_xor(s,4); s += __shfl_xor(s,8);
    sum4[q] = s;
  }
  if(l15==0){
    #pragma unroll
    for(int q=0;q<4;++q) redsum[wc][l4*4+q] = sum4[q];
  }
  __syncthreads();

  f4 pacc = {0,0,0,0};
  for(int ks=0; ks<KC; ++ks){
    bf8s ap = *(const bf8s*)(&Plds[l15][ks*32 + l4*8]);
    bf8s bv = *(const bf8s*)(Vb + (size_t)(wc*16+l15)*512 + ks*32 + l4*8);
    pacc = __builtin_amdgcn_mfma_f32_16x16x32_bf16(ap, bv, pacc, 0,0,0);
  }
  #pragma unroll
  for(int q=0;q<4;++q){
    int row = l4*4+q;
    float sum = redsum[0][row]+redsum[1][row]+redsum[2][row]+redsum[3][row];
    float rsv = 1.f/sum;
    float a[16];
    float amsum = 0.f;
    #pragma unroll
    for(int m=1;m<=16;++m){ a[m-1] = amlds[row][m]; amsum += a[m-1]; }
    float am0 = sum - amsum;
    int hh = wc*16 + l15;
    float acc = pacc[q] + am0*cvt(rel[hh]);
    #pragma unroll
    for(int m=1;m<=16;++m) acc += a[m-1]*cvt(rel[m*64 + hh]);
    vlds[row][hh] = (bf16)(acc*rsv);
  }
  __syncthreads();

  // ---- Phase B: proj (vals @ wsT^T) + bo + resid -> h; LN2 -> y ----
  bf8s pa0 = *(const bf8s*)(&vlds[l15][l4*8]);
  bf8s pa1 = *(const bf8s*)(&vlds[l15][32 + l4*8]);
  f4 acc2[8] = {};
  #pragma unroll
  for(int j=0;j<8;++j){
    int nn = wc*8 + j;
    bf8s bv0 = *(const bf8s*)(wsT + (size_t)(nn*16+l15)*64 + l4*8);
    bf8s bv1 = *(const bf8s*)(wsT + (size_t)(nn*16+l15)*64 + 32 + l4*8);
    acc2[j] = __builtin_amdgcn_mfma_f32_16x16x32_bf16(pa0, bv0, acc2[j], 0,0,0);
    acc2[j] = __builtin_amdgcn_mfma_f32_16x16x32_bf16(pa1, bv1, acc2[j], 0,0,0);
  }
  float s4[4] = {0,0,0,0}, s24[4] = {0,0,0,0};
  #pragma unroll
  for(int j=0;j<8;++j){
    int col = (wc*8+j)*16 + l15;
    float bv = cvt(bo[col]);
    #pragma unroll
    for(int q=0;q<4;++q){
      int row = t0 + l4*4 + q;
      size_t off = ((size_t)b*512 + row)*512 + col;
      float v = acc2[j][q] + bv + h[off];
      acc2[j][q] = v;
      h[off] = v;
      s4[q] += v; s24[q] += v*v;
    }
  }
  #pragma unroll
  for(int q=0;q<4;++q){
    #pragma unroll
    for(int o=1;o<16;o<<=1){ s4[q] += __shfl_xor(s4[q],o); s24[q] += __shfl_xor(s24[q],o); }
    if(l15==0){ rs[wc][l4*4+q] = s4[q]; rs2[wc][l4*4+q] = s24[q]; }
  }
  __syncthreads();
  #pragma unroll
  for(int q=0;q<4;++q){
    int rloc = l4*4+q;
    float a  = rs[0][rloc]+rs[1][rloc]+rs[2][rloc]+rs[3][rloc];
    float a2 = rs2[0][rloc]+rs2[1][rloc]+rs2[2][rloc]+rs2[3][rloc];
    float mean = a*(1.f/512.f);
    float var  = a2*(1.f/512.f) - mean*mean;
    float inv  = rsqrtf(var + 1e-5f);
    int row = t0 + rloc;
    #pragma unroll
    for(int j=0;j<8;++j){
      int col = (wc*8+j)*16 + l15;
      y[((size_t)b*512 + row)*512 + col] =
          (bf16)((acc2[j][q]-mean)*inv*cvt(g[col]) + cvt(be[col]));
    }
  }
}

extern "C" void kernel_launch(void* const* d_in, const int* in_sizes, int n_in,
                              void* d_out, int out_size, void* d_ws, size_t ws_size,
                              hipStream_t stream){
  const int* idx = (const int*)d_in[0];

  char* p = (char*)d_ws;
  auto alloc = [&](size_t bytes)->char*{ char* r = p; p += (bytes + 255) & ~(size_t)255; return r; };

  int*  flag  = (int*)alloc(4);
  bf16* rel_b = (bf16*)alloc(12672*2);
  bf16* bo_b  = (bf16*)alloc(3072*2);
  bf16* g1_b  = (bf16*)alloc(3072*2);
  bf16* be1_b = (bf16*)alloc(3072*2);
  bf16* g2_b  = (bf16*)alloc(3072*2);
  bf16* be2_b = (bf16*)alloc(3072*2);
  bf16* b1_b  = (bf16*)alloc(12288*2);
  bf16* b2_b  = (bf16*)alloc(3072*2);
  bf16* bout_b= (bf16*)alloc(2048*2);
  bf16* bqkv  = (bf16*)alloc(LL*192*2);
  bf16* WqkvT = (bf16*)alloc((size_t)LL*3*64*512*2);    // [L][192][512]
  bf16* W1T   = (bf16*)alloc((size_t)LL*2048*512*2);    // [L][2048][512]
  bf16* W2T   = (bf16*)alloc((size_t)LL*512*2048*2);    // [L][512][2048]
  bf16* WoutT = (bf16*)alloc((size_t)2048*512*2);       // [2048][512]
  bf16* wsT_all=(bf16*)alloc((size_t)LL*512*64*2);      // [L][512][64]
  float* pe   = (float*)alloc((size_t)TT*DD*4);         // 1 MB pe table
  float* h    = (float*)alloc((size_t)BT*DD*4);         // 16 MB
  bf16*  y    = (bf16*) alloc((size_t)BT*DD*2);         //  8 MB (ln2 out)
  bf16*  hb   = y;                                      // last-FFN2 bf16 out (y dead by then)
  bf16*  QKV  = (bf16*) alloc((size_t)3*BT*64*2);       // Q|K planes
  bf16*  VbT  = (bf16*) alloc((size_t)BB*64*512*2);     // [16][64][512]
  bf16*  mid  = (bf16*)d_out;                           // FFN scratch in d_out
  bf16*  Qb = QKV, *Kb = QKV + (size_t)BT*64;

  // ---- setup ----
  k_flag<<<1,64,0,stream>>>(d_in[11], flag);
  k_cvt_all<<<(46592+255)/256,256,0,stream>>>(
      d_in[8], d_in[10], d_in[11], d_in[12], d_in[13], d_in[14],
      d_in[16], d_in[18], d_in[20], d_in[3], d_in[5], d_in[7],
      rel_b, bo_b, g1_b, be1_b, g2_b, be2_b, b1_b, b2_b, bout_b, bqkv, flag);
  k_petab<<<TT,256,0,stream>>>(pe);
  k_tr3<<<dim3(2,16,3*LL),256,0,stream>>>(d_in[2], d_in[4], d_in[6], WqkvT, flag);
  k_tr<<<dim3(64,16,LL),256,0,stream>>>(d_in[15], W1T, 512, 2048, 512*2048, 2048*512, 512, flag);
  k_tr<<<dim3(16,64,LL),256,0,stream>>>(d_in[17], W2T, 2048, 512, 2048*512, 512*2048, 2048, flag);
  k_tr<<<dim3(64,16,1),256,0,stream>>>(d_in[19], WoutT, 512, 2048, 0, 0, 512, flag);
  k_wsumT<<<(LL*32768+255)/256,256,0,stream>>>(d_in[9], wsT_all, flag);

  k_embed<<<BT,256,0,stream>>>(idx, d_in[1], pe, h, flag);

  for(int l=0; l<LL; ++l){
    // fused LN1 + QKV (+V transpose)
    k_lnqkv<<<256,256,0,stream>>>(h, g1_b+l*DD, be1_b+l*DD,
                                  WqkvT + (size_t)l*3*64*512, bqkv + l*192, QKV, VbT);
    // fused attn + proj + resid + LN2 -> h, y
    k_attnproj<<<dim3(32,16),256,0,stream>>>(Qb, Kb, VbT, rel_b + l*33*64,
                                             wsT_all + (size_t)l*32768,
                                             bo_b + l*DD, g2_b + l*DD, be2_b + l*DD, h, y);
    // mid = relu(y @ W1 + b1)   (bf16, d_out scratch) — 128x128 tile
    mm<128,128,2,2,0,true,false,false><<<dim3(1024,1,1),256,0,stream>>>(
        y, W1T + (size_t)l*2048*512, mid, b1_b + l*FF, BT, 2048, 512, 0,0,0,0, 16, nullptr, nullptr);
    if(l < LL-1){
      // h += mid @ W2 + b2 (f32)
      mm<128,64,4,1,1,false,true,false><<<dim3(512,1,1),256,0,stream>>>(
          mid, W2T + (size_t)l*512*2048, h, b2_b + l*DD, BT, 512, 2048, 0,0,0,0, 8, nullptr, nullptr);
    } else {
      // last layer: h-resid read + bf16 store straight to hb
      mm<128,64,4,1,3,false,true,false><<<dim3(512,1,1),256,0,stream>>>(
          mid, W2T + (size_t)l*512*2048, h, b2_b + l*DD, BT, 512, 2048, 0,0,0,0, 8, nullptr, hb);
    }
  }
  // out = hb @ Wout + bout (dual store per flag) — 128x128 tile
  mm<128,128,2,2,2,false,false,false><<<dim3(1024,1,1),256,0,stream>>>(
      hb, WoutT, d_out, bout_b, BT, 2048, 512, 0,0,0,0, 16, flag, nullptr);
}